// Round 4
// baseline (11132.330 us; speedup 1.0000x reference)
//
#include <hip/hip_runtime.h>
#include <hip/hip_bf16.h>
#include <math.h>

typedef __hip_bfloat16 bf16;

#define NN 40962
#define NE 245760
#define HDIM 256
#define NH 8
#define CH 32

#define EPB 16   // edges per block in edge_score
#define MPB 16   // edges per block in edge_mlp

__device__ __forceinline__ float b2f(bf16 v) { return __bfloat162float(v); }
__device__ __forceinline__ bf16 f2b(float v) { return __float2bfloat16(v); }

// ---- edge input projection: e[ed][j] = b[j] + sum_k attr[ed][k] * W[k][j] ----------
__global__ void k_edge_proj(const float* __restrict__ attr, const float* __restrict__ W,
                            const float* __restrict__ b, bf16* __restrict__ e) {
  long long i0 = (long long)blockIdx.x * blockDim.x + threadIdx.x;
  long long total = (long long)NE * HDIM;
  long long stride = (long long)gridDim.x * blockDim.x;
  for (long long t = i0; t < total; t += stride) {
    int ed = (int)(t >> 8);      // t / 256
    int j  = (int)(t & 255);
    float acc = b[j];
#pragma unroll
    for (int k = 0; k < 16; ++k) acc += attr[ed * 16 + k] * W[k * HDIM + j];
    e[t] = f2b(acc);
  }
}

// ---- node projections: xl[n][j] = sum_k x[n][k]*Wl[k][j] ; same for xr --------------
template <int ID>
__global__ void k_node_proj(const float* __restrict__ x, const float* __restrict__ Wl,
                            const float* __restrict__ Wr, bf16* __restrict__ xl,
                            bf16* __restrict__ xr) {
  int j = threadIdx.x;
  __shared__ float xs[ID];
  for (int n = blockIdx.x; n < NN; n += gridDim.x) {
    if (j < ID) xs[j] = x[(size_t)n * ID + j];
    __syncthreads();
    float al = 0.f, ar = 0.f;
#pragma unroll 8
    for (int k = 0; k < ID; ++k) {
      float xv = xs[k];
      al += xv * Wl[k * HDIM + j];
      ar += xv * Wr[k * HDIM + j];
    }
    xl[(size_t)n * HDIM + j] = f2b(al);
    xr[(size_t)n * HDIM + j] = f2b(ar);
    __syncthreads();
  }
}

// ---- clear agg [NN*HDIM] and den [NN*NH] --------------------------------------------
__global__ void k_clear(float* __restrict__ agg, float* __restrict__ den) {
  int i = blockIdx.x * blockDim.x + threadIdx.x;
  int stride = gridDim.x * blockDim.x;
  for (int t = i; t < NN * HDIM; t += stride) agg[t] = 0.f;
  for (int t = i; t < NN * NH; t += stride) den[t] = 0.f;
}

__global__ void k_zero(float* __restrict__ p, int n) {
  int i = blockIdx.x * blockDim.x + threadIdx.x;
  if (i < n) p[i] = 0.f;
}

// ---- fused ee = e@We ; s[ed][h] = sum_c lrelu(xl[src]+xr[dst]+ee)*att[h][c] ---------
__global__ void k_edge_score(const bf16* __restrict__ e, const float* __restrict__ We,
                             const bf16* __restrict__ xl, const bf16* __restrict__ xr,
                             const float* __restrict__ att, const int* __restrict__ src,
                             const int* __restrict__ dst, float* __restrict__ s) {
  int j = threadIdx.x;
  __shared__ float els[EPB][HDIM];
  __shared__ float red[HDIM];
  int base = blockIdx.x * EPB;            // NE % EPB == 0
  for (int t = j; t < EPB * HDIM; t += 256) {
    int p = t >> 8, k = t & 255;
    els[p][k] = b2f(e[(size_t)(base + p) * HDIM + k]);
  }
  __syncthreads();
  float acc[EPB];
#pragma unroll
  for (int p = 0; p < EPB; ++p) acc[p] = 0.f;
  for (int k = 0; k < HDIM; ++k) {
    float w = We[k * HDIM + j];
#pragma unroll
    for (int p = 0; p < EPB; ++p) acc[p] += els[p][k] * w;
  }
  float av = att[j];
  for (int p = 0; p < EPB; ++p) {
    int ed = base + p;
    int sn = src[ed], dn = dst[ed];
    float m = acc[p] + b2f(xl[(size_t)sn * HDIM + j]) + b2f(xr[(size_t)dn * HDIM + j]);
    m = (m > 0.f) ? m : 0.2f * m;         // leaky_relu 0.2
    red[j] = m * av;
    __syncthreads();
    if (j < NH) {
      float t = 0.f;
#pragma unroll
      for (int c = 0; c < CH; ++c) t += red[j * CH + c];
      s[ed * NH + j] = t;
    }
    __syncthreads();
  }
}

// ---- ex = exp(s) ; agg[dst] += ex*xl[src] ; den[dst] += ex --------------------------
// (identical to ref softmax: max-subtraction cancels in ex/den; |s| is O(1))
__global__ void k_edge_soft_agg(const float* __restrict__ s, const bf16* __restrict__ xl,
                                const int* __restrict__ src, const int* __restrict__ dst,
                                float* __restrict__ agg, float* __restrict__ den) {
  int j = threadIdx.x;
  int h = j >> 5;
  for (int ed = blockIdx.x; ed < NE; ed += gridDim.x) {
    int sn = src[ed], dn = dst[ed];
    float ex = expf(s[ed * NH + h]);
    atomicAdd(&agg[(size_t)dn * HDIM + j], ex * b2f(xl[(size_t)sn * HDIM + j]));
    if ((j & 31) == 0) atomicAdd(&den[dn * NH + h], ex);
  }
}

// ---- out = mean_h(agg/den) + x@Wres + bn ; write pre-LN; optional LN (LDS-serial) ---
template <int ID, bool LN>
__global__ void k_node_out(const float* __restrict__ agg, const float* __restrict__ den,
                           const float* __restrict__ x, const float* __restrict__ Wres,
                           const float* __restrict__ bn, const float* __restrict__ lng,
                           const float* __restrict__ lnb, float* __restrict__ xpre,
                           float* __restrict__ xpost) {
  int t = threadIdx.x;
  int c = t & 31, sub = t >> 5;           // 8 nodes per block
  __shared__ float onode[8][CH];
  int n = blockIdx.x * 8 + sub;           // grid = (NN+7)/8
  float o = 0.f;
  if (n < NN) {
#pragma unroll
    for (int h = 0; h < NH; ++h)
      o += agg[(size_t)n * HDIM + h * CH + c] / (den[n * NH + h] + 1e-16f);
    o *= (1.f / NH);
    float r = 0.f;
    for (int k = 0; k < ID; ++k) r += x[(size_t)n * ID + k] * Wres[k * CH + c];
    o += r + bn[c];
    xpre[(size_t)n * CH + c] = o;
    onode[sub][c] = o;
  }
  __syncthreads();
  if (LN && n < NN) {
    float mu = 0.f;
#pragma unroll
    for (int k = 0; k < CH; ++k) mu += onode[sub][k];
    mu *= (1.f / CH);
    float var = 0.f;
#pragma unroll
    for (int k = 0; k < CH; ++k) { float d = onode[sub][k] - mu; var += d * d; }
    var *= (1.f / CH);
    xpost[(size_t)n * CH + c] = (o - mu) * rsqrtf(var + 1e-5f) * lng[c] + lnb[c];
  }
}

// ---- residual edge MLP: e += gelu([out_s,out_d,e]@Wu1+bu1)@Wu2 + bu2 ----------------
__global__ void k_edge_mlp(bf16* __restrict__ e, const float* __restrict__ xo,
                           const int* __restrict__ src, const int* __restrict__ dst,
                           const float* __restrict__ Wu1, const float* __restrict__ bu1,
                           const float* __restrict__ Wu2, const float* __restrict__ bu2) {
  int j = threadIdx.x;
  __shared__ float hs[MPB][2 * CH + HDIM];   // [16][320]
  __shared__ float hid[MPB][HDIM];           // [16][256]
  int base = blockIdx.x * MPB;               // NE % MPB == 0
  for (int tt = j; tt < MPB * HDIM; tt += 256) {
    int p = tt >> 8, k = tt & 255;
    hs[p][2 * CH + k] = b2f(e[(size_t)(base + p) * HDIM + k]);
  }
  for (int tt = j; tt < MPB * 2 * CH; tt += 256) {
    int p = tt >> 6, k = tt & 63;
    int ed = base + p;
    hs[p][k] = (k < CH) ? xo[(size_t)src[ed] * CH + k]
                        : xo[(size_t)dst[ed] * CH + (k - CH)];
  }
  __syncthreads();
  float acc[MPB];
#pragma unroll
  for (int p = 0; p < MPB; ++p) acc[p] = bu1[j];
  for (int k = 0; k < 2 * CH + HDIM; ++k) {
    float w = Wu1[k * HDIM + j];
#pragma unroll
    for (int p = 0; p < MPB; ++p) acc[p] += hs[p][k] * w;
  }
#pragma unroll
  for (int p = 0; p < MPB; ++p) {
    float xv = acc[p];
    float tnh = tanhf(0.7978845608028654f * (xv + 0.044715f * xv * xv * xv));
    hid[p][j] = 0.5f * xv * (1.f + tnh);     // gelu tanh approx (jax default)
  }
  __syncthreads();
#pragma unroll
  for (int p = 0; p < MPB; ++p) acc[p] = bu2[j];
  for (int k = 0; k < HDIM; ++k) {
    float w = Wu2[k * HDIM + j];
#pragma unroll
    for (int p = 0; p < MPB; ++p) acc[p] += hid[p][k] * w;
  }
#pragma unroll
  for (int p = 0; p < MPB; ++p) {
    size_t idx = (size_t)(base + p) * HDIM + j;
    e[idx] = f2b(hs[p][2 * CH + j] + acc[p]);   // old e + delta
  }
}

// ---- SGFormer q,k,v projections + per-head L2 normalization -------------------------
__global__ void k_sg_qkv(const float* __restrict__ x, const float* __restrict__ Wq,
                         const float* __restrict__ Wk, const float* __restrict__ Wv,
                         bf16* __restrict__ qs, bf16* __restrict__ ks,
                         bf16* __restrict__ vv) {
  int j = threadIdx.x;
  int hb = j & ~31;                       // head base channel
  __shared__ float xs[HDIM], qq[HDIM], kk[HDIM];
  for (int n = blockIdx.x; n < NN; n += gridDim.x) {
    xs[j] = x[(size_t)n * HDIM + j];
    __syncthreads();
    float q = 0.f, k = 0.f, v = 0.f;
#pragma unroll 8
    for (int d = 0; d < HDIM; ++d) {
      float xv = xs[d];
      q += xv * Wq[d * HDIM + j];
      k += xv * Wk[d * HDIM + j];
      v += xv * Wv[d * HDIM + j];
    }
    qq[j] = q * q; kk[j] = k * k;
    __syncthreads();
    float qn = 0.f, kn = 0.f;
#pragma unroll
    for (int c = 0; c < CH; ++c) { qn += qq[hb + c]; kn += kk[hb + c]; }
    qs[(size_t)n * HDIM + j] = f2b(q / (sqrtf(qn) + 1e-6f));
    ks[(size_t)n * HDIM + j] = f2b(k / (sqrtf(kn) + 1e-6f));
    vv[(size_t)n * HDIM + j] = f2b(v);
    __syncthreads();
  }
}

// ---- kv[h][c][d] = sum_n ks[n,h,c]*v[n,h,d] ; ksum[h][c] = sum_n ks[n,h,c] ----------
__global__ void k_sg_kv(const bf16* __restrict__ ks, const bf16* __restrict__ vv,
                        float* __restrict__ kv, float* __restrict__ ksum) {
  int t = threadIdx.x;
  int h = t >> 5, c = t & 31;
  float kvloc[CH];
  float ksl = 0.f;
#pragma unroll
  for (int d = 0; d < CH; ++d) kvloc[d] = 0.f;
  __shared__ float krow[HDIM], vrow[HDIM];
  for (int n = blockIdx.x; n < NN; n += gridDim.x) {
    krow[t] = b2f(ks[(size_t)n * HDIM + t]);
    vrow[t] = b2f(vv[(size_t)n * HDIM + t]);
    __syncthreads();
    float kc = krow[h * CH + c];
    ksl += kc;
#pragma unroll
    for (int d = 0; d < CH; ++d) kvloc[d] += kc * vrow[h * CH + d];
    __syncthreads();
  }
#pragma unroll
  for (int d = 0; d < CH; ++d) atomicAdd(&kv[(h * CH + c) * CH + d], kvloc[d]);
  atomicAdd(&ksum[h * CH + c], ksl);
}

// ---- trans = mean_h((qs@kv + N*v)/(qs·ksum + N)) ; out = LN(a*x + (1-a)*trans) ------
// OUTPUT IS FLOAT32 (reference output dtype).
__global__ void k_sg_final(const bf16* __restrict__ qs, const bf16* __restrict__ vv,
                           const float* __restrict__ kv, const float* __restrict__ ksum,
                           const float* __restrict__ xg, const float* __restrict__ alphap,
                           const float* __restrict__ cng, const float* __restrict__ cnb,
                           float* __restrict__ out) {
  int t = threadIdx.x;
  int d = t & 31, sub = t >> 5;
  __shared__ float qrow[8][HDIM];          // 8 KB
  __shared__ float crow[8][CH];
  int n = blockIdx.x * 8 + sub;            // grid = (NN+7)/8
  for (int tt = t; tt < 8 * HDIM; tt += 256) {
    int p = tt >> 8, k = tt & 255;
    int n2 = blockIdx.x * 8 + p;
    if (n2 < NN) qrow[p][k] = b2f(qs[(size_t)n2 * HDIM + k]);
  }
  __syncthreads();
  float alpha = 1.f / (1.f + expf(-alphap[0]));
  const float Nf = (float)NN;
  float comb = 0.f;
  if (n < NN) {
    float acc = 0.f;
#pragma unroll
    for (int h = 0; h < NH; ++h) {
      float nm = 0.f, dp = 0.f;
#pragma unroll 8
      for (int c = 0; c < CH; ++c) {
        float qv = qrow[sub][h * CH + c];
        nm += qv * kv[(h * CH + c) * CH + d];
        dp += qv * ksum[h * CH + c];
      }
      nm += Nf * b2f(vv[(size_t)n * HDIM + h * CH + d]);
      acc += nm / (dp + Nf);
    }
    float trans = acc * (1.f / NH);
    comb = alpha * xg[(size_t)n * CH + d] + (1.f - alpha) * trans;
    crow[sub][d] = comb;
  }
  __syncthreads();
  if (n < NN) {
    float mu = 0.f;
#pragma unroll
    for (int k = 0; k < CH; ++k) mu += crow[sub][k];
    mu *= (1.f / CH);
    float var = 0.f;
#pragma unroll
    for (int k = 0; k < CH; ++k) { float dv = crow[sub][k] - mu; var += dv * dv; }
    var *= (1.f / CH);
    float o = (comb - mu) * rsqrtf(var + 1e-5f) * cng[d] + cnb[d];
    out[(size_t)n * CH + d] = o;           // f32 store
  }
}

extern "C" void kernel_launch(void* const* d_in, const int* in_sizes, int n_in,
                              void* d_out, int out_size, void* d_ws, size_t ws_size,
                              hipStream_t stream) {
  const float* mesh  = (const float*)d_in[0];
  const int*   eidx  = (const int*)d_in[1];
  const float* eattr = (const float*)d_in[2];
  const float* epW   = (const float*)d_in[3];
  const float* epb   = (const float*)d_in[4];
  const float* Wl0   = (const float*)d_in[5];
  const float* Wr0   = (const float*)d_in[6];
  const float* WlL   = (const float*)d_in[7];
  const float* WrL   = (const float*)d_in[8];
  const float* We0   = (const float*)d_in[9];
  const float* WeL   = (const float*)d_in[10];
  const float* att0  = (const float*)d_in[11];
  const float* attL  = (const float*)d_in[12];
  const float* Wres0 = (const float*)d_in[13];
  const float* WresL = (const float*)d_in[14];
  const float* bn0   = (const float*)d_in[15];
  const float* bnL   = (const float*)d_in[16];
  const float* Wu1_0 = (const float*)d_in[17];
  const float* Wu1L  = (const float*)d_in[18];
  const float* bu1_0 = (const float*)d_in[19];
  const float* bu1L  = (const float*)d_in[20];
  const float* Wu2_0 = (const float*)d_in[21];
  const float* Wu2L  = (const float*)d_in[22];
  const float* bu2_0 = (const float*)d_in[23];
  const float* bu2L  = (const float*)d_in[24];
  const float* lng   = (const float*)d_in[25];
  const float* lnb   = (const float*)d_in[26];
  const float* Wq    = (const float*)d_in[27];
  const float* Wk    = (const float*)d_in[28];
  const float* Wv    = (const float*)d_in[29];
  const float* alphap= (const float*)d_in[30];
  const float* cng   = (const float*)d_in[31];
  const float* cnb   = (const float*)d_in[32];

  const int* src = eidx;
  const int* dst = eidx + NE;

  char* base = (char*)d_ws;
  size_t o = 0;
  bf16* e    = (bf16*)(base + o); o += (size_t)NE * HDIM * 2;
  bf16* xl   = (bf16*)(base + o); o += (size_t)NN * HDIM * 2;   // reused: qs
  bf16* xr   = (bf16*)(base + o); o += (size_t)NN * HDIM * 2;   // reused: ks
  float* agg = (float*)(base + o); o += (size_t)NN * HDIM * 4;  // reused: vv (bf16)
  float* sbuf= (float*)(base + o); o += (size_t)NE * NH * 4;
  float* den = (float*)(base + o); o += (size_t)NN * NH * 4;
  float* xa  = (float*)(base + o); o += (size_t)NN * CH * 4;
  float* xb  = (float*)(base + o); o += (size_t)NN * CH * 4;
  float* xc  = (float*)(base + o); o += (size_t)NN * CH * 4;
  float* kv  = (float*)(base + o); o += NH * CH * CH * 4;
  float* ksum= (float*)(base + o); o += NH * CH * 4;
  if (ws_size < o) return;   // fail cleanly if ws too small

  k_edge_proj<<<16384, 256, 0, stream>>>(eattr, epW, epb, e);

  const float* xin = mesh;
  float* post = xb;
  for (int l = 0; l < 4; ++l) {
    const float *Wl_p, *Wr_p, *We_p, *att_p, *Wres_p, *bn_p, *Wu1_p, *bu1_p, *Wu2_p, *bu2_p;
    if (l == 0) {
      Wl_p = Wl0; Wr_p = Wr0; We_p = We0; att_p = att0; Wres_p = Wres0; bn_p = bn0;
      Wu1_p = Wu1_0; bu1_p = bu1_0; Wu2_p = Wu2_0; bu2_p = bu2_0;
    } else {
      int i = l - 1;
      Wl_p = WlL + (size_t)i * CH * HDIM;
      Wr_p = WrL + (size_t)i * CH * HDIM;
      We_p = WeL + (size_t)i * HDIM * HDIM;
      att_p = attL + (size_t)i * HDIM;
      Wres_p = WresL + (size_t)i * CH * CH;
      bn_p = bnL + (size_t)i * CH;
      Wu1_p = Wu1L + (size_t)i * (2 * CH + HDIM) * HDIM;
      bu1_p = bu1L + (size_t)i * HDIM;
      Wu2_p = Wu2L + (size_t)i * HDIM * HDIM;
      bu2_p = bu2L + (size_t)i * HDIM;
    }

    if (l == 0) k_node_proj<HDIM><<<4096, 256, 0, stream>>>(xin, Wl_p, Wr_p, xl, xr);
    else        k_node_proj<CH>  <<<4096, 256, 0, stream>>>(xin, Wl_p, Wr_p, xl, xr);

    k_clear<<<2048, 256, 0, stream>>>(agg, den);
    k_edge_score<<<NE / EPB, 256, 0, stream>>>(e, We_p, xl, xr, att_p, src, dst, sbuf);
    k_edge_soft_agg<<<8192, 256, 0, stream>>>(sbuf, xl, src, dst, agg, den);

    if (l == 0)
      k_node_out<HDIM, true><<<(NN + 7) / 8, 256, 0, stream>>>(agg, den, xin, Wres_p, bn_p,
                                                               lng, lnb, xa, post);
    else if (l < 3)
      k_node_out<CH, true><<<(NN + 7) / 8, 256, 0, stream>>>(agg, den, xin, Wres_p, bn_p,
                                                             lng + (size_t)l * CH,
                                                             lnb + (size_t)l * CH, xa, post);
    else
      k_node_out<CH, false><<<(NN + 7) / 8, 256, 0, stream>>>(agg, den, xin, Wres_p, bn_p,
                                                              nullptr, nullptr, xa, nullptr);

    if (l < 3) k_edge_mlp<<<NE / MPB, 256, 0, stream>>>(e, xa, src, dst, Wu1_p, bu1_p, Wu2_p, bu2_p);

    xin = post;
    post = (post == xb) ? xc : xb;
  }
  // final GAT output (no LN) is in xa

  bf16* vv = (bf16*)agg;
  k_sg_qkv<<<4096, 256, 0, stream>>>(mesh, Wq, Wk, Wv, xl, xr, vv);
  k_zero<<<(NH * CH * CH + NH * CH + 255) / 256, 256, 0, stream>>>(kv, NH * CH * CH + NH * CH);
  k_sg_kv<<<256, 256, 0, stream>>>(xr, vv, kv, ksum);
  k_sg_final<<<(NN + 7) / 8, 256, 0, stream>>>(xl, vv, kv, ksum, xa, alphap, cng, cnb,
                                               (float*)d_out);
}

// Round 5
// 7749.472 us; speedup vs baseline: 1.4365x; 1.4365x over previous
//
#include <hip/hip_runtime.h>
#include <hip/hip_bf16.h>
#include <math.h>

typedef __hip_bfloat16 bf16;
typedef __attribute__((ext_vector_type(8))) __bf16 bf16x8;
typedef __attribute__((ext_vector_type(4))) float f32x4;

#define NN 40962
#define NE 245760
#define HDIM 256
#define NH 8
#define CH 32

#define EPB 16   // edges per block in edge_score
#define MT 64    // edges per block in MFMA edge_mlp

__device__ __forceinline__ float b2f(bf16 v) { return __bfloat162float(v); }
__device__ __forceinline__ bf16 f2b(float v) { return __float2bfloat16(v); }
__device__ __forceinline__ unsigned short f2bs(float v) {
  bf16 b = __float2bfloat16(v);
  return __builtin_bit_cast(unsigned short, b);
}
__device__ __forceinline__ float bs2f(unsigned short u) {
  return __bfloat162float(__builtin_bit_cast(bf16, u));
}

// ---- edge input projection: e[ed][j] = b[j] + sum_k attr[ed][k] * W[k][j] ----------
__global__ void k_edge_proj(const float* __restrict__ attr, const float* __restrict__ W,
                            const float* __restrict__ b, bf16* __restrict__ e) {
  long long i0 = (long long)blockIdx.x * blockDim.x + threadIdx.x;
  long long total = (long long)NE * HDIM;
  long long stride = (long long)gridDim.x * blockDim.x;
  for (long long t = i0; t < total; t += stride) {
    int ed = (int)(t >> 8);
    int j  = (int)(t & 255);
    float acc = b[j];
#pragma unroll
    for (int k = 0; k < 16; ++k) acc += attr[ed * 16 + k] * W[k * HDIM + j];
    e[t] = f2b(acc);
  }
}

// ---- node projections: xl[n][j] = sum_k x[n][k]*Wl[k][j] ; same for xr --------------
template <int ID>
__global__ void k_node_proj(const float* __restrict__ x, const float* __restrict__ Wl,
                            const float* __restrict__ Wr, bf16* __restrict__ xl,
                            bf16* __restrict__ xr) {
  int j = threadIdx.x;
  __shared__ float xs[ID];
  for (int n = blockIdx.x; n < NN; n += gridDim.x) {
    if (j < ID) xs[j] = x[(size_t)n * ID + j];
    __syncthreads();
    float al = 0.f, ar = 0.f;
#pragma unroll 8
    for (int k = 0; k < ID; ++k) {
      float xv = xs[k];
      al += xv * Wl[k * HDIM + j];
      ar += xv * Wr[k * HDIM + j];
    }
    xl[(size_t)n * HDIM + j] = f2b(al);
    xr[(size_t)n * HDIM + j] = f2b(ar);
    __syncthreads();
  }
}

// ---- clear agg [NN*HDIM] and den [NN*NH] --------------------------------------------
__global__ void k_clear(float* __restrict__ agg, float* __restrict__ den) {
  int i = blockIdx.x * blockDim.x + threadIdx.x;
  int stride = gridDim.x * blockDim.x;
  for (int t = i; t < NN * HDIM; t += stride) agg[t] = 0.f;
  for (int t = i; t < NN * NH; t += stride) den[t] = 0.f;
}

__global__ void k_zero(float* __restrict__ p, int n) {
  int i = blockIdx.x * blockDim.x + threadIdx.x;
  if (i < n) p[i] = 0.f;
}

// ---- weight swizzle into MFMA B-fragment-major layout (bf16 bits) -------------------
// out[(((n0*(K/32) + k0)*64 + l)*8 + i] = bf16(W[k0*32 + (l>>4)*8 + i][n0*16 + (l&15)])
template <int K>
__global__ void k_swz_w(const float* __restrict__ W, unsigned short* __restrict__ out) {
  int t = blockIdx.x * 256 + threadIdx.x;
  if (t >= K * 256) return;
  int i  = t & 7;
  int l  = (t >> 3) & 63;
  int k0 = (t >> 9) % (K / 32);
  int n0 = t / (512 * (K / 32));
  int k = k0 * 32 + (l >> 4) * 8 + i;
  int n = n0 * 16 + (l & 15);
  out[t] = f2bs(W[k * 256 + n]);
}

// ---- fused ee = e@We ; s[ed][h] = sum_c lrelu(xl[src]+xr[dst]+ee)*att[h][c] ---------
__global__ void k_edge_score(const bf16* __restrict__ e, const float* __restrict__ We,
                             const bf16* __restrict__ xl, const bf16* __restrict__ xr,
                             const float* __restrict__ att, const int* __restrict__ src,
                             const int* __restrict__ dst, float* __restrict__ s) {
  int j = threadIdx.x;
  __shared__ float els[EPB][HDIM];
  __shared__ float red[HDIM];
  int base = blockIdx.x * EPB;
  for (int t = j; t < EPB * HDIM; t += 256) {
    int p = t >> 8, k = t & 255;
    els[p][k] = b2f(e[(size_t)(base + p) * HDIM + k]);
  }
  __syncthreads();
  float acc[EPB];
#pragma unroll
  for (int p = 0; p < EPB; ++p) acc[p] = 0.f;
  for (int k = 0; k < HDIM; ++k) {
    float w = We[k * HDIM + j];
#pragma unroll
    for (int p = 0; p < EPB; ++p) acc[p] += els[p][k] * w;
  }
  float av = att[j];
  for (int p = 0; p < EPB; ++p) {
    int ed = base + p;
    int sn = src[ed], dn = dst[ed];
    float m = acc[p] + b2f(xl[(size_t)sn * HDIM + j]) + b2f(xr[(size_t)dn * HDIM + j]);
    m = (m > 0.f) ? m : 0.2f * m;
    red[j] = m * av;
    __syncthreads();
    if (j < NH) {
      float t = 0.f;
#pragma unroll
      for (int c = 0; c < CH; ++c) t += red[j * CH + c];
      s[ed * NH + j] = t;
    }
    __syncthreads();
  }
}

// ---- ex = exp(s) ; agg[dst] += ex*xl[src] ; den[dst] += ex --------------------------
__global__ void k_edge_soft_agg(const float* __restrict__ s, const bf16* __restrict__ xl,
                                const int* __restrict__ src, const int* __restrict__ dst,
                                float* __restrict__ agg, float* __restrict__ den) {
  int j = threadIdx.x;
  int h = j >> 5;
  for (int ed = blockIdx.x; ed < NE; ed += gridDim.x) {
    int sn = src[ed], dn = dst[ed];
    float ex = expf(s[ed * NH + h]);
    atomicAdd(&agg[(size_t)dn * HDIM + j], ex * b2f(xl[(size_t)sn * HDIM + j]));
    if ((j & 31) == 0) atomicAdd(&den[dn * NH + h], ex);
  }
}

// ---- out = mean_h(agg/den) + x@Wres + bn ; write pre-LN; optional LN ----------------
template <int ID, bool LN>
__global__ void k_node_out(const float* __restrict__ agg, const float* __restrict__ den,
                           const float* __restrict__ x, const float* __restrict__ Wres,
                           const float* __restrict__ bn, const float* __restrict__ lng,
                           const float* __restrict__ lnb, float* __restrict__ xpre,
                           float* __restrict__ xpost) {
  int t = threadIdx.x;
  int c = t & 31, sub = t >> 5;
  __shared__ float onode[8][CH];
  int n = blockIdx.x * 8 + sub;
  float o = 0.f;
  if (n < NN) {
#pragma unroll
    for (int h = 0; h < NH; ++h)
      o += agg[(size_t)n * HDIM + h * CH + c] / (den[n * NH + h] + 1e-16f);
    o *= (1.f / NH);
    float r = 0.f;
    for (int k = 0; k < ID; ++k) r += x[(size_t)n * ID + k] * Wres[k * CH + c];
    o += r + bn[c];
    xpre[(size_t)n * CH + c] = o;
    onode[sub][c] = o;
  }
  __syncthreads();
  if (LN && n < NN) {
    float mu = 0.f;
#pragma unroll
    for (int k = 0; k < CH; ++k) mu += onode[sub][k];
    mu *= (1.f / CH);
    float var = 0.f;
#pragma unroll
    for (int k = 0; k < CH; ++k) { float d = onode[sub][k] - mu; var += d * d; }
    var *= (1.f / CH);
    xpost[(size_t)n * CH + c] = (o - mu) * rsqrtf(var + 1e-5f) * lng[c] + lnb[c];
  }
}

// ---- MFMA residual edge MLP: e += gelu([out_s,out_d,e]@Wu1+bu1)@Wu2 + bu2 -----------
// 64 edges/block, 4 waves; each wave computes a 64x64 output stripe with
// mfma_f32_16x16x32_bf16. Weights come pre-swizzled (fragment-major) from ws.
__global__ __launch_bounds__(256) void k_edge_mlp_mfma(
    bf16* __restrict__ e, const float* __restrict__ xo,
    const int* __restrict__ src, const int* __restrict__ dst,
    const unsigned short* __restrict__ W1s, const float* __restrict__ bu1,
    const unsigned short* __restrict__ W2s, const float* __restrict__ bu2) {
  __shared__ unsigned short A1s[MT][328];   // [64][320+8 pad] input rows
  __shared__ unsigned short A2s[MT][264];   // [64][256+8 pad] gelu(h1), reused for out
  __shared__ int sidx[MT], didx[MT];
  int tid = threadIdx.x;
  int l = tid & 63;
  int wave = tid >> 6;
  int base = blockIdx.x * MT;
  int lr = l & 15;          // row/col-in-tile lane index
  int lk = l >> 4;          // k-chunk lane index

  if (tid < MT) sidx[tid] = src[base + tid];
  else if (tid < 2 * MT) didx[tid - MT] = dst[base + tid - MT];
  __syncthreads();

  // stage e rows (bf16, 16B chunks) into cols 64..319
  for (int t = tid; t < MT * 32; t += 256) {
    int p = t >> 5, cc = t & 31;
    uint4 v = *reinterpret_cast<const uint4*>(&e[(size_t)(base + p) * HDIM + cc * 8]);
    *reinterpret_cast<uint4*>(&A1s[p][64 + cc * 8]) = v;
  }
  // stage xo[src]|xo[dst] (f32 -> bf16) into cols 0..63
  for (int t = tid; t < MT * 64; t += 256) {
    int p = t >> 6, c = t & 63;
    float v = (c < CH) ? xo[(size_t)sidx[p] * CH + c]
                       : xo[(size_t)didx[p] * CH + (c - CH)];
    A1s[p][c] = f2bs(v);
  }
  __syncthreads();

  int j0 = wave * 64;      // wave's output column base

  // ---- GEMM1: h1 = A1 @ Wu1  (K=320) ----
  f32x4 acc[4][4];
#pragma unroll
  for (int m = 0; m < 4; ++m)
#pragma unroll
    for (int n = 0; n < 4; ++n)
#pragma unroll
      for (int r = 0; r < 4; ++r) acc[m][n][r] = 0.f;

  for (int k0 = 0; k0 < 10; ++k0) {
    bf16x8 a[4], b[4];
#pragma unroll
    for (int m = 0; m < 4; ++m)
      a[m] = *reinterpret_cast<const bf16x8*>(&A1s[m * 16 + lr][k0 * 32 + lk * 8]);
#pragma unroll
    for (int n = 0; n < 4; ++n) {
      int nt = (j0 >> 4) + n;
      b[n] = *reinterpret_cast<const bf16x8*>(W1s + ((size_t)(nt * 10 + k0) * 64 + l) * 8);
    }
#pragma unroll
    for (int m = 0; m < 4; ++m)
#pragma unroll
      for (int n = 0; n < 4; ++n)
        acc[m][n] = __builtin_amdgcn_mfma_f32_16x16x32_bf16(a[m], b[n], acc[m][n], 0, 0, 0);
  }

  // gelu(h1 + bu1) -> A2 (bf16)
#pragma unroll
  for (int n = 0; n < 4; ++n) {
    float bv = bu1[j0 + n * 16 + lr];
#pragma unroll
    for (int m = 0; m < 4; ++m)
#pragma unroll
      for (int r = 0; r < 4; ++r) {
        float xv = acc[m][n][r] + bv;
        float tnh = tanhf(0.7978845608028654f * (xv + 0.044715f * xv * xv * xv));
        float g = 0.5f * xv * (1.f + tnh);
        A2s[m * 16 + lk * 4 + r][j0 + n * 16 + lr] = f2bs(g);
      }
  }
  __syncthreads();

  // ---- GEMM2: d = A2 @ Wu2  (K=256) ----
#pragma unroll
  for (int m = 0; m < 4; ++m)
#pragma unroll
    for (int n = 0; n < 4; ++n)
#pragma unroll
      for (int r = 0; r < 4; ++r) acc[m][n][r] = 0.f;

  for (int k0 = 0; k0 < 8; ++k0) {
    bf16x8 a[4], b[4];
#pragma unroll
    for (int m = 0; m < 4; ++m)
      a[m] = *reinterpret_cast<const bf16x8*>(&A2s[m * 16 + lr][k0 * 32 + lk * 8]);
#pragma unroll
    for (int n = 0; n < 4; ++n) {
      int nt = (j0 >> 4) + n;
      b[n] = *reinterpret_cast<const bf16x8*>(W2s + ((size_t)(nt * 8 + k0) * 64 + l) * 8);
    }
#pragma unroll
    for (int m = 0; m < 4; ++m)
#pragma unroll
      for (int n = 0; n < 4; ++n)
        acc[m][n] = __builtin_amdgcn_mfma_f32_16x16x32_bf16(a[m], b[n], acc[m][n], 0, 0, 0);
  }
  __syncthreads();   // all A2 reads done before overwrite

  // epilogue: e_new = e_old + d + bu2 -> scatter into A2 (bf16)
#pragma unroll
  for (int n = 0; n < 4; ++n) {
    int col = j0 + n * 16 + lr;
    float bv = bu2[col];
#pragma unroll
    for (int m = 0; m < 4; ++m)
#pragma unroll
      for (int r = 0; r < 4; ++r) {
        int row = m * 16 + lk * 4 + r;
        float eo = bs2f(A1s[row][64 + col]);
        A2s[row][col] = f2bs(eo + acc[m][n][r] + bv);
      }
  }
  __syncthreads();

  // coalesced store back to e
  for (int t = tid; t < MT * 32; t += 256) {
    int p = t >> 5, cc = t & 31;
    *reinterpret_cast<uint4*>(&e[(size_t)(base + p) * HDIM + cc * 8]) =
        *reinterpret_cast<const uint4*>(&A2s[p][cc * 8]);
  }
}

// ---- SGFormer q,k,v projections + per-head L2 normalization -------------------------
__global__ void k_sg_qkv(const float* __restrict__ x, const float* __restrict__ Wq,
                         const float* __restrict__ Wk, const float* __restrict__ Wv,
                         bf16* __restrict__ qs, bf16* __restrict__ ks,
                         bf16* __restrict__ vv) {
  int j = threadIdx.x;
  int hb = j & ~31;
  __shared__ float xs[HDIM], qq[HDIM], kk[HDIM];
  for (int n = blockIdx.x; n < NN; n += gridDim.x) {
    xs[j] = x[(size_t)n * HDIM + j];
    __syncthreads();
    float q = 0.f, k = 0.f, v = 0.f;
#pragma unroll 8
    for (int d = 0; d < HDIM; ++d) {
      float xv = xs[d];
      q += xv * Wq[d * HDIM + j];
      k += xv * Wk[d * HDIM + j];
      v += xv * Wv[d * HDIM + j];
    }
    qq[j] = q * q; kk[j] = k * k;
    __syncthreads();
    float qn = 0.f, kn = 0.f;
#pragma unroll
    for (int c = 0; c < CH; ++c) { qn += qq[hb + c]; kn += kk[hb + c]; }
    qs[(size_t)n * HDIM + j] = f2b(q / (sqrtf(qn) + 1e-6f));
    ks[(size_t)n * HDIM + j] = f2b(k / (sqrtf(kn) + 1e-6f));
    vv[(size_t)n * HDIM + j] = f2b(v);
    __syncthreads();
  }
}

// ---- kv[h][c][d] = sum_n ks[n,h,c]*v[n,h,d] ; ksum[h][c] = sum_n ks[n,h,c] ----------
__global__ void k_sg_kv(const bf16* __restrict__ ks, const bf16* __restrict__ vv,
                        float* __restrict__ kv, float* __restrict__ ksum) {
  int t = threadIdx.x;
  int h = t >> 5, c = t & 31;
  float kvloc[CH];
  float ksl = 0.f;
#pragma unroll
  for (int d = 0; d < CH; ++d) kvloc[d] = 0.f;
  __shared__ float krow[HDIM], vrow[HDIM];
  for (int n = blockIdx.x; n < NN; n += gridDim.x) {
    krow[t] = b2f(ks[(size_t)n * HDIM + t]);
    vrow[t] = b2f(vv[(size_t)n * HDIM + t]);
    __syncthreads();
    float kc = krow[h * CH + c];
    ksl += kc;
#pragma unroll
    for (int d = 0; d < CH; ++d) kvloc[d] += kc * vrow[h * CH + d];
    __syncthreads();
  }
#pragma unroll
  for (int d = 0; d < CH; ++d) atomicAdd(&kv[(h * CH + c) * CH + d], kvloc[d]);
  atomicAdd(&ksum[h * CH + c], ksl);
}

// ---- trans = mean_h((qs@kv + N*v)/(qs·ksum + N)) ; out = LN(a*x + (1-a)*trans) ------
__global__ void k_sg_final(const bf16* __restrict__ qs, const bf16* __restrict__ vv,
                           const float* __restrict__ kv, const float* __restrict__ ksum,
                           const float* __restrict__ xg, const float* __restrict__ alphap,
                           const float* __restrict__ cng, const float* __restrict__ cnb,
                           float* __restrict__ out) {
  int t = threadIdx.x;
  int d = t & 31, sub = t >> 5;
  __shared__ float qrow[8][HDIM];
  __shared__ float crow[8][CH];
  int n = blockIdx.x * 8 + sub;
  for (int tt = t; tt < 8 * HDIM; tt += 256) {
    int p = tt >> 8, k = tt & 255;
    int n2 = blockIdx.x * 8 + p;
    if (n2 < NN) qrow[p][k] = b2f(qs[(size_t)n2 * HDIM + k]);
  }
  __syncthreads();
  float alpha = 1.f / (1.f + expf(-alphap[0]));
  const float Nf = (float)NN;
  float comb = 0.f;
  if (n < NN) {
    float acc = 0.f;
#pragma unroll
    for (int h = 0; h < NH; ++h) {
      float nm = 0.f, dp = 0.f;
#pragma unroll 8
      for (int c = 0; c < CH; ++c) {
        float qv = qrow[sub][h * CH + c];
        nm += qv * kv[(h * CH + c) * CH + d];
        dp += qv * ksum[h * CH + c];
      }
      nm += Nf * b2f(vv[(size_t)n * HDIM + h * CH + d]);
      acc += nm / (dp + Nf);
    }
    float trans = acc * (1.f / NH);
    comb = alpha * xg[(size_t)n * CH + d] + (1.f - alpha) * trans;
    crow[sub][d] = comb;
  }
  __syncthreads();
  if (n < NN) {
    float mu = 0.f;
#pragma unroll
    for (int k = 0; k < CH; ++k) mu += crow[sub][k];
    mu *= (1.f / CH);
    float var = 0.f;
#pragma unroll
    for (int k = 0; k < CH; ++k) { float dv = crow[sub][k] - mu; var += dv * dv; }
    var *= (1.f / CH);
    float o = (comb - mu) * rsqrtf(var + 1e-5f) * cng[d] + cnb[d];
    out[(size_t)n * CH + d] = o;
  }
}

extern "C" void kernel_launch(void* const* d_in, const int* in_sizes, int n_in,
                              void* d_out, int out_size, void* d_ws, size_t ws_size,
                              hipStream_t stream) {
  const float* mesh  = (const float*)d_in[0];
  const int*   eidx  = (const int*)d_in[1];
  const float* eattr = (const float*)d_in[2];
  const float* epW   = (const float*)d_in[3];
  const float* epb   = (const float*)d_in[4];
  const float* Wl0   = (const float*)d_in[5];
  const float* Wr0   = (const float*)d_in[6];
  const float* WlL   = (const float*)d_in[7];
  const float* WrL   = (const float*)d_in[8];
  const float* We0   = (const float*)d_in[9];
  const float* WeL   = (const float*)d_in[10];
  const float* att0  = (const float*)d_in[11];
  const float* attL  = (const float*)d_in[12];
  const float* Wres0 = (const float*)d_in[13];
  const float* WresL = (const float*)d_in[14];
  const float* bn0   = (const float*)d_in[15];
  const float* bnL   = (const float*)d_in[16];
  const float* Wu1_0 = (const float*)d_in[17];
  const float* Wu1L  = (const float*)d_in[18];
  const float* bu1_0 = (const float*)d_in[19];
  const float* bu1L  = (const float*)d_in[20];
  const float* Wu2_0 = (const float*)d_in[21];
  const float* Wu2L  = (const float*)d_in[22];
  const float* bu2_0 = (const float*)d_in[23];
  const float* bu2L  = (const float*)d_in[24];
  const float* lng   = (const float*)d_in[25];
  const float* lnb   = (const float*)d_in[26];
  const float* Wq    = (const float*)d_in[27];
  const float* Wk    = (const float*)d_in[28];
  const float* Wv    = (const float*)d_in[29];
  const float* alphap= (const float*)d_in[30];
  const float* cng   = (const float*)d_in[31];
  const float* cnb   = (const float*)d_in[32];

  const int* src = eidx;
  const int* dst = eidx + NE;

  char* base = (char*)d_ws;
  size_t o = 0;
  auto alloc = [&](size_t bytes) -> char* {
    o = (o + 255) & ~(size_t)255;
    char* p = base + o;
    o += bytes;
    return p;
  };
  bf16* e    = (bf16*)alloc((size_t)NE * HDIM * 2);
  bf16* xl   = (bf16*)alloc((size_t)NN * HDIM * 2);   // reused: qs
  bf16* xr   = (bf16*)alloc((size_t)NN * HDIM * 2);   // reused: ks
  float* agg = (float*)alloc((size_t)NN * HDIM * 4);  // reused: vv (bf16)
  float* sbuf= (float*)alloc((size_t)NE * NH * 4);
  float* den = (float*)alloc((size_t)NN * NH * 4);
  float* xa  = (float*)alloc((size_t)NN * CH * 4);
  float* xb  = (float*)alloc((size_t)NN * CH * 4);
  float* xc  = (float*)alloc((size_t)NN * CH * 4);
  float* kv  = (float*)alloc(NH * CH * CH * 4);
  float* ksum= (float*)alloc(NH * CH * 4);
  unsigned short* w1s = (unsigned short*)alloc((size_t)3 * 320 * 256 * 2);
  unsigned short* w2s = (unsigned short*)alloc((size_t)3 * 256 * 256 * 2);
  if (ws_size < o) return;   // fail cleanly if ws too small

  // pre-swizzle edge-MLP weights (layers 0..2 only; layer 3's edge update is dead)
  for (int i = 0; i < 3; ++i) {
    const float* W1 = (i == 0) ? Wu1_0 : Wu1L + (size_t)(i - 1) * 320 * 256;
    const float* W2 = (i == 0) ? Wu2_0 : Wu2L + (size_t)(i - 1) * 256 * 256;
    k_swz_w<320><<<320, 256, 0, stream>>>(W1, w1s + (size_t)i * 320 * 256);
    k_swz_w<256><<<256, 256, 0, stream>>>(W2, w2s + (size_t)i * 256 * 256);
  }

  k_edge_proj<<<16384, 256, 0, stream>>>(eattr, epW, epb, e);

  const float* xin = mesh;
  float* post = xb;
  for (int l = 0; l < 4; ++l) {
    const float *Wl_p, *Wr_p, *We_p, *att_p, *Wres_p, *bn_p, *bu1_p, *bu2_p;
    if (l == 0) {
      Wl_p = Wl0; Wr_p = Wr0; We_p = We0; att_p = att0; Wres_p = Wres0; bn_p = bn0;
      bu1_p = bu1_0; bu2_p = bu2_0;
    } else {
      int i = l - 1;
      Wl_p = WlL + (size_t)i * CH * HDIM;
      Wr_p = WrL + (size_t)i * CH * HDIM;
      We_p = WeL + (size_t)i * HDIM * HDIM;
      att_p = attL + (size_t)i * HDIM;
      Wres_p = WresL + (size_t)i * CH * CH;
      bn_p = bnL + (size_t)i * CH;
      bu1_p = bu1L + (size_t)i * HDIM;
      bu2_p = bu2L + (size_t)i * HDIM;
    }

    if (l == 0) k_node_proj<HDIM><<<4096, 256, 0, stream>>>(xin, Wl_p, Wr_p, xl, xr);
    else        k_node_proj<CH>  <<<4096, 256, 0, stream>>>(xin, Wl_p, Wr_p, xl, xr);

    k_clear<<<2048, 256, 0, stream>>>(agg, den);
    k_edge_score<<<NE / EPB, 256, 0, stream>>>(e, We_p, xl, xr, att_p, src, dst, sbuf);
    k_edge_soft_agg<<<8192, 256, 0, stream>>>(sbuf, xl, src, dst, agg, den);

    if (l == 0)
      k_node_out<HDIM, true><<<(NN + 7) / 8, 256, 0, stream>>>(agg, den, xin, Wres_p, bn_p,
                                                               lng, lnb, xa, post);
    else if (l < 3)
      k_node_out<CH, true><<<(NN + 7) / 8, 256, 0, stream>>>(agg, den, xin, Wres_p, bn_p,
                                                             lng + (size_t)l * CH,
                                                             lnb + (size_t)l * CH, xa, post);
    else
      k_node_out<CH, false><<<(NN + 7) / 8, 256, 0, stream>>>(agg, den, xin, Wres_p, bn_p,
                                                              nullptr, nullptr, xa, nullptr);

    if (l < 3)
      k_edge_mlp_mfma<<<NE / MT, 256, 0, stream>>>(e, xa, src, dst,
                                                   w1s + (size_t)l * 320 * 256, bu1_p,
                                                   w2s + (size_t)l * 256 * 256, bu2_p);

    xin = post;
    post = (post == xb) ? xc : xb;
  }
  // final GAT output (no LN) is in xa

  bf16* vv = (bf16*)agg;
  k_sg_qkv<<<4096, 256, 0, stream>>>(mesh, Wq, Wk, Wv, xl, xr, vv);
  k_zero<<<(NH * CH * CH + NH * CH + 255) / 256, 256, 0, stream>>>(kv, NH * CH * CH + NH * CH);
  k_sg_kv<<<256, 256, 0, stream>>>(xr, vv, kv, ksum);
  k_sg_final<<<(NN + 7) / 8, 256, 0, stream>>>(xl, vv, kv, ksum, xa, alphap, cng, cnb,
                                               (float*)d_out);
}

// Round 6
// 3265.586 us; speedup vs baseline: 3.4090x; 2.3731x over previous
//
#include <hip/hip_runtime.h>
#include <hip/hip_bf16.h>
#include <math.h>

typedef __hip_bfloat16 bf16;
typedef __attribute__((ext_vector_type(8))) __bf16 bf16x8;
typedef __attribute__((ext_vector_type(4))) float f32x4;

#define NN 40962
#define NE 245760
#define HDIM 256
#define NH 8
#define CH 32

#define MT 64    // rows per block in MFMA kernels

__device__ __forceinline__ float b2f(bf16 v) { return __bfloat162float(v); }
__device__ __forceinline__ bf16 f2b(float v) { return __float2bfloat16(v); }
__device__ __forceinline__ unsigned short f2bs(float v) {
  bf16 b = __float2bfloat16(v);
  return __builtin_bit_cast(unsigned short, b);
}
__device__ __forceinline__ float bs2f(unsigned short u) {
  return __bfloat162float(__builtin_bit_cast(bf16, u));
}

// ---- edge input projection: e[ed][j] = b[j] + sum_k attr[ed][k] * W[k][j] ----------
__global__ void k_edge_proj(const float* __restrict__ attr, const float* __restrict__ W,
                            const float* __restrict__ b, bf16* __restrict__ e) {
  long long i0 = (long long)blockIdx.x * blockDim.x + threadIdx.x;
  long long total = (long long)NE * HDIM;
  long long stride = (long long)gridDim.x * blockDim.x;
  for (long long t = i0; t < total; t += stride) {
    int ed = (int)(t >> 8);
    int j  = (int)(t & 255);
    float acc = b[j];
#pragma unroll
    for (int k = 0; k < 16; ++k) acc += attr[ed * 16 + k] * W[k * HDIM + j];
    e[t] = f2b(acc);
  }
}

// ---- small node projections (layers 1..3): xl = x@Wl, xr = x@Wr  (in_ch = CH) ------
template <int ID>
__global__ void k_node_proj(const float* __restrict__ x, const float* __restrict__ Wl,
                            const float* __restrict__ Wr, bf16* __restrict__ xl,
                            bf16* __restrict__ xr) {
  int j = threadIdx.x;
  __shared__ float xs[ID];
  for (int n = blockIdx.x; n < NN; n += gridDim.x) {
    if (j < ID) xs[j] = x[(size_t)n * ID + j];
    __syncthreads();
    float al = 0.f, ar = 0.f;
#pragma unroll 8
    for (int k = 0; k < ID; ++k) {
      float xv = xs[k];
      al += xv * Wl[k * HDIM + j];
      ar += xv * Wr[k * HDIM + j];
    }
    xl[(size_t)n * HDIM + j] = f2b(al);
    xr[(size_t)n * HDIM + j] = f2b(ar);
    __syncthreads();
  }
}

// ---- clear agg [NN*HDIM] and den [NN*NH] --------------------------------------------
__global__ void k_clear(float* __restrict__ agg, float* __restrict__ den) {
  int i = blockIdx.x * blockDim.x + threadIdx.x;
  int stride = gridDim.x * blockDim.x;
  for (int t = i; t < NN * HDIM; t += stride) agg[t] = 0.f;
  for (int t = i; t < NN * NH; t += stride) den[t] = 0.f;
}

__global__ void k_zero(float* __restrict__ p, int n) {
  int i = blockIdx.x * blockDim.x + threadIdx.x;
  if (i < n) p[i] = 0.f;
}

// ---- weight swizzle into MFMA B-fragment-major layout (bf16), K-dim template --------
// out[(((n0*(K/32) + k0)*64 + l)*8 + i] = bf16(W[k0*32 + (l>>4)*8 + i][n0*16 + (l&15)])
template <int K>
__global__ void k_swz_w(const float* __restrict__ W, unsigned short* __restrict__ out) {
  int t = blockIdx.x * 256 + threadIdx.x;
  if (t >= K * 256) return;
  int i  = t & 7;
  int l  = (t >> 3) & 63;
  int k0 = (t >> 9) % (K / 32);
  int n0 = t / (512 * (K / 32));
  int k = k0 * 32 + (l >> 4) * 8 + i;
  int n = n0 * 16 + (l & 15);
  out[t] = f2bs(W[k * 256 + n]);
}

// ---- fused swizzle of the nine 256x256 weights (We x4, Wl0, Wr0, Wq, Wk, Wv) --------
__global__ void k_swz_all(const float* __restrict__ We0, const float* __restrict__ WeL,
                          const float* __restrict__ Wl0, const float* __restrict__ Wr0,
                          const float* __restrict__ Wq, const float* __restrict__ Wk,
                          const float* __restrict__ Wv, unsigned short* __restrict__ dst) {
  int mat = blockIdx.x >> 8;                       // 0..8
  int t = ((blockIdx.x & 255) << 8) | threadIdx.x; // 0..65535
  const float* W;
  switch (mat) {
    case 0: W = We0; break;
    case 1: W = WeL; break;
    case 2: W = WeL + 65536; break;
    case 3: W = WeL + 131072; break;
    case 4: W = Wl0; break;
    case 5: W = Wr0; break;
    case 6: W = Wq; break;
    case 7: W = Wk; break;
    default: W = Wv; break;
  }
  int i  = t & 7;
  int l  = (t >> 3) & 63;
  int k0 = (t >> 9) & 7;
  int n0 = t >> 12;
  int k = k0 * 32 + (l >> 4) * 8 + i;
  int n = n0 * 16 + (l & 15);
  dst[(size_t)mat * 65536 + t] = f2bs(W[k * 256 + n]);
}

// ---- MFMA edge score: ee = e@We ; s = sum_c lrelu(ee + xl[src]+xr[dst]) * att -------
// writes sx = exp(s). 64 edges/block, 4 waves x 64-col stripes.
__global__ __launch_bounds__(256) void k_edge_score_mfma(
    const bf16* __restrict__ e, const unsigned short* __restrict__ Wes,
    const bf16* __restrict__ xl, const bf16* __restrict__ xr,
    const float* __restrict__ att, const int* __restrict__ src,
    const int* __restrict__ dst, float* __restrict__ sx) {
  __shared__ unsigned short Ae[MT][264];
  __shared__ unsigned short Xs[MT][264];
  __shared__ float attS[HDIM];
  __shared__ int sidx[MT], didx[MT];
  int tid = threadIdx.x, l = tid & 63, w = tid >> 6;
  int lr = l & 15, lk = l >> 4;
  int base = blockIdx.x * MT;                    // NE % 64 == 0
  attS[tid] = att[tid];
  if (tid < MT) sidx[tid] = src[base + tid];
  else if (tid < 2 * MT) didx[tid - MT] = dst[base + tid - MT];
  __syncthreads();
  // stage e rows
  for (int t = tid; t < MT * 32; t += 256) {
    int p = t >> 5, c = t & 31;
    *reinterpret_cast<uint4*>(&Ae[p][c * 8]) =
        *reinterpret_cast<const uint4*>(&e[(size_t)(base + p) * HDIM + c * 8]);
  }
  // stage xsum = xl[src] + xr[dst]
  for (int t = tid; t < MT * 32; t += 256) {
    int p = t >> 5, c = t & 31;
    uint4 ul = *reinterpret_cast<const uint4*>(&xl[(size_t)sidx[p] * HDIM + c * 8]);
    uint4 ur = *reinterpret_cast<const uint4*>(&xr[(size_t)didx[p] * HDIM + c * 8]);
    const unsigned short* al = (const unsigned short*)&ul;
    const unsigned short* ar = (const unsigned short*)&ur;
    unsigned short ov[8];
#pragma unroll
    for (int i = 0; i < 8; ++i) ov[i] = f2bs(bs2f(al[i]) + bs2f(ar[i]));
    *reinterpret_cast<uint4*>(&Xs[p][c * 8]) = *reinterpret_cast<const uint4*>(ov);
  }
  __syncthreads();

  int j0 = w * 64;
  f32x4 acc[4][4];
#pragma unroll
  for (int m = 0; m < 4; ++m)
#pragma unroll
    for (int n = 0; n < 4; ++n)
#pragma unroll
      for (int r = 0; r < 4; ++r) acc[m][n][r] = 0.f;
  for (int k0 = 0; k0 < 8; ++k0) {
    bf16x8 a[4], b[4];
#pragma unroll
    for (int m = 0; m < 4; ++m)
      a[m] = *reinterpret_cast<const bf16x8*>(&Ae[m * 16 + lr][k0 * 32 + lk * 8]);
#pragma unroll
    for (int n = 0; n < 4; ++n) {
      int nt = (j0 >> 4) + n;
      b[n] = *reinterpret_cast<const bf16x8*>(Wes + ((size_t)(nt * 8 + k0) * 64 + l) * 8);
    }
#pragma unroll
    for (int m = 0; m < 4; ++m)
#pragma unroll
      for (int n = 0; n < 4; ++n)
        acc[m][n] = __builtin_amdgcn_mfma_f32_16x16x32_bf16(a[m], b[n], acc[m][n], 0, 0, 0);
  }
  // epilogue: lrelu(ee + xsum) * att -> scoreboard (overwrite Xs)
#pragma unroll
  for (int n = 0; n < 4; ++n) {
    int col = j0 + n * 16 + lr;
    float av = attS[col];
#pragma unroll
    for (int m = 0; m < 4; ++m)
#pragma unroll
      for (int r = 0; r < 4; ++r) {
        int row = m * 16 + lk * 4 + r;
        float mm = acc[m][n][r] + bs2f(Xs[row][col]);
        mm = (mm > 0.f) ? mm : 0.2f * mm;
        Xs[row][col] = f2bs(mm * av);
      }
  }
  __syncthreads();
  // head-sums -> exp(s)
  for (int pair = tid; pair < MT * NH; pair += 256) {
    int ed = pair >> 3, h = pair & 7;
    float s = 0.f;
#pragma unroll
    for (int c = 0; c < CH; ++c) s += bs2f(Xs[ed][h * CH + c]);
    sx[(size_t)(base + ed) * NH + h] = expf(s);
  }
}

// ---- ex (pre-exp'd) ; agg[dst] += ex*xl[src] ; den[dst] += ex -----------------------
__global__ void k_edge_soft_agg(const float* __restrict__ s, const bf16* __restrict__ xl,
                                const int* __restrict__ src, const int* __restrict__ dst,
                                float* __restrict__ agg, float* __restrict__ den) {
  int j = threadIdx.x;
  int h = j >> 5;
  for (int ed = blockIdx.x; ed < NE; ed += gridDim.x) {
    int sn = src[ed], dn = dst[ed];
    float ex = s[ed * NH + h];
    atomicAdd(&agg[(size_t)dn * HDIM + j], ex * b2f(xl[(size_t)sn * HDIM + j]));
    if ((j & 31) == 0) atomicAdd(&den[dn * NH + h], ex);
  }
}

// ---- out = mean_h(agg/den) + x@Wres + bn ; write pre-LN; optional LN ----------------
template <int ID, bool LN>
__global__ void k_node_out(const float* __restrict__ agg, const float* __restrict__ den,
                           const float* __restrict__ x, const float* __restrict__ Wres,
                           const float* __restrict__ bn, const float* __restrict__ lng,
                           const float* __restrict__ lnb, float* __restrict__ xpre,
                           float* __restrict__ xpost) {
  int t = threadIdx.x;
  int c = t & 31, sub = t >> 5;
  __shared__ float onode[8][CH];
  int n = blockIdx.x * 8 + sub;
  float o = 0.f;
  if (n < NN) {
#pragma unroll
    for (int h = 0; h < NH; ++h)
      o += agg[(size_t)n * HDIM + h * CH + c] / (den[n * NH + h] + 1e-16f);
    o *= (1.f / NH);
    float r = 0.f;
    for (int k = 0; k < ID; ++k) r += x[(size_t)n * ID + k] * Wres[k * CH + c];
    o += r + bn[c];
    xpre[(size_t)n * CH + c] = o;
    onode[sub][c] = o;
  }
  __syncthreads();
  if (LN && n < NN) {
    float mu = 0.f;
#pragma unroll
    for (int k = 0; k < CH; ++k) mu += onode[sub][k];
    mu *= (1.f / CH);
    float var = 0.f;
#pragma unroll
    for (int k = 0; k < CH; ++k) { float d = onode[sub][k] - mu; var += d * d; }
    var *= (1.f / CH);
    xpost[(size_t)n * CH + c] = (o - mu) * rsqrtf(var + 1e-5f) * lng[c] + lnb[c];
  }
}

// ---- MFMA residual edge MLP: e += gelu([out_s,out_d,e]@Wu1+bu1)@Wu2 + bu2 -----------
__global__ __launch_bounds__(256) void k_edge_mlp_mfma(
    bf16* __restrict__ e, const float* __restrict__ xo,
    const int* __restrict__ src, const int* __restrict__ dst,
    const unsigned short* __restrict__ W1s, const float* __restrict__ bu1,
    const unsigned short* __restrict__ W2s, const float* __restrict__ bu2) {
  __shared__ unsigned short A1s[MT][328];
  __shared__ unsigned short A2s[MT][264];
  __shared__ int sidx[MT], didx[MT];
  int tid = threadIdx.x;
  int l = tid & 63;
  int wave = tid >> 6;
  int base = blockIdx.x * MT;
  int lr = l & 15;
  int lk = l >> 4;

  if (tid < MT) sidx[tid] = src[base + tid];
  else if (tid < 2 * MT) didx[tid - MT] = dst[base + tid - MT];
  __syncthreads();

  for (int t = tid; t < MT * 32; t += 256) {
    int p = t >> 5, cc = t & 31;
    uint4 v = *reinterpret_cast<const uint4*>(&e[(size_t)(base + p) * HDIM + cc * 8]);
    *reinterpret_cast<uint4*>(&A1s[p][64 + cc * 8]) = v;
  }
  for (int t = tid; t < MT * 64; t += 256) {
    int p = t >> 6, c = t & 63;
    float v = (c < CH) ? xo[(size_t)sidx[p] * CH + c]
                       : xo[(size_t)didx[p] * CH + (c - CH)];
    A1s[p][c] = f2bs(v);
  }
  __syncthreads();

  int j0 = wave * 64;

  f32x4 acc[4][4];
#pragma unroll
  for (int m = 0; m < 4; ++m)
#pragma unroll
    for (int n = 0; n < 4; ++n)
#pragma unroll
      for (int r = 0; r < 4; ++r) acc[m][n][r] = 0.f;

  for (int k0 = 0; k0 < 10; ++k0) {
    bf16x8 a[4], b[4];
#pragma unroll
    for (int m = 0; m < 4; ++m)
      a[m] = *reinterpret_cast<const bf16x8*>(&A1s[m * 16 + lr][k0 * 32 + lk * 8]);
#pragma unroll
    for (int n = 0; n < 4; ++n) {
      int nt = (j0 >> 4) + n;
      b[n] = *reinterpret_cast<const bf16x8*>(W1s + ((size_t)(nt * 10 + k0) * 64 + l) * 8);
    }
#pragma unroll
    for (int m = 0; m < 4; ++m)
#pragma unroll
      for (int n = 0; n < 4; ++n)
        acc[m][n] = __builtin_amdgcn_mfma_f32_16x16x32_bf16(a[m], b[n], acc[m][n], 0, 0, 0);
  }

#pragma unroll
  for (int n = 0; n < 4; ++n) {
    float bv = bu1[j0 + n * 16 + lr];
#pragma unroll
    for (int m = 0; m < 4; ++m)
#pragma unroll
      for (int r = 0; r < 4; ++r) {
        float xv = acc[m][n][r] + bv;
        float tnh = tanhf(0.7978845608028654f * (xv + 0.044715f * xv * xv * xv));
        float g = 0.5f * xv * (1.f + tnh);
        A2s[m * 16 + lk * 4 + r][j0 + n * 16 + lr] = f2bs(g);
      }
  }
  __syncthreads();

#pragma unroll
  for (int m = 0; m < 4; ++m)
#pragma unroll
    for (int n = 0; n < 4; ++n)
#pragma unroll
      for (int r = 0; r < 4; ++r) acc[m][n][r] = 0.f;

  for (int k0 = 0; k0 < 8; ++k0) {
    bf16x8 a[4], b[4];
#pragma unroll
    for (int m = 0; m < 4; ++m)
      a[m] = *reinterpret_cast<const bf16x8*>(&A2s[m * 16 + lr][k0 * 32 + lk * 8]);
#pragma unroll
    for (int n = 0; n < 4; ++n) {
      int nt = (j0 >> 4) + n;
      b[n] = *reinterpret_cast<const bf16x8*>(W2s + ((size_t)(nt * 8 + k0) * 64 + l) * 8);
    }
#pragma unroll
    for (int m = 0; m < 4; ++m)
#pragma unroll
      for (int n = 0; n < 4; ++n)
        acc[m][n] = __builtin_amdgcn_mfma_f32_16x16x32_bf16(a[m], b[n], acc[m][n], 0, 0, 0);
  }
  __syncthreads();

#pragma unroll
  for (int n = 0; n < 4; ++n) {
    int col = j0 + n * 16 + lr;
    float bv = bu2[col];
#pragma unroll
    for (int m = 0; m < 4; ++m)
#pragma unroll
      for (int r = 0; r < 4; ++r) {
        int row = m * 16 + lk * 4 + r;
        float eo = bs2f(A1s[row][64 + col]);
        A2s[row][col] = f2bs(eo + acc[m][n][r] + bv);
      }
  }
  __syncthreads();

  for (int t = tid; t < MT * 32; t += 256) {
    int p = t >> 5, cc = t & 31;
    *reinterpret_cast<uint4*>(&e[(size_t)(base + p) * HDIM + cc * 8]) =
        *reinterpret_cast<const uint4*>(&A2s[p][cc * 8]);
  }
}

// ---- MFMA layer-0 node projection: xl = mesh@Wl0, xr = mesh@Wr0 ---------------------
__global__ __launch_bounds__(256) void k_node_proj0_mfma(
    const float* __restrict__ x, const unsigned short* __restrict__ Wls,
    const unsigned short* __restrict__ Wrs, bf16* __restrict__ xl,
    bf16* __restrict__ xr) {
  __shared__ unsigned short A[MT][264];
  __shared__ unsigned short O[MT][264];
  int tid = threadIdx.x, l = tid & 63, w = tid >> 6;
  int lr = l & 15, lk = l >> 4;
  int base = blockIdx.x * MT;
  for (int t = tid; t < MT * 64; t += 256) {
    int p = t >> 6, c = t & 63;
    int row = base + p; if (row >= NN) row = NN - 1;
    float4 v = *reinterpret_cast<const float4*>(&x[(size_t)row * HDIM + c * 4]);
    unsigned short tmp[4] = {f2bs(v.x), f2bs(v.y), f2bs(v.z), f2bs(v.w)};
    *reinterpret_cast<uint2*>(&A[p][c * 4]) = *reinterpret_cast<const uint2*>(tmp);
  }
  __syncthreads();
  int j0 = w * 64;
#pragma unroll
  for (int mtx = 0; mtx < 2; ++mtx) {
    const unsigned short* Ws = (mtx == 0) ? Wls : Wrs;
    bf16* outp = (mtx == 0) ? xl : xr;
    f32x4 acc[4][4];
#pragma unroll
    for (int m = 0; m < 4; ++m)
#pragma unroll
      for (int n = 0; n < 4; ++n)
#pragma unroll
        for (int r = 0; r < 4; ++r) acc[m][n][r] = 0.f;
    for (int k0 = 0; k0 < 8; ++k0) {
      bf16x8 a[4], b[4];
#pragma unroll
      for (int m = 0; m < 4; ++m)
        a[m] = *reinterpret_cast<const bf16x8*>(&A[m * 16 + lr][k0 * 32 + lk * 8]);
#pragma unroll
      for (int n = 0; n < 4; ++n) {
        int nt = (j0 >> 4) + n;
        b[n] = *reinterpret_cast<const bf16x8*>(Ws + ((size_t)(nt * 8 + k0) * 64 + l) * 8);
      }
#pragma unroll
      for (int m = 0; m < 4; ++m)
#pragma unroll
        for (int n = 0; n < 4; ++n)
          acc[m][n] = __builtin_amdgcn_mfma_f32_16x16x32_bf16(a[m], b[n], acc[m][n], 0, 0, 0);
    }
#pragma unroll
    for (int n = 0; n < 4; ++n)
#pragma unroll
      for (int m = 0; m < 4; ++m)
#pragma unroll
        for (int r = 0; r < 4; ++r)
          O[m * 16 + lk * 4 + r][j0 + n * 16 + lr] = f2bs(acc[m][n][r]);
    __syncthreads();
    for (int t = tid; t < MT * 32; t += 256) {
      int p = t >> 5, c = t & 31;
      if (base + p < NN)
        *reinterpret_cast<uint4*>(&outp[(size_t)(base + p) * HDIM + c * 8]) =
            *reinterpret_cast<const uint4*>(&O[p][c * 8]);
    }
    __syncthreads();
  }
}

// ---- MFMA SGFormer qkv: q,k,v = mesh @ Wq|Wk|Wv ; q,k L2-normalized per head --------
__global__ __launch_bounds__(256) void k_sg_qkv_mfma(
    const float* __restrict__ x, const unsigned short* __restrict__ Wqs,
    const unsigned short* __restrict__ Wks, const unsigned short* __restrict__ Wvs,
    bf16* __restrict__ qs, bf16* __restrict__ ks, bf16* __restrict__ vv) {
  __shared__ unsigned short A[MT][264];
  __shared__ unsigned short O[MT][264];
  int tid = threadIdx.x, l = tid & 63, w = tid >> 6;
  int lr = l & 15, lk = l >> 4;
  int base = blockIdx.x * MT;
  for (int t = tid; t < MT * 64; t += 256) {
    int p = t >> 6, c = t & 63;
    int row = base + p; if (row >= NN) row = NN - 1;
    float4 v = *reinterpret_cast<const float4*>(&x[(size_t)row * HDIM + c * 4]);
    unsigned short tmp[4] = {f2bs(v.x), f2bs(v.y), f2bs(v.z), f2bs(v.w)};
    *reinterpret_cast<uint2*>(&A[p][c * 4]) = *reinterpret_cast<const uint2*>(tmp);
  }
  __syncthreads();
  int j0 = w * 64;
#pragma unroll
  for (int mtx = 0; mtx < 3; ++mtx) {
    const unsigned short* Ws = (mtx == 0) ? Wqs : (mtx == 1) ? Wks : Wvs;
    bf16* outp = (mtx == 0) ? qs : (mtx == 1) ? ks : vv;
    f32x4 acc[4][4];
#pragma unroll
    for (int m = 0; m < 4; ++m)
#pragma unroll
      for (int n = 0; n < 4; ++n)
#pragma unroll
        for (int r = 0; r < 4; ++r) acc[m][n][r] = 0.f;
    for (int k0 = 0; k0 < 8; ++k0) {
      bf16x8 a[4], b[4];
#pragma unroll
      for (int m = 0; m < 4; ++m)
        a[m] = *reinterpret_cast<const bf16x8*>(&A[m * 16 + lr][k0 * 32 + lk * 8]);
#pragma unroll
      for (int n = 0; n < 4; ++n) {
        int nt = (j0 >> 4) + n;
        b[n] = *reinterpret_cast<const bf16x8*>(Ws + ((size_t)(nt * 8 + k0) * 64 + l) * 8);
      }
#pragma unroll
      for (int m = 0; m < 4; ++m)
#pragma unroll
        for (int n = 0; n < 4; ++n)
          acc[m][n] = __builtin_amdgcn_mfma_f32_16x16x32_bf16(a[m], b[n], acc[m][n], 0, 0, 0);
    }
    if (mtx < 2) {
      // per-head L2 norm: head A = cols [j0, j0+32) (n=0,1); head B = n=2,3.
      float pa[4][4], pb[4][4];
#pragma unroll
      for (int m = 0; m < 4; ++m)
#pragma unroll
        for (int r = 0; r < 4; ++r) {
          pa[m][r] = acc[m][0][r] * acc[m][0][r] + acc[m][1][r] * acc[m][1][r];
          pb[m][r] = acc[m][2][r] * acc[m][2][r] + acc[m][3][r] * acc[m][3][r];
        }
#pragma unroll
      for (int off = 1; off < 16; off <<= 1) {
#pragma unroll
        for (int m = 0; m < 4; ++m)
#pragma unroll
          for (int r = 0; r < 4; ++r) {
            pa[m][r] += __shfl_xor(pa[m][r], off);
            pb[m][r] += __shfl_xor(pb[m][r], off);
          }
      }
#pragma unroll
      for (int m = 0; m < 4; ++m)
#pragma unroll
        for (int r = 0; r < 4; ++r) {
          float ra = 1.f / (sqrtf(pa[m][r]) + 1e-6f);
          float rb = 1.f / (sqrtf(pb[m][r]) + 1e-6f);
          acc[m][0][r] *= ra; acc[m][1][r] *= ra;
          acc[m][2][r] *= rb; acc[m][3][r] *= rb;
        }
    }
#pragma unroll
    for (int n = 0; n < 4; ++n)
#pragma unroll
      for (int m = 0; m < 4; ++m)
#pragma unroll
        for (int r = 0; r < 4; ++r)
          O[m * 16 + lk * 4 + r][j0 + n * 16 + lr] = f2bs(acc[m][n][r]);
    __syncthreads();
    for (int t = tid; t < MT * 32; t += 256) {
      int p = t >> 5, c = t & 31;
      if (base + p < NN)
        *reinterpret_cast<uint4*>(&outp[(size_t)(base + p) * HDIM + c * 8]) =
            *reinterpret_cast<const uint4*>(&O[p][c * 8]);
    }
    __syncthreads();
  }
}

// ---- kv[h][c][d] = sum_n ks[n,h,c]*v[n,h,d] ; ksum[h][c] = sum_n ks[n,h,c] ----------
__global__ void k_sg_kv(const bf16* __restrict__ ks, const bf16* __restrict__ vv,
                        float* __restrict__ kv, float* __restrict__ ksum) {
  int t = threadIdx.x;
  int h = t >> 5, c = t & 31;
  float kvloc[CH];
  float ksl = 0.f;
#pragma unroll
  for (int d = 0; d < CH; ++d) kvloc[d] = 0.f;
  __shared__ float krow[HDIM], vrow[HDIM];
  for (int n = blockIdx.x; n < NN; n += gridDim.x) {
    krow[t] = b2f(ks[(size_t)n * HDIM + t]);
    vrow[t] = b2f(vv[(size_t)n * HDIM + t]);
    __syncthreads();
    float kc = krow[h * CH + c];
    ksl += kc;
#pragma unroll
    for (int d = 0; d < CH; ++d) kvloc[d] += kc * vrow[h * CH + d];
    __syncthreads();
  }
#pragma unroll
  for (int d = 0; d < CH; ++d) atomicAdd(&kv[(h * CH + c) * CH + d], kvloc[d]);
  atomicAdd(&ksum[h * CH + c], ksl);
}

// ---- trans = mean_h((qs@kv + N*v)/(qs·ksum + N)) ; out = LN(a*x + (1-a)*trans) ------
__global__ void k_sg_final(const bf16* __restrict__ qs, const bf16* __restrict__ vv,
                           const float* __restrict__ kv, const float* __restrict__ ksum,
                           const float* __restrict__ xg, const float* __restrict__ alphap,
                           const float* __restrict__ cng, const float* __restrict__ cnb,
                           float* __restrict__ out) {
  int t = threadIdx.x;
  int d = t & 31, sub = t >> 5;
  __shared__ float qrow[8][HDIM];
  __shared__ float crow[8][CH];
  int n = blockIdx.x * 8 + sub;
  for (int tt = t; tt < 8 * HDIM; tt += 256) {
    int p = tt >> 8, k = tt & 255;
    int n2 = blockIdx.x * 8 + p;
    if (n2 < NN) qrow[p][k] = b2f(qs[(size_t)n2 * HDIM + k]);
  }
  __syncthreads();
  float alpha = 1.f / (1.f + expf(-alphap[0]));
  const float Nf = (float)NN;
  float comb = 0.f;
  if (n < NN) {
    float acc = 0.f;
#pragma unroll
    for (int h = 0; h < NH; ++h) {
      float nm = 0.f, dp = 0.f;
#pragma unroll 8
      for (int c = 0; c < CH; ++c) {
        float qv = qrow[sub][h * CH + c];
        nm += qv * kv[(h * CH + c) * CH + d];
        dp += qv * ksum[h * CH + c];
      }
      nm += Nf * b2f(vv[(size_t)n * HDIM + h * CH + d]);
      acc += nm / (dp + Nf);
    }
    float trans = acc * (1.f / NH);
    comb = alpha * xg[(size_t)n * CH + d] + (1.f - alpha) * trans;
    crow[sub][d] = comb;
  }
  __syncthreads();
  if (n < NN) {
    float mu = 0.f;
#pragma unroll
    for (int k = 0; k < CH; ++k) mu += crow[sub][k];
    mu *= (1.f / CH);
    float var = 0.f;
#pragma unroll
    for (int k = 0; k < CH; ++k) { float dv = crow[sub][k] - mu; var += dv * dv; }
    var *= (1.f / CH);
    float o = (comb - mu) * rsqrtf(var + 1e-5f) * cng[d] + cnb[d];
    out[(size_t)n * CH + d] = o;
  }
}

extern "C" void kernel_launch(void* const* d_in, const int* in_sizes, int n_in,
                              void* d_out, int out_size, void* d_ws, size_t ws_size,
                              hipStream_t stream) {
  const float* mesh  = (const float*)d_in[0];
  const int*   eidx  = (const int*)d_in[1];
  const float* eattr = (const float*)d_in[2];
  const float* epW   = (const float*)d_in[3];
  const float* epb   = (const float*)d_in[4];
  const float* Wl0   = (const float*)d_in[5];
  const float* Wr0   = (const float*)d_in[6];
  const float* WlL   = (const float*)d_in[7];
  const float* WrL   = (const float*)d_in[8];
  const float* We0   = (const float*)d_in[9];
  const float* WeL   = (const float*)d_in[10];
  const float* att0  = (const float*)d_in[11];
  const float* attL  = (const float*)d_in[12];
  const float* Wres0 = (const float*)d_in[13];
  const float* WresL = (const float*)d_in[14];
  const float* bn0   = (const float*)d_in[15];
  const float* bnL   = (const float*)d_in[16];
  const float* Wu1_0 = (const float*)d_in[17];
  const float* Wu1L  = (const float*)d_in[18];
  const float* bu1_0 = (const float*)d_in[19];
  const float* bu1L  = (const float*)d_in[20];
  const float* Wu2_0 = (const float*)d_in[21];
  const float* Wu2L  = (const float*)d_in[22];
  const float* bu2_0 = (const float*)d_in[23];
  const float* bu2L  = (const float*)d_in[24];
  const float* lng   = (const float*)d_in[25];
  const float* lnb   = (const float*)d_in[26];
  const float* Wq    = (const float*)d_in[27];
  const float* Wk    = (const float*)d_in[28];
  const float* Wv    = (const float*)d_in[29];
  const float* alphap= (const float*)d_in[30];
  const float* cng   = (const float*)d_in[31];
  const float* cnb   = (const float*)d_in[32];

  const int* src = eidx;
  const int* dst = eidx + NE;

  char* base = (char*)d_ws;
  size_t o = 0;
  auto alloc = [&](size_t bytes) -> char* {
    o = (o + 255) & ~(size_t)255;
    char* p = base + o;
    o += bytes;
    return p;
  };
  bf16* e    = (bf16*)alloc((size_t)NE * HDIM * 2);
  bf16* xl   = (bf16*)alloc((size_t)NN * HDIM * 2);   // reused: qs
  bf16* xr   = (bf16*)alloc((size_t)NN * HDIM * 2);   // reused: ks
  float* agg = (float*)alloc((size_t)NN * HDIM * 4);  // reused: vv (bf16)
  float* sbuf= (float*)alloc((size_t)NE * NH * 4);
  float* den = (float*)alloc((size_t)NN * NH * 4);
  float* xa  = (float*)alloc((size_t)NN * CH * 4);
  float* xb  = (float*)alloc((size_t)NN * CH * 4);
  float* xc  = (float*)alloc((size_t)NN * CH * 4);
  float* kv  = (float*)alloc(NH * CH * CH * 4);
  float* ksum= (float*)alloc(NH * CH * 4);
  unsigned short* w1s = (unsigned short*)alloc((size_t)3 * 320 * 256 * 2);
  unsigned short* w2s = (unsigned short*)alloc((size_t)3 * 256 * 256 * 2);
  unsigned short* wall= (unsigned short*)alloc((size_t)9 * 65536 * 2);
  if (ws_size < o) return;   // fail cleanly if ws too small

  // pre-swizzle weights
  for (int i = 0; i < 3; ++i) {
    const float* W1 = (i == 0) ? Wu1_0 : Wu1L + (size_t)(i - 1) * 320 * 256;
    const float* W2 = (i == 0) ? Wu2_0 : Wu2L + (size_t)(i - 1) * 256 * 256;
    k_swz_w<320><<<320, 256, 0, stream>>>(W1, w1s + (size_t)i * 320 * 256);
    k_swz_w<256><<<256, 256, 0, stream>>>(W2, w2s + (size_t)i * 256 * 256);
  }
  k_swz_all<<<9 * 256, 256, 0, stream>>>(We0, WeL, Wl0, Wr0, Wq, Wk, Wv, wall);

  k_edge_proj<<<16384, 256, 0, stream>>>(eattr, epW, epb, e);

  const float* xin = mesh;
  float* post = xb;
  for (int l = 0; l < 4; ++l) {
    const float *Wl_p, *Wr_p, *att_p, *Wres_p, *bn_p, *bu1_p, *bu2_p;
    if (l == 0) {
      Wl_p = Wl0; Wr_p = Wr0; att_p = att0; Wres_p = Wres0; bn_p = bn0;
      bu1_p = bu1_0; bu2_p = bu2_0;
    } else {
      int i = l - 1;
      Wl_p = WlL + (size_t)i * CH * HDIM;
      Wr_p = WrL + (size_t)i * CH * HDIM;
      att_p = attL + (size_t)i * HDIM;
      Wres_p = WresL + (size_t)i * CH * CH;
      bn_p = bnL + (size_t)i * CH;
      bu1_p = bu1L + (size_t)i * HDIM;
      bu2_p = bu2L + (size_t)i * HDIM;
    }

    if (l == 0)
      k_node_proj0_mfma<<<(NN + MT - 1) / MT, 256, 0, stream>>>(
          mesh, wall + (size_t)4 * 65536, wall + (size_t)5 * 65536, xl, xr);
    else
      k_node_proj<CH><<<4096, 256, 0, stream>>>(xin, Wl_p, Wr_p, xl, xr);

    k_clear<<<2048, 256, 0, stream>>>(agg, den);
    k_edge_score_mfma<<<NE / MT, 256, 0, stream>>>(e, wall + (size_t)l * 65536,
                                                   xl, xr, att_p, src, dst, sbuf);
    k_edge_soft_agg<<<8192, 256, 0, stream>>>(sbuf, xl, src, dst, agg, den);

    if (l == 0)
      k_node_out<HDIM, true><<<(NN + 7) / 8, 256, 0, stream>>>(agg, den, xin, Wres_p, bn_p,
                                                               lng, lnb, xa, post);
    else if (l < 3)
      k_node_out<CH, true><<<(NN + 7) / 8, 256, 0, stream>>>(agg, den, xin, Wres_p, bn_p,
                                                             lng + (size_t)l * CH,
                                                             lnb + (size_t)l * CH, xa, post);
    else
      k_node_out<CH, false><<<(NN + 7) / 8, 256, 0, stream>>>(agg, den, xin, Wres_p, bn_p,
                                                              nullptr, nullptr, xa, nullptr);

    if (l < 3)
      k_edge_mlp_mfma<<<NE / MT, 256, 0, stream>>>(e, xa, src, dst,
                                                   w1s + (size_t)l * 320 * 256, bu1_p,
                                                   w2s + (size_t)l * 256 * 256, bu2_p);

    xin = post;
    post = (post == xb) ? xc : xb;
  }
  // final GAT output (no LN) is in xa

  bf16* vv = (bf16*)agg;
  k_sg_qkv_mfma<<<(NN + MT - 1) / MT, 256, 0, stream>>>(
      mesh, wall + (size_t)6 * 65536, wall + (size_t)7 * 65536,
      wall + (size_t)8 * 65536, xl, xr, vv);
  k_zero<<<(NH * CH * CH + NH * CH + 255) / 256, 256, 0, stream>>>(kv, NH * CH * CH + NH * CH);
  k_sg_kv<<<256, 256, 0, stream>>>(xr, vv, kv, ksum);
  k_sg_final<<<(NN + 7) / 8, 256, 0, stream>>>(xl, vv, kv, ksum, xa, alphap, cng, cnb,
                                               (float*)d_out);
}

// Round 7
// 2907.259 us; speedup vs baseline: 3.8291x; 1.1233x over previous
//
#include <hip/hip_runtime.h>
#include <hip/hip_bf16.h>
#include <math.h>

typedef __hip_bfloat16 bf16;
typedef __attribute__((ext_vector_type(8))) __bf16 bf16x8;
typedef __attribute__((ext_vector_type(4))) float f32x4;

#define NN 40962
#define NE 245760
#define HDIM 256
#define NH 8
#define CH 32

#define MT 64    // rows per block in MFMA kernels

__device__ __forceinline__ float b2f(bf16 v) { return __bfloat162float(v); }
__device__ __forceinline__ bf16 f2b(float v) { return __float2bfloat16(v); }
__device__ __forceinline__ unsigned short f2bs(float v) {
  bf16 b = __float2bfloat16(v);
  return __builtin_bit_cast(unsigned short, b);
}
__device__ __forceinline__ float bs2f(unsigned short u) {
  return __bfloat162float(__builtin_bit_cast(bf16, u));
}

// ---- edge input projection (vectorized): 8 cols/thread, uint4 stores ----------------
__global__ void k_edge_proj(const float* __restrict__ attr, const float* __restrict__ W,
                            const float* __restrict__ b, bf16* __restrict__ e) {
  int t = blockIdx.x * 256 + threadIdx.x;     // NE*32 threads total
  int ed = t >> 5;
  int q  = t & 31;                             // col block of 8
  int j0 = q * 8;
  float acc[8];
#pragma unroll
  for (int i = 0; i < 8; ++i) acc[i] = b[j0 + i];
  float ar[16];
#pragma unroll
  for (int k = 0; k < 16; ++k) ar[k] = attr[ed * 16 + k];
#pragma unroll
  for (int k = 0; k < 16; ++k) {
    float4 w0 = *reinterpret_cast<const float4*>(&W[k * HDIM + j0]);
    float4 w1 = *reinterpret_cast<const float4*>(&W[k * HDIM + j0 + 4]);
    acc[0] += ar[k] * w0.x; acc[1] += ar[k] * w0.y;
    acc[2] += ar[k] * w0.z; acc[3] += ar[k] * w0.w;
    acc[4] += ar[k] * w1.x; acc[5] += ar[k] * w1.y;
    acc[6] += ar[k] * w1.z; acc[7] += ar[k] * w1.w;
  }
  unsigned short ov[8];
#pragma unroll
  for (int i = 0; i < 8; ++i) ov[i] = f2bs(acc[i]);
  *reinterpret_cast<uint4*>(&e[(size_t)ed * HDIM + j0]) =
      *reinterpret_cast<const uint4*>(ov);
}

__global__ void k_zero(float* __restrict__ p, int n) {
  int i = blockIdx.x * blockDim.x + threadIdx.x;
  if (i < n) p[i] = 0.f;
}
__global__ void k_zero_i(int* __restrict__ p, int n) {
  int i = blockIdx.x * blockDim.x + threadIdx.x;
  if (i < n) p[i] = 0;
}
__global__ void k_copy_i(const int* __restrict__ a, int* __restrict__ b, int n) {
  int i = blockIdx.x * blockDim.x + threadIdx.x;
  if (i < n) b[i] = a[i];
}

// ---- CSR build: count, scan, fill ---------------------------------------------------
__global__ void k_csr_count(const int* __restrict__ dst, int* __restrict__ cnt) {
  int e = blockIdx.x * 256 + threadIdx.x;
  if (e < NE) atomicAdd(&cnt[dst[e]], 1);
}
__global__ void k_csr_scan(const int* __restrict__ cnt, int* __restrict__ rowptr) {
  __shared__ int part[256];
  __shared__ int tot;
  int t = threadIdx.x;
  const int CHUNK = (NN + 255) / 256;
  int lo = t * CHUNK, hi = lo + CHUNK; if (hi > NN) hi = NN; if (lo > NN) lo = NN;
  int s = 0;
  for (int i = lo; i < hi; ++i) s += cnt[i];
  part[t] = s;
  __syncthreads();
  if (t == 0) {
    int run = 0;
    for (int i = 0; i < 256; ++i) { int v = part[i]; part[i] = run; run += v; }
    tot = run;
  }
  __syncthreads();
  int run = part[t];
  for (int i = lo; i < hi; ++i) { rowptr[i] = run; run += cnt[i]; }
  if (t == 0) rowptr[NN] = tot;
}
__global__ void k_csr_fill(const int* __restrict__ src, const int* __restrict__ dst,
                           int* __restrict__ cursor, int2* __restrict__ csr) {
  int e = blockIdx.x * 256 + threadIdx.x;
  if (e >= NE) return;
  int p = atomicAdd(&cursor[dst[e]], 1);
  int2 v; v.x = e; v.y = src[e];
  csr[p] = v;
}

// ---- weight swizzle into MFMA B-fragment-major layout (bf16), K-dim template --------
template <int K>
__global__ void k_swz_w(const float* __restrict__ W, unsigned short* __restrict__ out) {
  int t = blockIdx.x * 256 + threadIdx.x;
  if (t >= K * 256) return;
  int i  = t & 7;
  int l  = (t >> 3) & 63;
  int k0 = (t >> 9) % (K / 32);
  int n0 = t / (512 * (K / 32));
  int k = k0 * 32 + (l >> 4) * 8 + i;
  int n = n0 * 16 + (l & 15);
  out[t] = f2bs(W[k * 256 + n]);
}

// ---- fused swizzle of the nine 256x256 weights (We x4, Wl0, Wr0, Wq, Wk, Wv) --------
__global__ void k_swz_all(const float* __restrict__ We0, const float* __restrict__ WeL,
                          const float* __restrict__ Wl0, const float* __restrict__ Wr0,
                          const float* __restrict__ Wq, const float* __restrict__ Wk,
                          const float* __restrict__ Wv, unsigned short* __restrict__ dst) {
  int mat = blockIdx.x >> 8;
  int t = ((blockIdx.x & 255) << 8) | threadIdx.x;
  const float* W;
  switch (mat) {
    case 0: W = We0; break;
    case 1: W = WeL; break;
    case 2: W = WeL + 65536; break;
    case 3: W = WeL + 131072; break;
    case 4: W = Wl0; break;
    case 5: W = Wr0; break;
    case 6: W = Wq; break;
    case 7: W = Wk; break;
    default: W = Wv; break;
  }
  int i  = t & 7;
  int l  = (t >> 3) & 63;
  int k0 = (t >> 9) & 7;
  int n0 = t >> 12;
  int k = k0 * 32 + (l >> 4) * 8 + i;
  int n = n0 * 16 + (l & 15);
  dst[(size_t)mat * 65536 + t] = f2bs(W[k * 256 + n]);
}

// ---- MFMA edge score -> writes sx = exp(s) ------------------------------------------
__global__ __launch_bounds__(256) void k_edge_score_mfma(
    const bf16* __restrict__ e, const unsigned short* __restrict__ Wes,
    const bf16* __restrict__ xl, const bf16* __restrict__ xr,
    const float* __restrict__ att, const int* __restrict__ src,
    const int* __restrict__ dst, float* __restrict__ sx) {
  __shared__ unsigned short Ae[MT][264];
  __shared__ unsigned short Xs[MT][264];
  __shared__ float attS[HDIM];
  __shared__ int sidx[MT], didx[MT];
  int tid = threadIdx.x, l = tid & 63, w = tid >> 6;
  int lr = l & 15, lk = l >> 4;
  int base = blockIdx.x * MT;
  attS[tid] = att[tid];
  if (tid < MT) sidx[tid] = src[base + tid];
  else if (tid < 2 * MT) didx[tid - MT] = dst[base + tid - MT];
  __syncthreads();
  for (int t = tid; t < MT * 32; t += 256) {
    int p = t >> 5, c = t & 31;
    *reinterpret_cast<uint4*>(&Ae[p][c * 8]) =
        *reinterpret_cast<const uint4*>(&e[(size_t)(base + p) * HDIM + c * 8]);
  }
  for (int t = tid; t < MT * 32; t += 256) {
    int p = t >> 5, c = t & 31;
    uint4 ul = *reinterpret_cast<const uint4*>(&xl[(size_t)sidx[p] * HDIM + c * 8]);
    uint4 ur = *reinterpret_cast<const uint4*>(&xr[(size_t)didx[p] * HDIM + c * 8]);
    const unsigned short* al = (const unsigned short*)&ul;
    const unsigned short* ar = (const unsigned short*)&ur;
    unsigned short ov[8];
#pragma unroll
    for (int i = 0; i < 8; ++i) ov[i] = f2bs(bs2f(al[i]) + bs2f(ar[i]));
    *reinterpret_cast<uint4*>(&Xs[p][c * 8]) = *reinterpret_cast<const uint4*>(ov);
  }
  __syncthreads();

  int j0 = w * 64;
  f32x4 acc[4][4];
#pragma unroll
  for (int m = 0; m < 4; ++m)
#pragma unroll
    for (int n = 0; n < 4; ++n)
#pragma unroll
      for (int r = 0; r < 4; ++r) acc[m][n][r] = 0.f;
  for (int k0 = 0; k0 < 8; ++k0) {
    bf16x8 a[4], b[4];
#pragma unroll
    for (int m = 0; m < 4; ++m)
      a[m] = *reinterpret_cast<const bf16x8*>(&Ae[m * 16 + lr][k0 * 32 + lk * 8]);
#pragma unroll
    for (int n = 0; n < 4; ++n) {
      int nt = (j0 >> 4) + n;
      b[n] = *reinterpret_cast<const bf16x8*>(Wes + ((size_t)(nt * 8 + k0) * 64 + l) * 8);
    }
#pragma unroll
    for (int m = 0; m < 4; ++m)
#pragma unroll
      for (int n = 0; n < 4; ++n)
        acc[m][n] = __builtin_amdgcn_mfma_f32_16x16x32_bf16(a[m], b[n], acc[m][n], 0, 0, 0);
  }
#pragma unroll
  for (int n = 0; n < 4; ++n) {
    int col = j0 + n * 16 + lr;
    float av = attS[col];
#pragma unroll
    for (int m = 0; m < 4; ++m)
#pragma unroll
      for (int r = 0; r < 4; ++r) {
        int row = m * 16 + lk * 4 + r;
        float mm = acc[m][n][r] + bs2f(Xs[row][col]);
        mm = (mm > 0.f) ? mm : 0.2f * mm;
        Xs[row][col] = f2bs(mm * av);
      }
  }
  __syncthreads();
  for (int pair = tid; pair < MT * NH; pair += 256) {
    int ed = pair >> 3, h = pair & 7;
    float s = 0.f;
#pragma unroll
    for (int c = 0; c < CH; ++c) s += bs2f(Xs[ed][h * CH + c]);
    sx[(size_t)(base + ed) * NH + h] = expf(s);
  }
}

// ---- fused CSR aggregate + node output + optional LN --------------------------------
// one block per node: agg/den in registers, then mean_h + x@Wres + bn (+LN)
template <int ID, bool LN>
__global__ __launch_bounds__(256) void k_gat_out(
    const int* __restrict__ rowptr, const int2* __restrict__ csr,
    const float* __restrict__ sx, const bf16* __restrict__ xl,
    const float* __restrict__ x, const float* __restrict__ Wres,
    const float* __restrict__ bn, const float* __restrict__ lng,
    const float* __restrict__ lnb, float* __restrict__ xpre,
    float* __restrict__ xpost) {
  int n = blockIdx.x;
  int j = threadIdx.x;
  int h = j >> 5, c = j & 31;
  int p0 = rowptr[n], p1 = rowptr[n + 1];
  float a = 0.f, dsum = 0.f;
  for (int p = p0; p < p1; ++p) {
    int2 es = csr[p];
    float ex = sx[(size_t)es.x * NH + h];
    a += ex * b2f(xl[(size_t)es.y * HDIM + j]);
    dsum += ex;
  }
  __shared__ float oh[HDIM];
  __shared__ float rs[NH][CH];
  __shared__ float oc[CH + 1];
  oh[j] = a / (dsum + 1e-16f);
  const int KS = ID / NH;
  float r = 0.f;
  for (int k = h * KS; k < (h + 1) * KS; ++k)
    r += x[(size_t)n * ID + k] * Wres[k * CH + c];
  rs[h][c] = r;
  __syncthreads();
  if (j < CH) {
    float o = 0.f;
#pragma unroll
    for (int hh = 0; hh < NH; ++hh) o += oh[hh * CH + j];
    o *= (1.f / NH);
    float rr = 0.f;
#pragma unroll
    for (int hh = 0; hh < NH; ++hh) rr += rs[hh][j];
    o += rr + bn[j];
    xpre[(size_t)n * CH + j] = o;
    oc[j] = o;
  }
  __syncthreads();
  if (LN && j < CH) {
    float mu = 0.f;
#pragma unroll
    for (int k = 0; k < CH; ++k) mu += oc[k];
    mu *= (1.f / CH);
    float var = 0.f;
#pragma unroll
    for (int k = 0; k < CH; ++k) { float d = oc[k] - mu; var += d * d; }
    var *= (1.f / CH);
    xpost[(size_t)n * CH + j] = (oc[j] - mu) * rsqrtf(var + 1e-5f) * lng[j] + lnb[j];
  }
}

// ---- MFMA residual edge MLP ---------------------------------------------------------
__global__ __launch_bounds__(256) void k_edge_mlp_mfma(
    bf16* __restrict__ e, const float* __restrict__ xo,
    const int* __restrict__ src, const int* __restrict__ dst,
    const unsigned short* __restrict__ W1s, const float* __restrict__ bu1,
    const unsigned short* __restrict__ W2s, const float* __restrict__ bu2) {
  __shared__ unsigned short A1s[MT][328];
  __shared__ unsigned short A2s[MT][264];
  __shared__ int sidx[MT], didx[MT];
  int tid = threadIdx.x;
  int l = tid & 63;
  int wave = tid >> 6;
  int base = blockIdx.x * MT;
  int lr = l & 15;
  int lk = l >> 4;

  if (tid < MT) sidx[tid] = src[base + tid];
  else if (tid < 2 * MT) didx[tid - MT] = dst[base + tid - MT];
  __syncthreads();

  for (int t = tid; t < MT * 32; t += 256) {
    int p = t >> 5, cc = t & 31;
    uint4 v = *reinterpret_cast<const uint4*>(&e[(size_t)(base + p) * HDIM + cc * 8]);
    *reinterpret_cast<uint4*>(&A1s[p][64 + cc * 8]) = v;
  }
  for (int t = tid; t < MT * 64; t += 256) {
    int p = t >> 6, c = t & 63;
    float v = (c < CH) ? xo[(size_t)sidx[p] * CH + c]
                       : xo[(size_t)didx[p] * CH + (c - CH)];
    A1s[p][c] = f2bs(v);
  }
  __syncthreads();

  int j0 = wave * 64;

  f32x4 acc[4][4];
#pragma unroll
  for (int m = 0; m < 4; ++m)
#pragma unroll
    for (int n = 0; n < 4; ++n)
#pragma unroll
      for (int r = 0; r < 4; ++r) acc[m][n][r] = 0.f;

  for (int k0 = 0; k0 < 10; ++k0) {
    bf16x8 a[4], b[4];
#pragma unroll
    for (int m = 0; m < 4; ++m)
      a[m] = *reinterpret_cast<const bf16x8*>(&A1s[m * 16 + lr][k0 * 32 + lk * 8]);
#pragma unroll
    for (int n = 0; n < 4; ++n) {
      int nt = (j0 >> 4) + n;
      b[n] = *reinterpret_cast<const bf16x8*>(W1s + ((size_t)(nt * 10 + k0) * 64 + l) * 8);
    }
#pragma unroll
    for (int m = 0; m < 4; ++m)
#pragma unroll
      for (int n = 0; n < 4; ++n)
        acc[m][n] = __builtin_amdgcn_mfma_f32_16x16x32_bf16(a[m], b[n], acc[m][n], 0, 0, 0);
  }

#pragma unroll
  for (int n = 0; n < 4; ++n) {
    float bv = bu1[j0 + n * 16 + lr];
#pragma unroll
    for (int m = 0; m < 4; ++m)
#pragma unroll
      for (int r = 0; r < 4; ++r) {
        float xv = acc[m][n][r] + bv;
        float tnh = tanhf(0.7978845608028654f * (xv + 0.044715f * xv * xv * xv));
        float g = 0.5f * xv * (1.f + tnh);
        A2s[m * 16 + lk * 4 + r][j0 + n * 16 + lr] = f2bs(g);
      }
  }
  __syncthreads();

#pragma unroll
  for (int m = 0; m < 4; ++m)
#pragma unroll
    for (int n = 0; n < 4; ++n)
#pragma unroll
      for (int r = 0; r < 4; ++r) acc[m][n][r] = 0.f;

  for (int k0 = 0; k0 < 8; ++k0) {
    bf16x8 a[4], b[4];
#pragma unroll
    for (int m = 0; m < 4; ++m)
      a[m] = *reinterpret_cast<const bf16x8*>(&A2s[m * 16 + lr][k0 * 32 + lk * 8]);
#pragma unroll
    for (int n = 0; n < 4; ++n) {
      int nt = (j0 >> 4) + n;
      b[n] = *reinterpret_cast<const bf16x8*>(W2s + ((size_t)(nt * 8 + k0) * 64 + l) * 8);
    }
#pragma unroll
    for (int m = 0; m < 4; ++m)
#pragma unroll
      for (int n = 0; n < 4; ++n)
        acc[m][n] = __builtin_amdgcn_mfma_f32_16x16x32_bf16(a[m], b[n], acc[m][n], 0, 0, 0);
  }
  __syncthreads();

#pragma unroll
  for (int n = 0; n < 4; ++n) {
    int col = j0 + n * 16 + lr;
    float bv = bu2[col];
#pragma unroll
    for (int m = 0; m < 4; ++m)
#pragma unroll
      for (int r = 0; r < 4; ++r) {
        int row = m * 16 + lk * 4 + r;
        float eo = bs2f(A1s[row][64 + col]);
        A2s[row][col] = f2bs(eo + acc[m][n][r] + bv);
      }
  }
  __syncthreads();

  for (int t = tid; t < MT * 32; t += 256) {
    int p = t >> 5, cc = t & 31;
    *reinterpret_cast<uint4*>(&e[(size_t)(base + p) * HDIM + cc * 8]) =
        *reinterpret_cast<const uint4*>(&A2s[p][cc * 8]);
  }
}

// ---- MFMA layer-0 node projection ---------------------------------------------------
__global__ __launch_bounds__(256) void k_node_proj0_mfma(
    const float* __restrict__ x, const unsigned short* __restrict__ Wls,
    const unsigned short* __restrict__ Wrs, bf16* __restrict__ xl,
    bf16* __restrict__ xr) {
  __shared__ unsigned short A[MT][264];
  __shared__ unsigned short O[MT][264];
  int tid = threadIdx.x, l = tid & 63, w = tid >> 6;
  int lr = l & 15, lk = l >> 4;
  int base = blockIdx.x * MT;
  for (int t = tid; t < MT * 64; t += 256) {
    int p = t >> 6, c = t & 63;
    int row = base + p; if (row >= NN) row = NN - 1;
    float4 v = *reinterpret_cast<const float4*>(&x[(size_t)row * HDIM + c * 4]);
    unsigned short tmp[4] = {f2bs(v.x), f2bs(v.y), f2bs(v.z), f2bs(v.w)};
    *reinterpret_cast<uint2*>(&A[p][c * 4]) = *reinterpret_cast<const uint2*>(tmp);
  }
  __syncthreads();
  int j0 = w * 64;
#pragma unroll
  for (int mtx = 0; mtx < 2; ++mtx) {
    const unsigned short* Ws = (mtx == 0) ? Wls : Wrs;
    bf16* outp = (mtx == 0) ? xl : xr;
    f32x4 acc[4][4];
#pragma unroll
    for (int m = 0; m < 4; ++m)
#pragma unroll
      for (int n = 0; n < 4; ++n)
#pragma unroll
        for (int r = 0; r < 4; ++r) acc[m][n][r] = 0.f;
    for (int k0 = 0; k0 < 8; ++k0) {
      bf16x8 a[4], b[4];
#pragma unroll
      for (int m = 0; m < 4; ++m)
        a[m] = *reinterpret_cast<const bf16x8*>(&A[m * 16 + lr][k0 * 32 + lk * 8]);
#pragma unroll
      for (int n = 0; n < 4; ++n) {
        int nt = (j0 >> 4) + n;
        b[n] = *reinterpret_cast<const bf16x8*>(Ws + ((size_t)(nt * 8 + k0) * 64 + l) * 8);
      }
#pragma unroll
      for (int m = 0; m < 4; ++m)
#pragma unroll
        for (int n = 0; n < 4; ++n)
          acc[m][n] = __builtin_amdgcn_mfma_f32_16x16x32_bf16(a[m], b[n], acc[m][n], 0, 0, 0);
    }
#pragma unroll
    for (int n = 0; n < 4; ++n)
#pragma unroll
      for (int m = 0; m < 4; ++m)
#pragma unroll
        for (int r = 0; r < 4; ++r)
          O[m * 16 + lk * 4 + r][j0 + n * 16 + lr] = f2bs(acc[m][n][r]);
    __syncthreads();
    for (int t = tid; t < MT * 32; t += 256) {
      int p = t >> 5, c = t & 31;
      if (base + p < NN)
        *reinterpret_cast<uint4*>(&outp[(size_t)(base + p) * HDIM + c * 8]) =
            *reinterpret_cast<const uint4*>(&O[p][c * 8]);
    }
    __syncthreads();
  }
}

// ---- MFMA small node projection (layers 1..3, K=32) ---------------------------------
__global__ __launch_bounds__(256) void k_node_projS_mfma(
    const float* __restrict__ x, const unsigned short* __restrict__ Wls,
    const unsigned short* __restrict__ Wrs, bf16* __restrict__ xl,
    bf16* __restrict__ xr) {
  __shared__ unsigned short A[MT][40];     // 64 x 32 (+8 pad)
  __shared__ unsigned short O[MT][264];
  int tid = threadIdx.x, l = tid & 63, w = tid >> 6;
  int lr = l & 15, lk = l >> 4;
  int base = blockIdx.x * MT;
  for (int t = tid; t < MT * 8; t += 256) {
    int p = t >> 3, q = t & 7;
    int row = base + p; if (row >= NN) row = NN - 1;
    float4 v = *reinterpret_cast<const float4*>(&x[(size_t)row * CH + q * 4]);
    unsigned short tmp[4] = {f2bs(v.x), f2bs(v.y), f2bs(v.z), f2bs(v.w)};
    *reinterpret_cast<uint2*>(&A[p][q * 4]) = *reinterpret_cast<const uint2*>(tmp);
  }
  __syncthreads();
  int j0 = w * 64;
#pragma unroll
  for (int mtx = 0; mtx < 2; ++mtx) {
    const unsigned short* Ws = (mtx == 0) ? Wls : Wrs;
    bf16* outp = (mtx == 0) ? xl : xr;
    f32x4 acc[4][4];
#pragma unroll
    for (int m = 0; m < 4; ++m)
#pragma unroll
      for (int n = 0; n < 4; ++n)
#pragma unroll
        for (int r = 0; r < 4; ++r) acc[m][n][r] = 0.f;
    bf16x8 a[4], b[4];
#pragma unroll
    for (int m = 0; m < 4; ++m)
      a[m] = *reinterpret_cast<const bf16x8*>(&A[m * 16 + lr][lk * 8]);
#pragma unroll
    for (int n = 0; n < 4; ++n) {
      int nt = (j0 >> 4) + n;
      b[n] = *reinterpret_cast<const bf16x8*>(Ws + ((size_t)nt * 64 + l) * 8);
    }
#pragma unroll
    for (int m = 0; m < 4; ++m)
#pragma unroll
      for (int n = 0; n < 4; ++n)
        acc[m][n] = __builtin_amdgcn_mfma_f32_16x16x32_bf16(a[m], b[n], acc[m][n], 0, 0, 0);
#pragma unroll
    for (int n = 0; n < 4; ++n)
#pragma unroll
      for (int m = 0; m < 4; ++m)
#pragma unroll
        for (int r = 0; r < 4; ++r)
          O[m * 16 + lk * 4 + r][j0 + n * 16 + lr] = f2bs(acc[m][n][r]);
    __syncthreads();
    for (int t = tid; t < MT * 32; t += 256) {
      int p = t >> 5, c = t & 31;
      if (base + p < NN)
        *reinterpret_cast<uint4*>(&outp[(size_t)(base + p) * HDIM + c * 8]) =
            *reinterpret_cast<const uint4*>(&O[p][c * 8]);
    }
    __syncthreads();
  }
}

// ---- MFMA SGFormer qkv --------------------------------------------------------------
__global__ __launch_bounds__(256) void k_sg_qkv_mfma(
    const float* __restrict__ x, const unsigned short* __restrict__ Wqs,
    const unsigned short* __restrict__ Wks, const unsigned short* __restrict__ Wvs,
    bf16* __restrict__ qs, bf16* __restrict__ ks, bf16* __restrict__ vv) {
  __shared__ unsigned short A[MT][264];
  __shared__ unsigned short O[MT][264];
  int tid = threadIdx.x, l = tid & 63, w = tid >> 6;
  int lr = l & 15, lk = l >> 4;
  int base = blockIdx.x * MT;
  for (int t = tid; t < MT * 64; t += 256) {
    int p = t >> 6, c = t & 63;
    int row = base + p; if (row >= NN) row = NN - 1;
    float4 v = *reinterpret_cast<const float4*>(&x[(size_t)row * HDIM + c * 4]);
    unsigned short tmp[4] = {f2bs(v.x), f2bs(v.y), f2bs(v.z), f2bs(v.w)};
    *reinterpret_cast<uint2*>(&A[p][c * 4]) = *reinterpret_cast<const uint2*>(tmp);
  }
  __syncthreads();
  int j0 = w * 64;
#pragma unroll
  for (int mtx = 0; mtx < 3; ++mtx) {
    const unsigned short* Ws = (mtx == 0) ? Wqs : (mtx == 1) ? Wks : Wvs;
    bf16* outp = (mtx == 0) ? qs : (mtx == 1) ? ks : vv;
    f32x4 acc[4][4];
#pragma unroll
    for (int m = 0; m < 4; ++m)
#pragma unroll
      for (int n = 0; n < 4; ++n)
#pragma unroll
        for (int r = 0; r < 4; ++r) acc[m][n][r] = 0.f;
    for (int k0 = 0; k0 < 8; ++k0) {
      bf16x8 a[4], b[4];
#pragma unroll
      for (int m = 0; m < 4; ++m)
        a[m] = *reinterpret_cast<const bf16x8*>(&A[m * 16 + lr][k0 * 32 + lk * 8]);
#pragma unroll
      for (int n = 0; n < 4; ++n) {
        int nt = (j0 >> 4) + n;
        b[n] = *reinterpret_cast<const bf16x8*>(Ws + ((size_t)(nt * 8 + k0) * 64 + l) * 8);
      }
#pragma unroll
      for (int m = 0; m < 4; ++m)
#pragma unroll
        for (int n = 0; n < 4; ++n)
          acc[m][n] = __builtin_amdgcn_mfma_f32_16x16x32_bf16(a[m], b[n], acc[m][n], 0, 0, 0);
    }
    if (mtx < 2) {
      float pa[4][4], pb[4][4];
#pragma unroll
      for (int m = 0; m < 4; ++m)
#pragma unroll
        for (int r = 0; r < 4; ++r) {
          pa[m][r] = acc[m][0][r] * acc[m][0][r] + acc[m][1][r] * acc[m][1][r];
          pb[m][r] = acc[m][2][r] * acc[m][2][r] + acc[m][3][r] * acc[m][3][r];
        }
#pragma unroll
      for (int off = 1; off < 16; off <<= 1) {
#pragma unroll
        for (int m = 0; m < 4; ++m)
#pragma unroll
          for (int r = 0; r < 4; ++r) {
            pa[m][r] += __shfl_xor(pa[m][r], off);
            pb[m][r] += __shfl_xor(pb[m][r], off);
          }
      }
#pragma unroll
      for (int m = 0; m < 4; ++m)
#pragma unroll
        for (int r = 0; r < 4; ++r) {
          float ra = 1.f / (sqrtf(pa[m][r]) + 1e-6f);
          float rb = 1.f / (sqrtf(pb[m][r]) + 1e-6f);
          acc[m][0][r] *= ra; acc[m][1][r] *= ra;
          acc[m][2][r] *= rb; acc[m][3][r] *= rb;
        }
    }
#pragma unroll
    for (int n = 0; n < 4; ++n)
#pragma unroll
      for (int m = 0; m < 4; ++m)
#pragma unroll
        for (int r = 0; r < 4; ++r)
          O[m * 16 + lk * 4 + r][j0 + n * 16 + lr] = f2bs(acc[m][n][r]);
    __syncthreads();
    for (int t = tid; t < MT * 32; t += 256) {
      int p = t >> 5, c = t & 31;
      if (base + p < NN)
        *reinterpret_cast<uint4*>(&outp[(size_t)(base + p) * HDIM + c * 8]) =
            *reinterpret_cast<const uint4*>(&O[p][c * 8]);
    }
    __syncthreads();
  }
}

// ---- kv[h][c][d] = sum_n ks[n,h,c]*v[n,h,d] ; ksum[h][c] = sum_n ks[n,h,c] ----------
__global__ void k_sg_kv(const bf16* __restrict__ ks, const bf16* __restrict__ vv,
                        float* __restrict__ kv, float* __restrict__ ksum) {
  int t = threadIdx.x;
  int h = t >> 5, c = t & 31;
  float kvloc[CH];
  float ksl = 0.f;
#pragma unroll
  for (int d = 0; d < CH; ++d) kvloc[d] = 0.f;
  __shared__ float krow[HDIM], vrow[HDIM];
  for (int n = blockIdx.x; n < NN; n += gridDim.x) {
    krow[t] = b2f(ks[(size_t)n * HDIM + t]);
    vrow[t] = b2f(vv[(size_t)n * HDIM + t]);
    __syncthreads();
    float kc = krow[h * CH + c];
    ksl += kc;
#pragma unroll
    for (int d = 0; d < CH; ++d) kvloc[d] += kc * vrow[h * CH + d];
    __syncthreads();
  }
#pragma unroll
  for (int d = 0; d < CH; ++d) atomicAdd(&kv[(h * CH + c) * CH + d], kvloc[d]);
  atomicAdd(&ksum[h * CH + c], ksl);
}

// ---- trans + combine + LN -> f32 out ------------------------------------------------
__global__ void k_sg_final(const bf16* __restrict__ qs, const bf16* __restrict__ vv,
                           const float* __restrict__ kv, const float* __restrict__ ksum,
                           const float* __restrict__ xg, const float* __restrict__ alphap,
                           const float* __restrict__ cng, const float* __restrict__ cnb,
                           float* __restrict__ out) {
  int t = threadIdx.x;
  int d = t & 31, sub = t >> 5;
  __shared__ float qrow[8][HDIM];
  __shared__ float crow[8][CH];
  int n = blockIdx.x * 8 + sub;
  for (int tt = t; tt < 8 * HDIM; tt += 256) {
    int p = tt >> 8, k = tt & 255;
    int n2 = blockIdx.x * 8 + p;
    if (n2 < NN) qrow[p][k] = b2f(qs[(size_t)n2 * HDIM + k]);
  }
  __syncthreads();
  float alpha = 1.f / (1.f + expf(-alphap[0]));
  const float Nf = (float)NN;
  float comb = 0.f;
  if (n < NN) {
    float acc = 0.f;
#pragma unroll
    for (int h = 0; h < NH; ++h) {
      float nm = 0.f, dp = 0.f;
#pragma unroll 8
      for (int c = 0; c < CH; ++c) {
        float qv = qrow[sub][h * CH + c];
        nm += qv * kv[(h * CH + c) * CH + d];
        dp += qv * ksum[h * CH + c];
      }
      nm += Nf * b2f(vv[(size_t)n * HDIM + h * CH + d]);
      acc += nm / (dp + Nf);
    }
    float trans = acc * (1.f / NH);
    comb = alpha * xg[(size_t)n * CH + d] + (1.f - alpha) * trans;
    crow[sub][d] = comb;
  }
  __syncthreads();
  if (n < NN) {
    float mu = 0.f;
#pragma unroll
    for (int k = 0; k < CH; ++k) mu += crow[sub][k];
    mu *= (1.f / CH);
    float var = 0.f;
#pragma unroll
    for (int k = 0; k < CH; ++k) { float dv = crow[sub][k] - mu; var += dv * dv; }
    var *= (1.f / CH);
    float o = (comb - mu) * rsqrtf(var + 1e-5f) * cng[d] + cnb[d];
    out[(size_t)n * CH + d] = o;
  }
}

extern "C" void kernel_launch(void* const* d_in, const int* in_sizes, int n_in,
                              void* d_out, int out_size, void* d_ws, size_t ws_size,
                              hipStream_t stream) {
  const float* mesh  = (const float*)d_in[0];
  const int*   eidx  = (const int*)d_in[1];
  const float* eattr = (const float*)d_in[2];
  const float* epW   = (const float*)d_in[3];
  const float* epb   = (const float*)d_in[4];
  const float* Wl0   = (const float*)d_in[5];
  const float* Wr0   = (const float*)d_in[6];
  const float* WlL   = (const float*)d_in[7];
  const float* WrL   = (const float*)d_in[8];
  const float* We0   = (const float*)d_in[9];
  const float* WeL   = (const float*)d_in[10];
  const float* att0  = (const float*)d_in[11];
  const float* attL  = (const float*)d_in[12];
  const float* Wres0 = (const float*)d_in[13];
  const float* WresL = (const float*)d_in[14];
  const float* bn0   = (const float*)d_in[15];
  const float* bnL   = (const float*)d_in[16];
  const float* Wu1_0 = (const float*)d_in[17];
  const float* Wu1L  = (const float*)d_in[18];
  const float* bu1_0 = (const float*)d_in[19];
  const float* bu1L  = (const float*)d_in[20];
  const float* Wu2_0 = (const float*)d_in[21];
  const float* Wu2L  = (const float*)d_in[22];
  const float* bu2_0 = (const float*)d_in[23];
  const float* bu2L  = (const float*)d_in[24];
  const float* lng   = (const float*)d_in[25];
  const float* lnb   = (const float*)d_in[26];
  const float* Wq    = (const float*)d_in[27];
  const float* Wk    = (const float*)d_in[28];
  const float* Wv    = (const float*)d_in[29];
  const float* alphap= (const float*)d_in[30];
  const float* cng   = (const float*)d_in[31];
  const float* cnb   = (const float*)d_in[32];

  const int* src = eidx;
  const int* dst = eidx + NE;

  char* base = (char*)d_ws;
  size_t o = 0;
  auto alloc = [&](size_t bytes) -> char* {
    o = (o + 255) & ~(size_t)255;
    char* p = base + o;
    o += bytes;
    return p;
  };
  bf16* e    = (bf16*)alloc((size_t)NE * HDIM * 2);
  bf16* xl   = (bf16*)alloc((size_t)NN * HDIM * 2);   // reused: qs
  bf16* xr   = (bf16*)alloc((size_t)NN * HDIM * 2);   // reused: ks
  bf16* vvb  = (bf16*)alloc((size_t)NN * HDIM * 2);   // SGFormer v
  float* sbuf= (float*)alloc((size_t)NE * NH * 4);    // exp(scores)
  float* xa  = (float*)alloc((size_t)NN * CH * 4);
  float* xb  = (float*)alloc((size_t)NN * CH * 4);
  float* xc  = (float*)alloc((size_t)NN * CH * 4);
  float* kv  = (float*)alloc(NH * CH * CH * 4);
  float* ksum= (float*)alloc(NH * CH * 4);
  unsigned short* w1s = (unsigned short*)alloc((size_t)3 * 320 * 256 * 2);
  unsigned short* w2s = (unsigned short*)alloc((size_t)3 * 256 * 256 * 2);
  unsigned short* wall= (unsigned short*)alloc((size_t)9 * 65536 * 2);
  unsigned short* w32s= (unsigned short*)alloc((size_t)6 * 32 * 256 * 2);
  int* cnt    = (int*)alloc((size_t)NN * 4);
  int* rowptr = (int*)alloc((size_t)(NN + 1) * 4);
  int* cursor = (int*)alloc((size_t)NN * 4);
  int2* csr   = (int2*)alloc((size_t)NE * 8);
  if (ws_size < o) return;   // fail cleanly if ws too small

  // pre-swizzle weights
  for (int i = 0; i < 3; ++i) {
    const float* W1 = (i == 0) ? Wu1_0 : Wu1L + (size_t)(i - 1) * 320 * 256;
    const float* W2 = (i == 0) ? Wu2_0 : Wu2L + (size_t)(i - 1) * 256 * 256;
    k_swz_w<320><<<320, 256, 0, stream>>>(W1, w1s + (size_t)i * 320 * 256);
    k_swz_w<256><<<256, 256, 0, stream>>>(W2, w2s + (size_t)i * 256 * 256);
  }
  k_swz_all<<<9 * 256, 256, 0, stream>>>(We0, WeL, Wl0, Wr0, Wq, Wk, Wv, wall);
  for (int i = 0; i < 3; ++i) {
    k_swz_w<32><<<32, 256, 0, stream>>>(WlL + (size_t)i * 32 * 256,
                                        w32s + (size_t)(i * 2 + 0) * 8192);
    k_swz_w<32><<<32, 256, 0, stream>>>(WrL + (size_t)i * 32 * 256,
                                        w32s + (size_t)(i * 2 + 1) * 8192);
  }

  // CSR build (graph constant across layers)
  k_zero_i<<<(NN + 255) / 256, 256, 0, stream>>>(cnt, NN);
  k_csr_count<<<(NE + 255) / 256, 256, 0, stream>>>(dst, cnt);
  k_csr_scan<<<1, 256, 0, stream>>>(cnt, rowptr);
  k_copy_i<<<(NN + 255) / 256, 256, 0, stream>>>(rowptr, cursor, NN);
  k_csr_fill<<<(NE + 255) / 256, 256, 0, stream>>>(src, dst, cursor, csr);

  k_edge_proj<<<NE * 32 / 256, 256, 0, stream>>>(eattr, epW, epb, e);

  const float* xin = mesh;
  float* post = xb;
  for (int l = 0; l < 4; ++l) {
    const float *att_p, *Wres_p, *bn_p, *bu1_p, *bu2_p;
    if (l == 0) {
      att_p = att0; Wres_p = Wres0; bn_p = bn0; bu1_p = bu1_0; bu2_p = bu2_0;
    } else {
      int i = l - 1;
      att_p = attL + (size_t)i * HDIM;
      Wres_p = WresL + (size_t)i * CH * CH;
      bn_p = bnL + (size_t)i * CH;
      bu1_p = bu1L + (size_t)i * HDIM;
      bu2_p = bu2L + (size_t)i * HDIM;
    }

    if (l == 0)
      k_node_proj0_mfma<<<(NN + MT - 1) / MT, 256, 0, stream>>>(
          mesh, wall + (size_t)4 * 65536, wall + (size_t)5 * 65536, xl, xr);
    else
      k_node_projS_mfma<<<(NN + MT - 1) / MT, 256, 0, stream>>>(
          xin, w32s + (size_t)((l - 1) * 2 + 0) * 8192,
          w32s + (size_t)((l - 1) * 2 + 1) * 8192, xl, xr);

    k_edge_score_mfma<<<NE / MT, 256, 0, stream>>>(e, wall + (size_t)l * 65536,
                                                   xl, xr, att_p, src, dst, sbuf);

    if (l == 0)
      k_gat_out<HDIM, true><<<NN, 256, 0, stream>>>(rowptr, csr, sbuf, xl, xin, Wres_p,
                                                    bn_p, lng, lnb, xa, post);
    else if (l < 3)
      k_gat_out<CH, true><<<NN, 256, 0, stream>>>(rowptr, csr, sbuf, xl, xin, Wres_p,
                                                  bn_p, lng + (size_t)l * CH,
                                                  lnb + (size_t)l * CH, xa, post);
    else
      k_gat_out<CH, false><<<NN, 256, 0, stream>>>(rowptr, csr, sbuf, xl, xin, Wres_p,
                                                   bn_p, nullptr, nullptr, xa, nullptr);

    if (l < 3)
      k_edge_mlp_mfma<<<NE / MT, 256, 0, stream>>>(e, xa, src, dst,
                                                   w1s + (size_t)l * 320 * 256, bu1_p,
                                                   w2s + (size_t)l * 256 * 256, bu2_p);

    xin = post;
    post = (post == xb) ? xc : xb;
  }
  // final GAT output (no LN) is in xa

  k_sg_qkv_mfma<<<(NN + MT - 1) / MT, 256, 0, stream>>>(
      mesh, wall + (size_t)6 * 65536, wall + (size_t)7 * 65536,
      wall + (size_t)8 * 65536, xl, xr, vvb);
  k_zero<<<(NH * CH * CH + NH * CH + 255) / 256, 256, 0, stream>>>(kv, NH * CH * CH + NH * CH);
  k_sg_kv<<<1024, 256, 0, stream>>>(xr, vvb, kv, ksum);
  k_sg_final<<<(NN + 7) / 8, 256, 0, stream>>>(xl, vvb, kv, ksum, xa, alphap, cng, cnb,
                                               (float*)d_out);
}

// Round 8
// 2145.663 us; speedup vs baseline: 5.1883x; 1.3549x over previous
//
#include <hip/hip_runtime.h>
#include <hip/hip_bf16.h>
#include <math.h>

typedef __hip_bfloat16 bf16;
typedef __attribute__((ext_vector_type(8))) __bf16 bf16x8;
typedef __attribute__((ext_vector_type(4))) float f32x4;

#define NN 40962
#define NE 245760
#define HDIM 256
#define NH 8
#define CH 32

#define MT 64     // rows per block in MFMA kernels
#define KVB 512   // stage-1 blocks for sg_kv partial reduction

__device__ __forceinline__ float b2f(bf16 v) { return __bfloat162float(v); }
__device__ __forceinline__ bf16 f2b(float v) { return __float2bfloat16(v); }
__device__ __forceinline__ unsigned short f2bs(float v) {
  bf16 b = __float2bfloat16(v);
  return __builtin_bit_cast(unsigned short, b);
}
__device__ __forceinline__ float bs2f(unsigned short u) {
  return __bfloat162float(__builtin_bit_cast(bf16, u));
}

// ---- edge input projection (vectorized): 8 cols/thread, uint4 stores ----------------
__global__ void k_edge_proj(const float* __restrict__ attr, const float* __restrict__ W,
                            const float* __restrict__ b, bf16* __restrict__ e) {
  int t = blockIdx.x * 256 + threadIdx.x;
  int ed = t >> 5;
  int q  = t & 31;
  int j0 = q * 8;
  float acc[8];
#pragma unroll
  for (int i = 0; i < 8; ++i) acc[i] = b[j0 + i];
  float ar[16];
#pragma unroll
  for (int k = 0; k < 16; ++k) ar[k] = attr[ed * 16 + k];
#pragma unroll
  for (int k = 0; k < 16; ++k) {
    float4 w0 = *reinterpret_cast<const float4*>(&W[k * HDIM + j0]);
    float4 w1 = *reinterpret_cast<const float4*>(&W[k * HDIM + j0 + 4]);
    acc[0] += ar[k] * w0.x; acc[1] += ar[k] * w0.y;
    acc[2] += ar[k] * w0.z; acc[3] += ar[k] * w0.w;
    acc[4] += ar[k] * w1.x; acc[5] += ar[k] * w1.y;
    acc[6] += ar[k] * w1.z; acc[7] += ar[k] * w1.w;
  }
  unsigned short ov[8];
#pragma unroll
  for (int i = 0; i < 8; ++i) ov[i] = f2bs(acc[i]);
  *reinterpret_cast<uint4*>(&e[(size_t)ed * HDIM + j0]) =
      *reinterpret_cast<const uint4*>(ov);
}

__global__ void k_zero_i(int* __restrict__ p, int n) {
  int i = blockIdx.x * blockDim.x + threadIdx.x;
  if (i < n) p[i] = 0;
}
__global__ void k_copy_i(const int* __restrict__ a, int* __restrict__ b, int n) {
  int i = blockIdx.x * blockDim.x + threadIdx.x;
  if (i < n) b[i] = a[i];
}

// ---- CSR build: count, scan, fill ---------------------------------------------------
__global__ void k_csr_count(const int* __restrict__ dst, int* __restrict__ cnt) {
  int e = blockIdx.x * 256 + threadIdx.x;
  if (e < NE) atomicAdd(&cnt[dst[e]], 1);
}
__global__ void k_csr_scan(const int* __restrict__ cnt, int* __restrict__ rowptr) {
  __shared__ int part[256];
  __shared__ int tot;
  int t = threadIdx.x;
  const int CHUNK = (NN + 255) / 256;
  int lo = t * CHUNK, hi = lo + CHUNK; if (hi > NN) hi = NN; if (lo > NN) lo = NN;
  int s = 0;
  for (int i = lo; i < hi; ++i) s += cnt[i];
  part[t] = s;
  __syncthreads();
  if (t == 0) {
    int run = 0;
    for (int i = 0; i < 256; ++i) { int v = part[i]; part[i] = run; run += v; }
    tot = run;
  }
  __syncthreads();
  int run = part[t];
  for (int i = lo; i < hi; ++i) { rowptr[i] = run; run += cnt[i]; }
  if (t == 0) rowptr[NN] = tot;
}
__global__ void k_csr_fill(const int* __restrict__ src, const int* __restrict__ dst,
                           int* __restrict__ cursor, int2* __restrict__ csr) {
  int e = blockIdx.x * 256 + threadIdx.x;
  if (e >= NE) return;
  int p = atomicAdd(&cursor[dst[e]], 1);
  int2 v; v.x = e; v.y = src[e];
  csr[p] = v;
}

// ---- weight swizzle into MFMA B-fragment-major layout (bf16), K-dim template --------
template <int K>
__global__ void k_swz_w(const float* __restrict__ W, unsigned short* __restrict__ out) {
  int t = blockIdx.x * 256 + threadIdx.x;
  if (t >= K * 256) return;
  int i  = t & 7;
  int l  = (t >> 3) & 63;
  int k0 = (t >> 9) % (K / 32);
  int n0 = t / (512 * (K / 32));
  int k = k0 * 32 + (l >> 4) * 8 + i;
  int n = n0 * 16 + (l & 15);
  out[t] = f2bs(W[k * 256 + n]);
}

// ---- fused swizzle of the nine 256x256 weights --------------------------------------
__global__ void k_swz_all(const float* __restrict__ We0, const float* __restrict__ WeL,
                          const float* __restrict__ Wl0, const float* __restrict__ Wr0,
                          const float* __restrict__ Wq, const float* __restrict__ Wk,
                          const float* __restrict__ Wv, unsigned short* __restrict__ dst) {
  int mat = blockIdx.x >> 8;
  int t = ((blockIdx.x & 255) << 8) | threadIdx.x;
  const float* W;
  switch (mat) {
    case 0: W = We0; break;
    case 1: W = WeL; break;
    case 2: W = WeL + 65536; break;
    case 3: W = WeL + 131072; break;
    case 4: W = Wl0; break;
    case 5: W = Wr0; break;
    case 6: W = Wq; break;
    case 7: W = Wk; break;
    default: W = Wv; break;
  }
  int i  = t & 7;
  int l  = (t >> 3) & 63;
  int k0 = (t >> 9) & 7;
  int n0 = t >> 12;
  int k = k0 * 32 + (l >> 4) * 8 + i;
  int n = n0 * 16 + (l & 15);
  dst[(size_t)mat * 65536 + t] = f2bs(W[k * 256 + n]);
}

// ---- MFMA edge score -> writes sx = exp(s) ------------------------------------------
__global__ __launch_bounds__(256) void k_edge_score_mfma(
    const bf16* __restrict__ e, const unsigned short* __restrict__ Wes,
    const bf16* __restrict__ xl, const bf16* __restrict__ xr,
    const float* __restrict__ att, const int* __restrict__ src,
    const int* __restrict__ dst, float* __restrict__ sx) {
  __shared__ unsigned short Ae[MT][264];
  __shared__ unsigned short Xs[MT][264];
  __shared__ float attS[HDIM];
  __shared__ int sidx[MT], didx[MT];
  int tid = threadIdx.x, l = tid & 63, w = tid >> 6;
  int lr = l & 15, lk = l >> 4;
  int base = blockIdx.x * MT;
  attS[tid] = att[tid];
  if (tid < MT) sidx[tid] = src[base + tid];
  else if (tid < 2 * MT) didx[tid - MT] = dst[base + tid - MT];
  __syncthreads();
  for (int t = tid; t < MT * 32; t += 256) {
    int p = t >> 5, c = t & 31;
    *reinterpret_cast<uint4*>(&Ae[p][c * 8]) =
        *reinterpret_cast<const uint4*>(&e[(size_t)(base + p) * HDIM + c * 8]);
  }
  for (int t = tid; t < MT * 32; t += 256) {
    int p = t >> 5, c = t & 31;
    uint4 ul = *reinterpret_cast<const uint4*>(&xl[(size_t)sidx[p] * HDIM + c * 8]);
    uint4 ur = *reinterpret_cast<const uint4*>(&xr[(size_t)didx[p] * HDIM + c * 8]);
    const unsigned short* al = (const unsigned short*)&ul;
    const unsigned short* ar = (const unsigned short*)&ur;
    unsigned short ov[8];
#pragma unroll
    for (int i = 0; i < 8; ++i) ov[i] = f2bs(bs2f(al[i]) + bs2f(ar[i]));
    *reinterpret_cast<uint4*>(&Xs[p][c * 8]) = *reinterpret_cast<const uint4*>(ov);
  }
  __syncthreads();

  int j0 = w * 64;
  f32x4 acc[4][4];
#pragma unroll
  for (int m = 0; m < 4; ++m)
#pragma unroll
    for (int n = 0; n < 4; ++n)
#pragma unroll
      for (int r = 0; r < 4; ++r) acc[m][n][r] = 0.f;
  for (int k0 = 0; k0 < 8; ++k0) {
    bf16x8 a[4], b[4];
#pragma unroll
    for (int m = 0; m < 4; ++m)
      a[m] = *reinterpret_cast<const bf16x8*>(&Ae[m * 16 + lr][k0 * 32 + lk * 8]);
#pragma unroll
    for (int n = 0; n < 4; ++n) {
      int nt = (j0 >> 4) + n;
      b[n] = *reinterpret_cast<const bf16x8*>(Wes + ((size_t)(nt * 8 + k0) * 64 + l) * 8);
    }
#pragma unroll
    for (int m = 0; m < 4; ++m)
#pragma unroll
      for (int n = 0; n < 4; ++n)
        acc[m][n] = __builtin_amdgcn_mfma_f32_16x16x32_bf16(a[m], b[n], acc[m][n], 0, 0, 0);
  }
#pragma unroll
  for (int n = 0; n < 4; ++n) {
    int col = j0 + n * 16 + lr;
    float av = attS[col];
#pragma unroll
    for (int m = 0; m < 4; ++m)
#pragma unroll
      for (int r = 0; r < 4; ++r) {
        int row = m * 16 + lk * 4 + r;
        float mm = acc[m][n][r] + bs2f(Xs[row][col]);
        mm = (mm > 0.f) ? mm : 0.2f * mm;
        Xs[row][col] = f2bs(mm * av);
      }
  }
  __syncthreads();
  for (int pair = tid; pair < MT * NH; pair += 256) {
    int ed = pair >> 3, h = pair & 7;
    float s = 0.f;
#pragma unroll
    for (int c = 0; c < CH; ++c) s += bs2f(Xs[ed][h * CH + c]);
    sx[(size_t)(base + ed) * NH + h] = expf(s);
  }
}

// ---- fused CSR aggregate + node output + optional LN --------------------------------
template <int ID, bool LN>
__global__ __launch_bounds__(256) void k_gat_out(
    const int* __restrict__ rowptr, const int2* __restrict__ csr,
    const float* __restrict__ sx, const bf16* __restrict__ xl,
    const float* __restrict__ x, const float* __restrict__ Wres,
    const float* __restrict__ bn, const float* __restrict__ lng,
    const float* __restrict__ lnb, float* __restrict__ xpre,
    float* __restrict__ xpost) {
  int n = blockIdx.x;
  int j = threadIdx.x;
  int h = j >> 5, c = j & 31;
  int p0 = rowptr[n], p1 = rowptr[n + 1];
  float a = 0.f, dsum = 0.f;
  for (int p = p0; p < p1; ++p) {
    int2 es = csr[p];
    float ex = sx[(size_t)es.x * NH + h];
    a += ex * b2f(xl[(size_t)es.y * HDIM + j]);
    dsum += ex;
  }
  __shared__ float oh[HDIM];
  __shared__ float rs[NH][CH];
  __shared__ float oc[CH + 1];
  oh[j] = a / (dsum + 1e-16f);
  const int KS = ID / NH;
  float r = 0.f;
  for (int k = h * KS; k < (h + 1) * KS; ++k)
    r += x[(size_t)n * ID + k] * Wres[k * CH + c];
  rs[h][c] = r;
  __syncthreads();
  if (j < CH) {
    float o = 0.f;
#pragma unroll
    for (int hh = 0; hh < NH; ++hh) o += oh[hh * CH + j];
    o *= (1.f / NH);
    float rr = 0.f;
#pragma unroll
    for (int hh = 0; hh < NH; ++hh) rr += rs[hh][j];
    o += rr + bn[j];
    xpre[(size_t)n * CH + j] = o;
    oc[j] = o;
  }
  __syncthreads();
  if (LN && j < CH) {
    float mu = 0.f;
#pragma unroll
    for (int k = 0; k < CH; ++k) mu += oc[k];
    mu *= (1.f / CH);
    float var = 0.f;
#pragma unroll
    for (int k = 0; k < CH; ++k) { float d = oc[k] - mu; var += d * d; }
    var *= (1.f / CH);
    xpost[(size_t)n * CH + j] = (oc[j] - mu) * rsqrtf(var + 1e-5f) * lng[j] + lnb[j];
  }
}

// ---- MFMA residual edge MLP ---------------------------------------------------------
__global__ __launch_bounds__(256) void k_edge_mlp_mfma(
    bf16* __restrict__ e, const float* __restrict__ xo,
    const int* __restrict__ src, const int* __restrict__ dst,
    const unsigned short* __restrict__ W1s, const float* __restrict__ bu1,
    const unsigned short* __restrict__ W2s, const float* __restrict__ bu2) {
  __shared__ unsigned short A1s[MT][328];
  __shared__ unsigned short A2s[MT][264];
  __shared__ int sidx[MT], didx[MT];
  int tid = threadIdx.x;
  int l = tid & 63;
  int wave = tid >> 6;
  int base = blockIdx.x * MT;
  int lr = l & 15;
  int lk = l >> 4;

  if (tid < MT) sidx[tid] = src[base + tid];
  else if (tid < 2 * MT) didx[tid - MT] = dst[base + tid - MT];
  __syncthreads();

  for (int t = tid; t < MT * 32; t += 256) {
    int p = t >> 5, cc = t & 31;
    uint4 v = *reinterpret_cast<const uint4*>(&e[(size_t)(base + p) * HDIM + cc * 8]);
    *reinterpret_cast<uint4*>(&A1s[p][64 + cc * 8]) = v;
  }
  for (int t = tid; t < MT * 64; t += 256) {
    int p = t >> 6, c = t & 63;
    float v = (c < CH) ? xo[(size_t)sidx[p] * CH + c]
                       : xo[(size_t)didx[p] * CH + (c - CH)];
    A1s[p][c] = f2bs(v);
  }
  __syncthreads();

  int j0 = wave * 64;

  f32x4 acc[4][4];
#pragma unroll
  for (int m = 0; m < 4; ++m)
#pragma unroll
    for (int n = 0; n < 4; ++n)
#pragma unroll
      for (int r = 0; r < 4; ++r) acc[m][n][r] = 0.f;

  for (int k0 = 0; k0 < 10; ++k0) {
    bf16x8 a[4], b[4];
#pragma unroll
    for (int m = 0; m < 4; ++m)
      a[m] = *reinterpret_cast<const bf16x8*>(&A1s[m * 16 + lr][k0 * 32 + lk * 8]);
#pragma unroll
    for (int n = 0; n < 4; ++n) {
      int nt = (j0 >> 4) + n;
      b[n] = *reinterpret_cast<const bf16x8*>(W1s + ((size_t)(nt * 10 + k0) * 64 + l) * 8);
    }
#pragma unroll
    for (int m = 0; m < 4; ++m)
#pragma unroll
      for (int n = 0; n < 4; ++n)
        acc[m][n] = __builtin_amdgcn_mfma_f32_16x16x32_bf16(a[m], b[n], acc[m][n], 0, 0, 0);
  }

#pragma unroll
  for (int n = 0; n < 4; ++n) {
    float bv = bu1[j0 + n * 16 + lr];
#pragma unroll
    for (int m = 0; m < 4; ++m)
#pragma unroll
      for (int r = 0; r < 4; ++r) {
        float xv = acc[m][n][r] + bv;
        float tnh = tanhf(0.7978845608028654f * (xv + 0.044715f * xv * xv * xv));
        float g = 0.5f * xv * (1.f + tnh);
        A2s[m * 16 + lk * 4 + r][j0 + n * 16 + lr] = f2bs(g);
      }
  }
  __syncthreads();

#pragma unroll
  for (int m = 0; m < 4; ++m)
#pragma unroll
    for (int n = 0; n < 4; ++n)
#pragma unroll
      for (int r = 0; r < 4; ++r) acc[m][n][r] = 0.f;

  for (int k0 = 0; k0 < 8; ++k0) {
    bf16x8 a[4], b[4];
#pragma unroll
    for (int m = 0; m < 4; ++m)
      a[m] = *reinterpret_cast<const bf16x8*>(&A2s[m * 16 + lr][k0 * 32 + lk * 8]);
#pragma unroll
    for (int n = 0; n < 4; ++n) {
      int nt = (j0 >> 4) + n;
      b[n] = *reinterpret_cast<const bf16x8*>(W2s + ((size_t)(nt * 8 + k0) * 64 + l) * 8);
    }
#pragma unroll
    for (int m = 0; m < 4; ++m)
#pragma unroll
      for (int n = 0; n < 4; ++n)
        acc[m][n] = __builtin_amdgcn_mfma_f32_16x16x32_bf16(a[m], b[n], acc[m][n], 0, 0, 0);
  }
  __syncthreads();

#pragma unroll
  for (int n = 0; n < 4; ++n) {
    int col = j0 + n * 16 + lr;
    float bv = bu2[col];
#pragma unroll
    for (int m = 0; m < 4; ++m)
#pragma unroll
      for (int r = 0; r < 4; ++r) {
        int row = m * 16 + lk * 4 + r;
        float eo = bs2f(A1s[row][64 + col]);
        A2s[row][col] = f2bs(eo + acc[m][n][r] + bv);
      }
  }
  __syncthreads();

  for (int t = tid; t < MT * 32; t += 256) {
    int p = t >> 5, cc = t & 31;
    *reinterpret_cast<uint4*>(&e[(size_t)(base + p) * HDIM + cc * 8]) =
        *reinterpret_cast<const uint4*>(&A2s[p][cc * 8]);
  }
}

// ---- MFMA layer-0 node projection ---------------------------------------------------
__global__ __launch_bounds__(256) void k_node_proj0_mfma(
    const float* __restrict__ x, const unsigned short* __restrict__ Wls,
    const unsigned short* __restrict__ Wrs, bf16* __restrict__ xl,
    bf16* __restrict__ xr) {
  __shared__ unsigned short A[MT][264];
  __shared__ unsigned short O[MT][264];
  int tid = threadIdx.x, l = tid & 63, w = tid >> 6;
  int lr = l & 15, lk = l >> 4;
  int base = blockIdx.x * MT;
  for (int t = tid; t < MT * 64; t += 256) {
    int p = t >> 6, c = t & 63;
    int row = base + p; if (row >= NN) row = NN - 1;
    float4 v = *reinterpret_cast<const float4*>(&x[(size_t)row * HDIM + c * 4]);
    unsigned short tmp[4] = {f2bs(v.x), f2bs(v.y), f2bs(v.z), f2bs(v.w)};
    *reinterpret_cast<uint2*>(&A[p][c * 4]) = *reinterpret_cast<const uint2*>(tmp);
  }
  __syncthreads();
  int j0 = w * 64;
#pragma unroll
  for (int mtx = 0; mtx < 2; ++mtx) {
    const unsigned short* Ws = (mtx == 0) ? Wls : Wrs;
    bf16* outp = (mtx == 0) ? xl : xr;
    f32x4 acc[4][4];
#pragma unroll
    for (int m = 0; m < 4; ++m)
#pragma unroll
      for (int n = 0; n < 4; ++n)
#pragma unroll
        for (int r = 0; r < 4; ++r) acc[m][n][r] = 0.f;
    for (int k0 = 0; k0 < 8; ++k0) {
      bf16x8 a[4], b[4];
#pragma unroll
      for (int m = 0; m < 4; ++m)
        a[m] = *reinterpret_cast<const bf16x8*>(&A[m * 16 + lr][k0 * 32 + lk * 8]);
#pragma unroll
      for (int n = 0; n < 4; ++n) {
        int nt = (j0 >> 4) + n;
        b[n] = *reinterpret_cast<const bf16x8*>(Ws + ((size_t)(nt * 8 + k0) * 64 + l) * 8);
      }
#pragma unroll
      for (int m = 0; m < 4; ++m)
#pragma unroll
        for (int n = 0; n < 4; ++n)
          acc[m][n] = __builtin_amdgcn_mfma_f32_16x16x32_bf16(a[m], b[n], acc[m][n], 0, 0, 0);
    }
#pragma unroll
    for (int n = 0; n < 4; ++n)
#pragma unroll
      for (int m = 0; m < 4; ++m)
#pragma unroll
        for (int r = 0; r < 4; ++r)
          O[m * 16 + lk * 4 + r][j0 + n * 16 + lr] = f2bs(acc[m][n][r]);
    __syncthreads();
    for (int t = tid; t < MT * 32; t += 256) {
      int p = t >> 5, c = t & 31;
      if (base + p < NN)
        *reinterpret_cast<uint4*>(&outp[(size_t)(base + p) * HDIM + c * 8]) =
            *reinterpret_cast<const uint4*>(&O[p][c * 8]);
    }
    __syncthreads();
  }
}

// ---- MFMA small node projection (layers 1..3, K=32) ---------------------------------
__global__ __launch_bounds__(256) void k_node_projS_mfma(
    const float* __restrict__ x, const unsigned short* __restrict__ Wls,
    const unsigned short* __restrict__ Wrs, bf16* __restrict__ xl,
    bf16* __restrict__ xr) {
  __shared__ unsigned short A[MT][40];
  __shared__ unsigned short O[MT][264];
  int tid = threadIdx.x, l = tid & 63, w = tid >> 6;
  int lr = l & 15, lk = l >> 4;
  int base = blockIdx.x * MT;
  for (int t = tid; t < MT * 8; t += 256) {
    int p = t >> 3, q = t & 7;
    int row = base + p; if (row >= NN) row = NN - 1;
    float4 v = *reinterpret_cast<const float4*>(&x[(size_t)row * CH + q * 4]);
    unsigned short tmp[4] = {f2bs(v.x), f2bs(v.y), f2bs(v.z), f2bs(v.w)};
    *reinterpret_cast<uint2*>(&A[p][q * 4]) = *reinterpret_cast<const uint2*>(tmp);
  }
  __syncthreads();
  int j0 = w * 64;
#pragma unroll
  for (int mtx = 0; mtx < 2; ++mtx) {
    const unsigned short* Ws = (mtx == 0) ? Wls : Wrs;
    bf16* outp = (mtx == 0) ? xl : xr;
    f32x4 acc[4][4];
#pragma unroll
    for (int m = 0; m < 4; ++m)
#pragma unroll
      for (int n = 0; n < 4; ++n)
#pragma unroll
        for (int r = 0; r < 4; ++r) acc[m][n][r] = 0.f;
    bf16x8 a[4], b[4];
#pragma unroll
    for (int m = 0; m < 4; ++m)
      a[m] = *reinterpret_cast<const bf16x8*>(&A[m * 16 + lr][lk * 8]);
#pragma unroll
    for (int n = 0; n < 4; ++n) {
      int nt = (j0 >> 4) + n;
      b[n] = *reinterpret_cast<const bf16x8*>(Ws + ((size_t)nt * 64 + l) * 8);
    }
#pragma unroll
    for (int m = 0; m < 4; ++m)
#pragma unroll
      for (int n = 0; n < 4; ++n)
        acc[m][n] = __builtin_amdgcn_mfma_f32_16x16x32_bf16(a[m], b[n], acc[m][n], 0, 0, 0);
#pragma unroll
    for (int n = 0; n < 4; ++n)
#pragma unroll
      for (int m = 0; m < 4; ++m)
#pragma unroll
        for (int r = 0; r < 4; ++r)
          O[m * 16 + lk * 4 + r][j0 + n * 16 + lr] = f2bs(acc[m][n][r]);
    __syncthreads();
    for (int t = tid; t < MT * 32; t += 256) {
      int p = t >> 5, c = t & 31;
      if (base + p < NN)
        *reinterpret_cast<uint4*>(&outp[(size_t)(base + p) * HDIM + c * 8]) =
            *reinterpret_cast<const uint4*>(&O[p][c * 8]);
    }
    __syncthreads();
  }
}

// ---- MFMA SGFormer qkv --------------------------------------------------------------
__global__ __launch_bounds__(256) void k_sg_qkv_mfma(
    const float* __restrict__ x, const unsigned short* __restrict__ Wqs,
    const unsigned short* __restrict__ Wks, const unsigned short* __restrict__ Wvs,
    bf16* __restrict__ qs, bf16* __restrict__ ks, bf16* __restrict__ vv) {
  __shared__ unsigned short A[MT][264];
  __shared__ unsigned short O[MT][264];
  int tid = threadIdx.x, l = tid & 63, w = tid >> 6;
  int lr = l & 15, lk = l >> 4;
  int base = blockIdx.x * MT;
  for (int t = tid; t < MT * 64; t += 256) {
    int p = t >> 6, c = t & 63;
    int row = base + p; if (row >= NN) row = NN - 1;
    float4 v = *reinterpret_cast<const float4*>(&x[(size_t)row * HDIM + c * 4]);
    unsigned short tmp[4] = {f2bs(v.x), f2bs(v.y), f2bs(v.z), f2bs(v.w)};
    *reinterpret_cast<uint2*>(&A[p][c * 4]) = *reinterpret_cast<const uint2*>(tmp);
  }
  __syncthreads();
  int j0 = w * 64;
#pragma unroll
  for (int mtx = 0; mtx < 3; ++mtx) {
    const unsigned short* Ws = (mtx == 0) ? Wqs : (mtx == 1) ? Wks : Wvs;
    bf16* outp = (mtx == 0) ? qs : (mtx == 1) ? ks : vv;
    f32x4 acc[4][4];
#pragma unroll
    for (int m = 0; m < 4; ++m)
#pragma unroll
      for (int n = 0; n < 4; ++n)
#pragma unroll
        for (int r = 0; r < 4; ++r) acc[m][n][r] = 0.f;
    for (int k0 = 0; k0 < 8; ++k0) {
      bf16x8 a[4], b[4];
#pragma unroll
      for (int m = 0; m < 4; ++m)
        a[m] = *reinterpret_cast<const bf16x8*>(&A[m * 16 + lr][k0 * 32 + lk * 8]);
#pragma unroll
      for (int n = 0; n < 4; ++n) {
        int nt = (j0 >> 4) + n;
        b[n] = *reinterpret_cast<const bf16x8*>(Ws + ((size_t)(nt * 8 + k0) * 64 + l) * 8);
      }
#pragma unroll
      for (int m = 0; m < 4; ++m)
#pragma unroll
        for (int n = 0; n < 4; ++n)
          acc[m][n] = __builtin_amdgcn_mfma_f32_16x16x32_bf16(a[m], b[n], acc[m][n], 0, 0, 0);
    }
    if (mtx < 2) {
      float pa[4][4], pb[4][4];
#pragma unroll
      for (int m = 0; m < 4; ++m)
#pragma unroll
        for (int r = 0; r < 4; ++r) {
          pa[m][r] = acc[m][0][r] * acc[m][0][r] + acc[m][1][r] * acc[m][1][r];
          pb[m][r] = acc[m][2][r] * acc[m][2][r] + acc[m][3][r] * acc[m][3][r];
        }
#pragma unroll
      for (int off = 1; off < 16; off <<= 1) {
#pragma unroll
        for (int m = 0; m < 4; ++m)
#pragma unroll
          for (int r = 0; r < 4; ++r) {
            pa[m][r] += __shfl_xor(pa[m][r], off);
            pb[m][r] += __shfl_xor(pb[m][r], off);
          }
      }
#pragma unroll
      for (int m = 0; m < 4; ++m)
#pragma unroll
        for (int r = 0; r < 4; ++r) {
          float ra = 1.f / (sqrtf(pa[m][r]) + 1e-6f);
          float rb = 1.f / (sqrtf(pb[m][r]) + 1e-6f);
          acc[m][0][r] *= ra; acc[m][1][r] *= ra;
          acc[m][2][r] *= rb; acc[m][3][r] *= rb;
        }
    }
#pragma unroll
    for (int n = 0; n < 4; ++n)
#pragma unroll
      for (int m = 0; m < 4; ++m)
#pragma unroll
        for (int r = 0; r < 4; ++r)
          O[m * 16 + lk * 4 + r][j0 + n * 16 + lr] = f2bs(acc[m][n][r]);
    __syncthreads();
    for (int t = tid; t < MT * 32; t += 256) {
      int p = t >> 5, c = t & 31;
      if (base + p < NN)
        *reinterpret_cast<uint4*>(&outp[(size_t)(base + p) * HDIM + c * 8]) =
            *reinterpret_cast<const uint4*>(&O[p][c * 8]);
    }
    __syncthreads();
  }
}

// ---- sg_kv stage 1: per-block partials (NO atomics) ---------------------------------
// part[b][ (h*32+c)*32+d ] , part[b][8192 + h*32+c] = ksum partial
__global__ void k_sg_kv1(const bf16* __restrict__ ks, const bf16* __restrict__ vv,
                         float* __restrict__ part) {
  int t = threadIdx.x;
  int h = t >> 5;
  float kvloc[CH];
  float ksl = 0.f;
#pragma unroll
  for (int d = 0; d < CH; ++d) kvloc[d] = 0.f;
  __shared__ float krow[HDIM], vrow[HDIM];
  for (int n = blockIdx.x; n < NN; n += KVB) {
    krow[t] = b2f(ks[(size_t)n * HDIM + t]);
    vrow[t] = b2f(vv[(size_t)n * HDIM + t]);
    __syncthreads();
    float kc = krow[t];
    ksl += kc;
#pragma unroll
    for (int d = 0; d < CH; ++d) kvloc[d] += kc * vrow[h * CH + d];
    __syncthreads();
  }
  float* dstp = part + (size_t)blockIdx.x * 8448;
#pragma unroll
  for (int d = 0; d < CH; d += 4)
    *reinterpret_cast<float4*>(&dstp[t * CH + d]) =
        *reinterpret_cast<const float4*>(&kvloc[d]);
  dstp[8192 + t] = ksl;
}

// ---- sg_kv stage 2: deterministic reduce over KVB partials --------------------------
__global__ void k_sg_kv2(const float* __restrict__ part, float* __restrict__ kv,
                         float* __restrict__ ksum) {
  int idx = blockIdx.x * 256 + threadIdx.x;
  if (idx >= 8448) return;
  float s = 0.f;
  for (int b = 0; b < KVB; ++b) s += part[(size_t)b * 8448 + idx];
  if (idx < 8192) kv[idx] = s;
  else ksum[idx - 8192] = s;
}

// ---- trans + combine + LN -> f32 out ------------------------------------------------
__global__ void k_sg_final(const bf16* __restrict__ qs, const bf16* __restrict__ vv,
                           const float* __restrict__ kv, const float* __restrict__ ksum,
                           const float* __restrict__ xg, const float* __restrict__ alphap,
                           const float* __restrict__ cng, const float* __restrict__ cnb,
                           float* __restrict__ out) {
  int t = threadIdx.x;
  int d = t & 31, sub = t >> 5;
  __shared__ float qrow[8][HDIM];
  __shared__ float crow[8][CH];
  int n = blockIdx.x * 8 + sub;
  for (int tt = t; tt < 8 * HDIM; tt += 256) {
    int p = tt >> 8, k = tt & 255;
    int n2 = blockIdx.x * 8 + p;
    if (n2 < NN) qrow[p][k] = b2f(qs[(size_t)n2 * HDIM + k]);
  }
  __syncthreads();
  float alpha = 1.f / (1.f + expf(-alphap[0]));
  const float Nf = (float)NN;
  float comb = 0.f;
  if (n < NN) {
    float acc = 0.f;
#pragma unroll
    for (int h = 0; h < NH; ++h) {
      float nm = 0.f, dp = 0.f;
#pragma unroll 8
      for (int c = 0; c < CH; ++c) {
        float qv = qrow[sub][h * CH + c];
        nm += qv * kv[(h * CH + c) * CH + d];
        dp += qv * ksum[h * CH + c];
      }
      nm += Nf * b2f(vv[(size_t)n * HDIM + h * CH + d]);
      acc += nm / (dp + Nf);
    }
    float trans = acc * (1.f / NH);
    comb = alpha * xg[(size_t)n * CH + d] + (1.f - alpha) * trans;
    crow[sub][d] = comb;
  }
  __syncthreads();
  if (n < NN) {
    float mu = 0.f;
#pragma unroll
    for (int k = 0; k < CH; ++k) mu += crow[sub][k];
    mu *= (1.f / CH);
    float var = 0.f;
#pragma unroll
    for (int k = 0; k < CH; ++k) { float dv = crow[sub][k] - mu; var += dv * dv; }
    var *= (1.f / CH);
    float o = (comb - mu) * rsqrtf(var + 1e-5f) * cng[d] + cnb[d];
    out[(size_t)n * CH + d] = o;
  }
}

extern "C" void kernel_launch(void* const* d_in, const int* in_sizes, int n_in,
                              void* d_out, int out_size, void* d_ws, size_t ws_size,
                              hipStream_t stream) {
  const float* mesh  = (const float*)d_in[0];
  const int*   eidx  = (const int*)d_in[1];
  const float* eattr = (const float*)d_in[2];
  const float* epW   = (const float*)d_in[3];
  const float* epb   = (const float*)d_in[4];
  const float* Wl0   = (const float*)d_in[5];
  const float* Wr0   = (const float*)d_in[6];
  const float* WlL   = (const float*)d_in[7];
  const float* WrL   = (const float*)d_in[8];
  const float* We0   = (const float*)d_in[9];
  const float* WeL   = (const float*)d_in[10];
  const float* att0  = (const float*)d_in[11];
  const float* attL  = (const float*)d_in[12];
  const float* Wres0 = (const float*)d_in[13];
  const float* WresL = (const float*)d_in[14];
  const float* bn0   = (const float*)d_in[15];
  const float* bnL   = (const float*)d_in[16];
  const float* Wu1_0 = (const float*)d_in[17];
  const float* Wu1L  = (const float*)d_in[18];
  const float* bu1_0 = (const float*)d_in[19];
  const float* bu1L  = (const float*)d_in[20];
  const float* Wu2_0 = (const float*)d_in[21];
  const float* Wu2L  = (const float*)d_in[22];
  const float* bu2_0 = (const float*)d_in[23];
  const float* bu2L  = (const float*)d_in[24];
  const float* lng   = (const float*)d_in[25];
  const float* lnb   = (const float*)d_in[26];
  const float* Wq    = (const float*)d_in[27];
  const float* Wk    = (const float*)d_in[28];
  const float* Wv    = (const float*)d_in[29];
  const float* alphap= (const float*)d_in[30];
  const float* cng   = (const float*)d_in[31];
  const float* cnb   = (const float*)d_in[32];

  const int* src = eidx;
  const int* dst = eidx + NE;

  char* base = (char*)d_ws;
  size_t o = 0;
  auto alloc = [&](size_t bytes) -> char* {
    o = (o + 255) & ~(size_t)255;
    char* p = base + o;
    o += bytes;
    return p;
  };
  bf16* e    = (bf16*)alloc((size_t)NE * HDIM * 2);
  bf16* xl   = (bf16*)alloc((size_t)NN * HDIM * 2);   // reused: qs
  bf16* xr   = (bf16*)alloc((size_t)NN * HDIM * 2);   // reused: ks
  bf16* vvb  = (bf16*)alloc((size_t)NN * HDIM * 2);   // SGFormer v
  float* sbuf= (float*)alloc((size_t)NE * NH * 4);    // exp(scores)
  float* xa  = (float*)alloc((size_t)NN * CH * 4);
  float* xb  = (float*)alloc((size_t)NN * CH * 4);
  float* xc  = (float*)alloc((size_t)NN * CH * 4);
  float* kv  = (float*)alloc(NH * CH * CH * 4);
  float* ksum= (float*)alloc(NH * CH * 4);
  float* kvpart = (float*)alloc((size_t)KVB * 8448 * 4);   // 17.3 MB
  unsigned short* w1s = (unsigned short*)alloc((size_t)3 * 320 * 256 * 2);
  unsigned short* w2s = (unsigned short*)alloc((size_t)3 * 256 * 256 * 2);
  unsigned short* wall= (unsigned short*)alloc((size_t)9 * 65536 * 2);
  unsigned short* w32s= (unsigned short*)alloc((size_t)6 * 32 * 256 * 2);
  int* cnt    = (int*)alloc((size_t)NN * 4);
  int* rowptr = (int*)alloc((size_t)(NN + 1) * 4);
  int* cursor = (int*)alloc((size_t)NN * 4);
  int2* csr   = (int2*)alloc((size_t)NE * 8);
  if (ws_size < o) return;   // fail cleanly if ws too small

  // pre-swizzle weights
  for (int i = 0; i < 3; ++i) {
    const float* W1 = (i == 0) ? Wu1_0 : Wu1L + (size_t)(i - 1) * 320 * 256;
    const float* W2 = (i == 0) ? Wu2_0 : Wu2L + (size_t)(i - 1) * 256 * 256;
    k_swz_w<320><<<320, 256, 0, stream>>>(W1, w1s + (size_t)i * 320 * 256);
    k_swz_w<256><<<256, 256, 0, stream>>>(W2, w2s + (size_t)i * 256 * 256);
  }
  k_swz_all<<<9 * 256, 256, 0, stream>>>(We0, WeL, Wl0, Wr0, Wq, Wk, Wv, wall);
  for (int i = 0; i < 3; ++i) {
    k_swz_w<32><<<32, 256, 0, stream>>>(WlL + (size_t)i * 32 * 256,
                                        w32s + (size_t)(i * 2 + 0) * 8192);
    k_swz_w<32><<<32, 256, 0, stream>>>(WrL + (size_t)i * 32 * 256,
                                        w32s + (size_t)(i * 2 + 1) * 8192);
  }

  // CSR build (graph constant across layers)
  k_zero_i<<<(NN + 255) / 256, 256, 0, stream>>>(cnt, NN);
  k_csr_count<<<(NE + 255) / 256, 256, 0, stream>>>(dst, cnt);
  k_csr_scan<<<1, 256, 0, stream>>>(cnt, rowptr);
  k_copy_i<<<(NN + 255) / 256, 256, 0, stream>>>(rowptr, cursor, NN);
  k_csr_fill<<<(NE + 255) / 256, 256, 0, stream>>>(src, dst, cursor, csr);

  k_edge_proj<<<NE * 32 / 256, 256, 0, stream>>>(eattr, epW, epb, e);

  const float* xin = mesh;
  float* post = xb;
  for (int l = 0; l < 4; ++l) {
    const float *att_p, *Wres_p, *bn_p, *bu1_p, *bu2_p;
    if (l == 0) {
      att_p = att0; Wres_p = Wres0; bn_p = bn0; bu1_p = bu1_0; bu2_p = bu2_0;
    } else {
      int i = l - 1;
      att_p = attL + (size_t)i * HDIM;
      Wres_p = WresL + (size_t)i * CH * CH;
      bn_p = bnL + (size_t)i * CH;
      bu1_p = bu1L + (size_t)i * HDIM;
      bu2_p = bu2L + (size_t)i * HDIM;
    }

    if (l == 0)
      k_node_proj0_mfma<<<(NN + MT - 1) / MT, 256, 0, stream>>>(
          mesh, wall + (size_t)4 * 65536, wall + (size_t)5 * 65536, xl, xr);
    else
      k_node_projS_mfma<<<(NN + MT - 1) / MT, 256, 0, stream>>>(
          xin, w32s + (size_t)((l - 1) * 2 + 0) * 8192,
          w32s + (size_t)((l - 1) * 2 + 1) * 8192, xl, xr);

    k_edge_score_mfma<<<NE / MT, 256, 0, stream>>>(e, wall + (size_t)l * 65536,
                                                   xl, xr, att_p, src, dst, sbuf);

    if (l == 0)
      k_gat_out<HDIM, true><<<NN, 256, 0, stream>>>(rowptr, csr, sbuf, xl, xin, Wres_p,
                                                    bn_p, lng, lnb, xa, post);
    else if (l < 3)
      k_gat_out<CH, true><<<NN, 256, 0, stream>>>(rowptr, csr, sbuf, xl, xin, Wres_p,
                                                  bn_p, lng + (size_t)l * CH,
                                                  lnb + (size_t)l * CH, xa, post);
    else
      k_gat_out<CH, false><<<NN, 256, 0, stream>>>(rowptr, csr, sbuf, xl, xin, Wres_p,
                                                   bn_p, nullptr, nullptr, xa, nullptr);

    if (l < 3)
      k_edge_mlp_mfma<<<NE / MT, 256, 0, stream>>>(e, xa, src, dst,
                                                   w1s + (size_t)l * 320 * 256, bu1_p,
                                                   w2s + (size_t)l * 256 * 256, bu2_p);

    xin = post;
    post = (post == xb) ? xc : xb;
  }
  // final GAT output (no LN) is in xa

  k_sg_qkv_mfma<<<(NN + MT - 1) / MT, 256, 0, stream>>>(
      mesh, wall + (size_t)6 * 65536, wall + (size_t)7 * 65536,
      wall + (size_t)8 * 65536, xl, xr, vvb);
  k_sg_kv1<<<KVB, 256, 0, stream>>>(xr, vvb, kvpart);
  k_sg_kv2<<<33, 256, 0, stream>>>(kvpart, kv, ksum);
  k_sg_final<<<(NN + 7) / 8, 256, 0, stream>>>(xl, vvb, kv, ksum, xa, alphap, cng, cnb,
                                               (float*)d_out);
}

// Round 9
// 1689.159 us; speedup vs baseline: 6.5905x; 1.2703x over previous
//
#include <hip/hip_runtime.h>
#include <hip/hip_bf16.h>
#include <math.h>

typedef __hip_bfloat16 bf16;
typedef __attribute__((ext_vector_type(8))) __bf16 bf16x8;
typedef __attribute__((ext_vector_type(4))) float f32x4;

#define NN 40962
#define NE 245760
#define HDIM 256
#define NH 8
#define CH 32

#define MT 64     // rows per block in MFMA kernels
#define KVB 512   // stage-1 blocks for sg_kv partial reduction

__device__ __forceinline__ float b2f(bf16 v) { return __bfloat162float(v); }
__device__ __forceinline__ bf16 f2b(float v) { return __float2bfloat16(v); }
__device__ __forceinline__ unsigned short f2bs(float v) {
  bf16 b = __float2bfloat16(v);
  return __builtin_bit_cast(unsigned short, b);
}
__device__ __forceinline__ float bs2f(unsigned short u) {
  return __bfloat162float(__builtin_bit_cast(bf16, u));
}

// gelu (tanh form) with native exp2: tanh(g) = (e^{2g}-1)/(e^{2g}+1)
__device__ __forceinline__ float fast_gelu(float x) {
  float x2 = x * x;
  float g = x * (0.7978845608028654f + 0.0356774081f * x2);
  float y = fminf(g * 2.885390081777927f, 60.f);   // 2*log2(e)*g, clamped
  float t = exp2f(y);
  float th = (t - 1.f) * __builtin_amdgcn_rcpf(t + 1.f);
  return 0.5f * x * (1.f + th);
}

// ---- edge input projection (vectorized): 8 cols/thread, uint4 stores ----------------
__global__ void k_edge_proj(const float* __restrict__ attr, const float* __restrict__ W,
                            const float* __restrict__ b, bf16* __restrict__ e) {
  int t = blockIdx.x * 256 + threadIdx.x;
  int ed = t >> 5;
  int q  = t & 31;
  int j0 = q * 8;
  float acc[8];
#pragma unroll
  for (int i = 0; i < 8; ++i) acc[i] = b[j0 + i];
  float ar[16];
#pragma unroll
  for (int k = 0; k < 16; ++k) ar[k] = attr[ed * 16 + k];
#pragma unroll
  for (int k = 0; k < 16; ++k) {
    float4 w0 = *reinterpret_cast<const float4*>(&W[k * HDIM + j0]);
    float4 w1 = *reinterpret_cast<const float4*>(&W[k * HDIM + j0 + 4]);
    acc[0] += ar[k] * w0.x; acc[1] += ar[k] * w0.y;
    acc[2] += ar[k] * w0.z; acc[3] += ar[k] * w0.w;
    acc[4] += ar[k] * w1.x; acc[5] += ar[k] * w1.y;
    acc[6] += ar[k] * w1.z; acc[7] += ar[k] * w1.w;
  }
  unsigned short ov[8];
#pragma unroll
  for (int i = 0; i < 8; ++i) ov[i] = f2bs(acc[i]);
  *reinterpret_cast<uint4*>(&e[(size_t)ed * HDIM + j0]) =
      *reinterpret_cast<const uint4*>(ov);
}

__global__ void k_zero_i(int* __restrict__ p, int n) {
  int i = blockIdx.x * blockDim.x + threadIdx.x;
  if (i < n) p[i] = 0;
}
__global__ void k_copy_i(const int* __restrict__ a, int* __restrict__ b, int n) {
  int i = blockIdx.x * blockDim.x + threadIdx.x;
  if (i < n) b[i] = a[i];
}

// ---- CSR build: count, scan, fill ---------------------------------------------------
__global__ void k_csr_count(const int* __restrict__ dst, int* __restrict__ cnt) {
  int e = blockIdx.x * 256 + threadIdx.x;
  if (e < NE) atomicAdd(&cnt[dst[e]], 1);
}
__global__ void k_csr_scan(const int* __restrict__ cnt, int* __restrict__ rowptr) {
  __shared__ int part[256];
  __shared__ int tot;
  int t = threadIdx.x;
  const int CHUNK = (NN + 255) / 256;
  int lo = t * CHUNK, hi = lo + CHUNK; if (hi > NN) hi = NN; if (lo > NN) lo = NN;
  int s = 0;
  for (int i = lo; i < hi; ++i) s += cnt[i];
  part[t] = s;
  __syncthreads();
  if (t == 0) {
    int run = 0;
    for (int i = 0; i < 256; ++i) { int v = part[i]; part[i] = run; run += v; }
    tot = run;
  }
  __syncthreads();
  int run = part[t];
  for (int i = lo; i < hi; ++i) { rowptr[i] = run; run += cnt[i]; }
  if (t == 0) rowptr[NN] = tot;
}
__global__ void k_csr_fill(const int* __restrict__ src, const int* __restrict__ dst,
                           int* __restrict__ cursor, int2* __restrict__ csr) {
  int e = blockIdx.x * 256 + threadIdx.x;
  if (e >= NE) return;
  int p = atomicAdd(&cursor[dst[e]], 1);
  int2 v; v.x = e; v.y = src[e];
  csr[p] = v;
}

// ---- weight swizzle into MFMA B-fragment-major layout (bf16), K-dim template --------
template <int K>
__global__ void k_swz_w(const float* __restrict__ W, unsigned short* __restrict__ out) {
  int t = blockIdx.x * 256 + threadIdx.x;
  if (t >= K * 256) return;
  int i  = t & 7;
  int l  = (t >> 3) & 63;
  int k0 = (t >> 9) % (K / 32);
  int n0 = t / (512 * (K / 32));
  int k = k0 * 32 + (l >> 4) * 8 + i;
  int n = n0 * 16 + (l & 15);
  out[t] = f2bs(W[k * 256 + n]);
}

// ---- fused swizzle of the nine 256x256 weights --------------------------------------
__global__ void k_swz_all(const float* __restrict__ We0, const float* __restrict__ WeL,
                          const float* __restrict__ Wl0, const float* __restrict__ Wr0,
                          const float* __restrict__ Wq, const float* __restrict__ Wk,
                          const float* __restrict__ Wv, unsigned short* __restrict__ dst) {
  int mat = blockIdx.x >> 8;
  int t = ((blockIdx.x & 255) << 8) | threadIdx.x;
  const float* W;
  switch (mat) {
    case 0: W = We0; break;
    case 1: W = WeL; break;
    case 2: W = WeL + 65536; break;
    case 3: W = WeL + 131072; break;
    case 4: W = Wl0; break;
    case 5: W = Wr0; break;
    case 6: W = Wq; break;
    case 7: W = Wk; break;
    default: W = Wv; break;
  }
  int i  = t & 7;
  int l  = (t >> 3) & 63;
  int k0 = (t >> 9) & 7;
  int n0 = t >> 12;
  int k = k0 * 32 + (l >> 4) * 8 + i;
  int n = n0 * 16 + (l & 15);
  dst[(size_t)mat * 65536 + t] = f2bs(W[k * 256 + n]);
}

// ---- MFMA edge score (8 waves x 32-col stripes) -> writes sx = exp(s) ---------------
__global__ __launch_bounds__(512) void k_edge_score_mfma(
    const bf16* __restrict__ e, const unsigned short* __restrict__ Wes,
    const bf16* __restrict__ xl, const bf16* __restrict__ xr,
    const float* __restrict__ att, const int* __restrict__ src,
    const int* __restrict__ dst, float* __restrict__ sx) {
  __shared__ unsigned short Ae[MT][264];
  __shared__ unsigned short Xs[MT][264];
  __shared__ float attS[HDIM];
  __shared__ int sidx[MT], didx[MT];
  int tid = threadIdx.x, l = tid & 63, w = tid >> 6;
  int lr = l & 15, lk = l >> 4;
  int base = blockIdx.x * MT;
  if (tid < HDIM) attS[tid] = att[tid];
  if (tid < MT) sidx[tid] = src[base + tid];
  else if (tid < 2 * MT) didx[tid - MT] = dst[base + tid - MT];
  __syncthreads();
  for (int t = tid; t < MT * 32; t += 512) {
    int p = t >> 5, c = t & 31;
    *reinterpret_cast<uint4*>(&Ae[p][c * 8]) =
        *reinterpret_cast<const uint4*>(&e[(size_t)(base + p) * HDIM + c * 8]);
  }
  for (int t = tid; t < MT * 32; t += 512) {
    int p = t >> 5, c = t & 31;
    uint4 ul = *reinterpret_cast<const uint4*>(&xl[(size_t)sidx[p] * HDIM + c * 8]);
    uint4 ur = *reinterpret_cast<const uint4*>(&xr[(size_t)didx[p] * HDIM + c * 8]);
    const unsigned short* al = (const unsigned short*)&ul;
    const unsigned short* ar = (const unsigned short*)&ur;
    unsigned short ov[8];
#pragma unroll
    for (int i = 0; i < 8; ++i) ov[i] = f2bs(bs2f(al[i]) + bs2f(ar[i]));
    *reinterpret_cast<uint4*>(&Xs[p][c * 8]) = *reinterpret_cast<const uint4*>(ov);
  }
  __syncthreads();

  int j0 = w * 32;
  f32x4 acc[4][2];
#pragma unroll
  for (int m = 0; m < 4; ++m)
#pragma unroll
    for (int n = 0; n < 2; ++n)
#pragma unroll
      for (int r = 0; r < 4; ++r) acc[m][n][r] = 0.f;
  for (int k0 = 0; k0 < 8; ++k0) {
    bf16x8 a[4], b[2];
#pragma unroll
    for (int m = 0; m < 4; ++m)
      a[m] = *reinterpret_cast<const bf16x8*>(&Ae[m * 16 + lr][k0 * 32 + lk * 8]);
#pragma unroll
    for (int n = 0; n < 2; ++n) {
      int nt = w * 2 + n;
      b[n] = *reinterpret_cast<const bf16x8*>(Wes + ((size_t)(nt * 8 + k0) * 64 + l) * 8);
    }
#pragma unroll
    for (int m = 0; m < 4; ++m)
#pragma unroll
      for (int n = 0; n < 2; ++n)
        acc[m][n] = __builtin_amdgcn_mfma_f32_16x16x32_bf16(a[m], b[n], acc[m][n], 0, 0, 0);
  }
#pragma unroll
  for (int n = 0; n < 2; ++n) {
    int col = j0 + n * 16 + lr;
    float av = attS[col];
#pragma unroll
    for (int m = 0; m < 4; ++m)
#pragma unroll
      for (int r = 0; r < 4; ++r) {
        int row = m * 16 + lk * 4 + r;
        float mm = acc[m][n][r] + bs2f(Xs[row][col]);
        mm = (mm > 0.f) ? mm : 0.2f * mm;
        Xs[row][col] = f2bs(mm * av);
      }
  }
  __syncthreads();
  for (int pair = tid; pair < MT * NH; pair += 512) {
    int ed = pair >> 3, h = pair & 7;
    float s = 0.f;
#pragma unroll
    for (int c = 0; c < CH; ++c) s += bs2f(Xs[ed][h * CH + c]);
    sx[(size_t)(base + ed) * NH + h] = expf(s);
  }
}

// ---- fused CSR aggregate + node output + optional LN --------------------------------
template <int ID, bool LN>
__global__ __launch_bounds__(256) void k_gat_out(
    const int* __restrict__ rowptr, const int2* __restrict__ csr,
    const float* __restrict__ sx, const bf16* __restrict__ xl,
    const float* __restrict__ x, const float* __restrict__ Wres,
    const float* __restrict__ bn, const float* __restrict__ lng,
    const float* __restrict__ lnb, float* __restrict__ xpre,
    float* __restrict__ xpost) {
  int n = blockIdx.x;
  int j = threadIdx.x;
  int h = j >> 5, c = j & 31;
  int p0 = rowptr[n], p1 = rowptr[n + 1];
  float a = 0.f, dsum = 0.f;
  for (int p = p0; p < p1; ++p) {
    int2 es = csr[p];
    float ex = sx[(size_t)es.x * NH + h];
    a += ex * b2f(xl[(size_t)es.y * HDIM + j]);
    dsum += ex;
  }
  __shared__ float oh[HDIM];
  __shared__ float rs[NH][CH];
  __shared__ float oc[CH + 1];
  oh[j] = a / (dsum + 1e-16f);
  const int KS = ID / NH;
  float r = 0.f;
  for (int k = h * KS; k < (h + 1) * KS; ++k)
    r += x[(size_t)n * ID + k] * Wres[k * CH + c];
  rs[h][c] = r;
  __syncthreads();
  if (j < CH) {
    float o = 0.f;
#pragma unroll
    for (int hh = 0; hh < NH; ++hh) o += oh[hh * CH + j];
    o *= (1.f / NH);
    float rr = 0.f;
#pragma unroll
    for (int hh = 0; hh < NH; ++hh) rr += rs[hh][j];
    o += rr + bn[j];
    xpre[(size_t)n * CH + j] = o;
    oc[j] = o;
  }
  __syncthreads();
  if (LN && j < CH) {
    float mu = 0.f;
#pragma unroll
    for (int k = 0; k < CH; ++k) mu += oc[k];
    mu *= (1.f / CH);
    float var = 0.f;
#pragma unroll
    for (int k = 0; k < CH; ++k) { float d = oc[k] - mu; var += d * d; }
    var *= (1.f / CH);
    xpost[(size_t)n * CH + j] = (oc[j] - mu) * rsqrtf(var + 1e-5f) * lng[j] + lnb[j];
  }
}

// ---- MFMA residual edge MLP (8 waves x 32-col stripes) ------------------------------
__global__ __launch_bounds__(512) void k_edge_mlp_mfma(
    bf16* __restrict__ e, const float* __restrict__ xo,
    const int* __restrict__ src, const int* __restrict__ dst,
    const unsigned short* __restrict__ W1s, const float* __restrict__ bu1,
    const unsigned short* __restrict__ W2s, const float* __restrict__ bu2) {
  __shared__ unsigned short A1s[MT][328];
  __shared__ unsigned short A2s[MT][264];
  __shared__ int sidx[MT], didx[MT];
  int tid = threadIdx.x;
  int l = tid & 63;
  int w = tid >> 6;
  int base = blockIdx.x * MT;
  int lr = l & 15;
  int lk = l >> 4;

  if (tid < MT) sidx[tid] = src[base + tid];
  else if (tid < 2 * MT) didx[tid - MT] = dst[base + tid - MT];
  __syncthreads();

  for (int t = tid; t < MT * 32; t += 512) {
    int p = t >> 5, cc = t & 31;
    uint4 v = *reinterpret_cast<const uint4*>(&e[(size_t)(base + p) * HDIM + cc * 8]);
    *reinterpret_cast<uint4*>(&A1s[p][64 + cc * 8]) = v;
  }
  for (int t = tid; t < MT * 64; t += 512) {
    int p = t >> 6, c = t & 63;
    float v = (c < CH) ? xo[(size_t)sidx[p] * CH + c]
                       : xo[(size_t)didx[p] * CH + (c - CH)];
    A1s[p][c] = f2bs(v);
  }
  __syncthreads();

  int j0 = w * 32;

  f32x4 acc[4][2];
#pragma unroll
  for (int m = 0; m < 4; ++m)
#pragma unroll
    for (int n = 0; n < 2; ++n)
#pragma unroll
      for (int r = 0; r < 4; ++r) acc[m][n][r] = 0.f;

  for (int k0 = 0; k0 < 10; ++k0) {
    bf16x8 a[4], b[2];
#pragma unroll
    for (int m = 0; m < 4; ++m)
      a[m] = *reinterpret_cast<const bf16x8*>(&A1s[m * 16 + lr][k0 * 32 + lk * 8]);
#pragma unroll
    for (int n = 0; n < 2; ++n) {
      int nt = w * 2 + n;
      b[n] = *reinterpret_cast<const bf16x8*>(W1s + ((size_t)(nt * 10 + k0) * 64 + l) * 8);
    }
#pragma unroll
    for (int m = 0; m < 4; ++m)
#pragma unroll
      for (int n = 0; n < 2; ++n)
        acc[m][n] = __builtin_amdgcn_mfma_f32_16x16x32_bf16(a[m], b[n], acc[m][n], 0, 0, 0);
  }

#pragma unroll
  for (int n = 0; n < 2; ++n) {
    float bv = bu1[j0 + n * 16 + lr];
#pragma unroll
    for (int m = 0; m < 4; ++m)
#pragma unroll
      for (int r = 0; r < 4; ++r) {
        float g = fast_gelu(acc[m][n][r] + bv);
        A2s[m * 16 + lk * 4 + r][j0 + n * 16 + lr] = f2bs(g);
      }
  }
  __syncthreads();

#pragma unroll
  for (int m = 0; m < 4; ++m)
#pragma unroll
    for (int n = 0; n < 2; ++n)
#pragma unroll
      for (int r = 0; r < 4; ++r) acc[m][n][r] = 0.f;

  for (int k0 = 0; k0 < 8; ++k0) {
    bf16x8 a[4], b[2];
#pragma unroll
    for (int m = 0; m < 4; ++m)
      a[m] = *reinterpret_cast<const bf16x8*>(&A2s[m * 16 + lr][k0 * 32 + lk * 8]);
#pragma unroll
    for (int n = 0; n < 2; ++n) {
      int nt = w * 2 + n;
      b[n] = *reinterpret_cast<const bf16x8*>(W2s + ((size_t)(nt * 8 + k0) * 64 + l) * 8);
    }
#pragma unroll
    for (int m = 0; m < 4; ++m)
#pragma unroll
      for (int n = 0; n < 2; ++n)
        acc[m][n] = __builtin_amdgcn_mfma_f32_16x16x32_bf16(a[m], b[n], acc[m][n], 0, 0, 0);
  }
  __syncthreads();   // all A2 reads done before overwrite

#pragma unroll
  for (int n = 0; n < 2; ++n) {
    int col = j0 + n * 16 + lr;
    float bv = bu2[col];
#pragma unroll
    for (int m = 0; m < 4; ++m)
#pragma unroll
      for (int r = 0; r < 4; ++r) {
        int row = m * 16 + lk * 4 + r;
        float eo = bs2f(A1s[row][64 + col]);
        A2s[row][col] = f2bs(eo + acc[m][n][r] + bv);
      }
  }
  __syncthreads();

  for (int t = tid; t < MT * 32; t += 512) {
    int p = t >> 5, cc = t & 31;
    *reinterpret_cast<uint4*>(&e[(size_t)(base + p) * HDIM + cc * 8]) =
        *reinterpret_cast<const uint4*>(&A2s[p][cc * 8]);
  }
}

// ---- MFMA layer-0 node projection ---------------------------------------------------
__global__ __launch_bounds__(256) void k_node_proj0_mfma(
    const float* __restrict__ x, const unsigned short* __restrict__ Wls,
    const unsigned short* __restrict__ Wrs, bf16* __restrict__ xl,
    bf16* __restrict__ xr) {
  __shared__ unsigned short A[MT][264];
  __shared__ unsigned short O[MT][264];
  int tid = threadIdx.x, l = tid & 63, w = tid >> 6;
  int lr = l & 15, lk = l >> 4;
  int base = blockIdx.x * MT;
  for (int t = tid; t < MT * 64; t += 256) {
    int p = t >> 6, c = t & 63;
    int row = base + p; if (row >= NN) row = NN - 1;
    float4 v = *reinterpret_cast<const float4*>(&x[(size_t)row * HDIM + c * 4]);
    unsigned short tmp[4] = {f2bs(v.x), f2bs(v.y), f2bs(v.z), f2bs(v.w)};
    *reinterpret_cast<uint2*>(&A[p][c * 4]) = *reinterpret_cast<const uint2*>(tmp);
  }
  __syncthreads();
  int j0 = w * 64;
#pragma unroll
  for (int mtx = 0; mtx < 2; ++mtx) {
    const unsigned short* Ws = (mtx == 0) ? Wls : Wrs;
    bf16* outp = (mtx == 0) ? xl : xr;
    f32x4 acc[4][4];
#pragma unroll
    for (int m = 0; m < 4; ++m)
#pragma unroll
      for (int n = 0; n < 4; ++n)
#pragma unroll
        for (int r = 0; r < 4; ++r) acc[m][n][r] = 0.f;
    for (int k0 = 0; k0 < 8; ++k0) {
      bf16x8 a[4], b[4];
#pragma unroll
      for (int m = 0; m < 4; ++m)
        a[m] = *reinterpret_cast<const bf16x8*>(&A[m * 16 + lr][k0 * 32 + lk * 8]);
#pragma unroll
      for (int n = 0; n < 4; ++n) {
        int nt = (j0 >> 4) + n;
        b[n] = *reinterpret_cast<const bf16x8*>(Ws + ((size_t)(nt * 8 + k0) * 64 + l) * 8);
      }
#pragma unroll
      for (int m = 0; m < 4; ++m)
#pragma unroll
        for (int n = 0; n < 4; ++n)
          acc[m][n] = __builtin_amdgcn_mfma_f32_16x16x32_bf16(a[m], b[n], acc[m][n], 0, 0, 0);
    }
#pragma unroll
    for (int n = 0; n < 4; ++n)
#pragma unroll
      for (int m = 0; m < 4; ++m)
#pragma unroll
        for (int r = 0; r < 4; ++r)
          O[m * 16 + lk * 4 + r][j0 + n * 16 + lr] = f2bs(acc[m][n][r]);
    __syncthreads();
    for (int t = tid; t < MT * 32; t += 256) {
      int p = t >> 5, c = t & 31;
      if (base + p < NN)
        *reinterpret_cast<uint4*>(&outp[(size_t)(base + p) * HDIM + c * 8]) =
            *reinterpret_cast<const uint4*>(&O[p][c * 8]);
    }
    __syncthreads();
  }
}

// ---- MFMA small node projection (layers 1..3, K=32) ---------------------------------
__global__ __launch_bounds__(256) void k_node_projS_mfma(
    const float* __restrict__ x, const unsigned short* __restrict__ Wls,
    const unsigned short* __restrict__ Wrs, bf16* __restrict__ xl,
    bf16* __restrict__ xr) {
  __shared__ unsigned short A[MT][40];
  __shared__ unsigned short O[MT][264];
  int tid = threadIdx.x, l = tid & 63, w = tid >> 6;
  int lr = l & 15, lk = l >> 4;
  int base = blockIdx.x * MT;
  for (int t = tid; t < MT * 8; t += 256) {
    int p = t >> 3, q = t & 7;
    int row = base + p; if (row >= NN) row = NN - 1;
    float4 v = *reinterpret_cast<const float4*>(&x[(size_t)row * CH + q * 4]);
    unsigned short tmp[4] = {f2bs(v.x), f2bs(v.y), f2bs(v.z), f2bs(v.w)};
    *reinterpret_cast<uint2*>(&A[p][q * 4]) = *reinterpret_cast<const uint2*>(tmp);
  }
  __syncthreads();
  int j0 = w * 64;
#pragma unroll
  for (int mtx = 0; mtx < 2; ++mtx) {
    const unsigned short* Ws = (mtx == 0) ? Wls : Wrs;
    bf16* outp = (mtx == 0) ? xl : xr;
    f32x4 acc[4][4];
#pragma unroll
    for (int m = 0; m < 4; ++m)
#pragma unroll
      for (int n = 0; n < 4; ++n)
#pragma unroll
        for (int r = 0; r < 4; ++r) acc[m][n][r] = 0.f;
    bf16x8 a[4], b[4];
#pragma unroll
    for (int m = 0; m < 4; ++m)
      a[m] = *reinterpret_cast<const bf16x8*>(&A[m * 16 + lr][lk * 8]);
#pragma unroll
    for (int n = 0; n < 4; ++n) {
      int nt = (j0 >> 4) + n;
      b[n] = *reinterpret_cast<const bf16x8*>(Ws + ((size_t)nt * 64 + l) * 8);
    }
#pragma unroll
    for (int m = 0; m < 4; ++m)
#pragma unroll
      for (int n = 0; n < 4; ++n)
        acc[m][n] = __builtin_amdgcn_mfma_f32_16x16x32_bf16(a[m], b[n], acc[m][n], 0, 0, 0);
#pragma unroll
    for (int n = 0; n < 4; ++n)
#pragma unroll
      for (int m = 0; m < 4; ++m)
#pragma unroll
        for (int r = 0; r < 4; ++r)
          O[m * 16 + lk * 4 + r][j0 + n * 16 + lr] = f2bs(acc[m][n][r]);
    __syncthreads();
    for (int t = tid; t < MT * 32; t += 256) {
      int p = t >> 5, c = t & 31;
      if (base + p < NN)
        *reinterpret_cast<uint4*>(&outp[(size_t)(base + p) * HDIM + c * 8]) =
            *reinterpret_cast<const uint4*>(&O[p][c * 8]);
    }
    __syncthreads();
  }
}

// ---- MFMA SGFormer qkv --------------------------------------------------------------
__global__ __launch_bounds__(256) void k_sg_qkv_mfma(
    const float* __restrict__ x, const unsigned short* __restrict__ Wqs,
    const unsigned short* __restrict__ Wks, const unsigned short* __restrict__ Wvs,
    bf16* __restrict__ qs, bf16* __restrict__ ks, bf16* __restrict__ vv) {
  __shared__ unsigned short A[MT][264];
  __shared__ unsigned short O[MT][264];
  int tid = threadIdx.x, l = tid & 63, w = tid >> 6;
  int lr = l & 15, lk = l >> 4;
  int base = blockIdx.x * MT;
  for (int t = tid; t < MT * 64; t += 256) {
    int p = t >> 6, c = t & 63;
    int row = base + p; if (row >= NN) row = NN - 1;
    float4 v = *reinterpret_cast<const float4*>(&x[(size_t)row * HDIM + c * 4]);
    unsigned short tmp[4] = {f2bs(v.x), f2bs(v.y), f2bs(v.z), f2bs(v.w)};
    *reinterpret_cast<uint2*>(&A[p][c * 4]) = *reinterpret_cast<const uint2*>(tmp);
  }
  __syncthreads();
  int j0 = w * 64;
#pragma unroll
  for (int mtx = 0; mtx < 3; ++mtx) {
    const unsigned short* Ws = (mtx == 0) ? Wqs : (mtx == 1) ? Wks : Wvs;
    bf16* outp = (mtx == 0) ? qs : (mtx == 1) ? ks : vv;
    f32x4 acc[4][4];
#pragma unroll
    for (int m = 0; m < 4; ++m)
#pragma unroll
      for (int n = 0; n < 4; ++n)
#pragma unroll
        for (int r = 0; r < 4; ++r) acc[m][n][r] = 0.f;
    for (int k0 = 0; k0 < 8; ++k0) {
      bf16x8 a[4], b[4];
#pragma unroll
      for (int m = 0; m < 4; ++m)
        a[m] = *reinterpret_cast<const bf16x8*>(&A[m * 16 + lr][k0 * 32 + lk * 8]);
#pragma unroll
      for (int n = 0; n < 4; ++n) {
        int nt = (j0 >> 4) + n;
        b[n] = *reinterpret_cast<const bf16x8*>(Ws + ((size_t)(nt * 8 + k0) * 64 + l) * 8);
      }
#pragma unroll
      for (int m = 0; m < 4; ++m)
#pragma unroll
        for (int n = 0; n < 4; ++n)
          acc[m][n] = __builtin_amdgcn_mfma_f32_16x16x32_bf16(a[m], b[n], acc[m][n], 0, 0, 0);
    }
    if (mtx < 2) {
      float pa[4][4], pb[4][4];
#pragma unroll
      for (int m = 0; m < 4; ++m)
#pragma unroll
        for (int r = 0; r < 4; ++r) {
          pa[m][r] = acc[m][0][r] * acc[m][0][r] + acc[m][1][r] * acc[m][1][r];
          pb[m][r] = acc[m][2][r] * acc[m][2][r] + acc[m][3][r] * acc[m][3][r];
        }
#pragma unroll
      for (int off = 1; off < 16; off <<= 1) {
#pragma unroll
        for (int m = 0; m < 4; ++m)
#pragma unroll
          for (int r = 0; r < 4; ++r) {
            pa[m][r] += __shfl_xor(pa[m][r], off);
            pb[m][r] += __shfl_xor(pb[m][r], off);
          }
      }
#pragma unroll
      for (int m = 0; m < 4; ++m)
#pragma unroll
        for (int r = 0; r < 4; ++r) {
          float ra = 1.f / (sqrtf(pa[m][r]) + 1e-6f);
          float rb = 1.f / (sqrtf(pb[m][r]) + 1e-6f);
          acc[m][0][r] *= ra; acc[m][1][r] *= ra;
          acc[m][2][r] *= rb; acc[m][3][r] *= rb;
        }
    }
#pragma unroll
    for (int n = 0; n < 4; ++n)
#pragma unroll
      for (int m = 0; m < 4; ++m)
#pragma unroll
        for (int r = 0; r < 4; ++r)
          O[m * 16 + lk * 4 + r][j0 + n * 16 + lr] = f2bs(acc[m][n][r]);
    __syncthreads();
    for (int t = tid; t < MT * 32; t += 256) {
      int p = t >> 5, c = t & 31;
      if (base + p < NN)
        *reinterpret_cast<uint4*>(&outp[(size_t)(base + p) * HDIM + c * 8]) =
            *reinterpret_cast<const uint4*>(&O[p][c * 8]);
    }
    __syncthreads();
  }
}

// ---- sg_kv stage 1: per-block partials (NO atomics) ---------------------------------
__global__ void k_sg_kv1(const bf16* __restrict__ ks, const bf16* __restrict__ vv,
                         float* __restrict__ part) {
  int t = threadIdx.x;
  int h = t >> 5;
  float kvloc[CH];
  float ksl = 0.f;
#pragma unroll
  for (int d = 0; d < CH; ++d) kvloc[d] = 0.f;
  __shared__ float krow[HDIM], vrow[HDIM];
  for (int n = blockIdx.x; n < NN; n += KVB) {
    krow[t] = b2f(ks[(size_t)n * HDIM + t]);
    vrow[t] = b2f(vv[(size_t)n * HDIM + t]);
    __syncthreads();
    float kc = krow[t];
    ksl += kc;
#pragma unroll
    for (int d = 0; d < CH; ++d) kvloc[d] += kc * vrow[h * CH + d];
    __syncthreads();
  }
  float* dstp = part + (size_t)blockIdx.x * 8448;
#pragma unroll
  for (int d = 0; d < CH; d += 4)
    *reinterpret_cast<float4*>(&dstp[t * CH + d]) =
        *reinterpret_cast<const float4*>(&kvloc[d]);
  dstp[8192 + t] = ksl;
}

// ---- sg_kv stage 2: deterministic reduce over KVB partials --------------------------
__global__ void k_sg_kv2(const float* __restrict__ part, float* __restrict__ kv,
                         float* __restrict__ ksum) {
  int idx = blockIdx.x * 256 + threadIdx.x;
  if (idx >= 8448) return;
  float s = 0.f;
  for (int b = 0; b < KVB; ++b) s += part[(size_t)b * 8448 + idx];
  if (idx < 8192) kv[idx] = s;
  else ksum[idx - 8192] = s;
}

// ---- trans + combine + LN -> f32 out ------------------------------------------------
__global__ void k_sg_final(const bf16* __restrict__ qs, const bf16* __restrict__ vv,
                           const float* __restrict__ kv, const float* __restrict__ ksum,
                           const float* __restrict__ xg, const float* __restrict__ alphap,
                           const float* __restrict__ cng, const float* __restrict__ cnb,
                           float* __restrict__ out) {
  int t = threadIdx.x;
  int d = t & 31, sub = t >> 5;
  __shared__ float qrow[8][HDIM];
  __shared__ float crow[8][CH];
  int n = blockIdx.x * 8 + sub;
  for (int tt = t; tt < 8 * HDIM; tt += 256) {
    int p = tt >> 8, k = tt & 255;
    int n2 = blockIdx.x * 8 + p;
    if (n2 < NN) qrow[p][k] = b2f(qs[(size_t)n2 * HDIM + k]);
  }
  __syncthreads();
  float alpha = 1.f / (1.f + expf(-alphap[0]));
  const float Nf = (float)NN;
  float comb = 0.f;
  if (n < NN) {
    float acc = 0.f;
#pragma unroll
    for (int h = 0; h < NH; ++h) {
      float nm = 0.f, dp = 0.f;
#pragma unroll 8
      for (int c = 0; c < CH; ++c) {
        float qv = qrow[sub][h * CH + c];
        nm += qv * kv[(h * CH + c) * CH + d];
        dp += qv * ksum[h * CH + c];
      }
      nm += Nf * b2f(vv[(size_t)n * HDIM + h * CH + d]);
      acc += nm / (dp + Nf);
    }
    float trans = acc * (1.f / NH);
    comb = alpha * xg[(size_t)n * CH + d] + (1.f - alpha) * trans;
    crow[sub][d] = comb;
  }
  __syncthreads();
  if (n < NN) {
    float mu = 0.f;
#pragma unroll
    for (int k = 0; k < CH; ++k) mu += crow[sub][k];
    mu *= (1.f / CH);
    float var = 0.f;
#pragma unroll
    for (int k = 0; k < CH; ++k) { float dv = crow[sub][k] - mu; var += dv * dv; }
    var *= (1.f / CH);
    float o = (comb - mu) * rsqrtf(var + 1e-5f) * cng[d] + cnb[d];
    out[(size_t)n * CH + d] = o;
  }
}

extern "C" void kernel_launch(void* const* d_in, const int* in_sizes, int n_in,
                              void* d_out, int out_size, void* d_ws, size_t ws_size,
                              hipStream_t stream) {
  const float* mesh  = (const float*)d_in[0];
  const int*   eidx  = (const int*)d_in[1];
  const float* eattr = (const float*)d_in[2];
  const float* epW   = (const float*)d_in[3];
  const float* epb   = (const float*)d_in[4];
  const float* Wl0   = (const float*)d_in[5];
  const float* Wr0   = (const float*)d_in[6];
  const float* WlL   = (const float*)d_in[7];
  const float* WrL   = (const float*)d_in[8];
  const float* We0   = (const float*)d_in[9];
  const float* WeL   = (const float*)d_in[10];
  const float* att0  = (const float*)d_in[11];
  const float* attL  = (const float*)d_in[12];
  const float* Wres0 = (const float*)d_in[13];
  const float* WresL = (const float*)d_in[14];
  const float* bn0   = (const float*)d_in[15];
  const float* bnL   = (const float*)d_in[16];
  const float* Wu1_0 = (const float*)d_in[17];
  const float* Wu1L  = (const float*)d_in[18];
  const float* bu1_0 = (const float*)d_in[19];
  const float* bu1L  = (const float*)d_in[20];
  const float* Wu2_0 = (const float*)d_in[21];
  const float* Wu2L  = (const float*)d_in[22];
  const float* bu2_0 = (const float*)d_in[23];
  const float* bu2L  = (const float*)d_in[24];
  const float* lng   = (const float*)d_in[25];
  const float* lnb   = (const float*)d_in[26];
  const float* Wq    = (const float*)d_in[27];
  const float* Wk    = (const float*)d_in[28];
  const float* Wv    = (const float*)d_in[29];
  const float* alphap= (const float*)d_in[30];
  const float* cng   = (const float*)d_in[31];
  const float* cnb   = (const float*)d_in[32];

  const int* src = eidx;
  const int* dst = eidx + NE;

  char* base = (char*)d_ws;
  size_t o = 0;
  auto alloc = [&](size_t bytes) -> char* {
    o = (o + 255) & ~(size_t)255;
    char* p = base + o;
    o += bytes;
    return p;
  };
  bf16* e    = (bf16*)alloc((size_t)NE * HDIM * 2);
  bf16* xl   = (bf16*)alloc((size_t)NN * HDIM * 2);   // reused: qs
  bf16* xr   = (bf16*)alloc((size_t)NN * HDIM * 2);   // reused: ks
  bf16* vvb  = (bf16*)alloc((size_t)NN * HDIM * 2);   // SGFormer v
  float* sbuf= (float*)alloc((size_t)NE * NH * 4);    // exp(scores)
  float* xa  = (float*)alloc((size_t)NN * CH * 4);
  float* xb  = (float*)alloc((size_t)NN * CH * 4);
  float* xc  = (float*)alloc((size_t)NN * CH * 4);
  float* kv  = (float*)alloc(NH * CH * CH * 4);
  float* ksum= (float*)alloc(NH * CH * 4);
  float* kvpart = (float*)alloc((size_t)KVB * 8448 * 4);   // 17.3 MB
  unsigned short* w1s = (unsigned short*)alloc((size_t)3 * 320 * 256 * 2);
  unsigned short* w2s = (unsigned short*)alloc((size_t)3 * 256 * 256 * 2);
  unsigned short* wall= (unsigned short*)alloc((size_t)9 * 65536 * 2);
  unsigned short* w32s= (unsigned short*)alloc((size_t)6 * 32 * 256 * 2);
  int* cnt    = (int*)alloc((size_t)NN * 4);
  int* rowptr = (int*)alloc((size_t)(NN + 1) * 4);
  int* cursor = (int*)alloc((size_t)NN * 4);
  int2* csr   = (int2*)alloc((size_t)NE * 8);
  if (ws_size < o) return;   // fail cleanly if ws too small

  // pre-swizzle weights
  for (int i = 0; i < 3; ++i) {
    const float* W1 = (i == 0) ? Wu1_0 : Wu1L + (size_t)(i - 1) * 320 * 256;
    const float* W2 = (i == 0) ? Wu2_0 : Wu2L + (size_t)(i - 1) * 256 * 256;
    k_swz_w<320><<<320, 256, 0, stream>>>(W1, w1s + (size_t)i * 320 * 256);
    k_swz_w<256><<<256, 256, 0, stream>>>(W2, w2s + (size_t)i * 256 * 256);
  }
  k_swz_all<<<9 * 256, 256, 0, stream>>>(We0, WeL, Wl0, Wr0, Wq, Wk, Wv, wall);
  for (int i = 0; i < 3; ++i) {
    k_swz_w<32><<<32, 256, 0, stream>>>(WlL + (size_t)i * 32 * 256,
                                        w32s + (size_t)(i * 2 + 0) * 8192);
    k_swz_w<32><<<32, 256, 0, stream>>>(WrL + (size_t)i * 32 * 256,
                                        w32s + (size_t)(i * 2 + 1) * 8192);
  }

  // CSR build (graph constant across layers)
  k_zero_i<<<(NN + 255) / 256, 256, 0, stream>>>(cnt, NN);
  k_csr_count<<<(NE + 255) / 256, 256, 0, stream>>>(dst, cnt);
  k_csr_scan<<<1, 256, 0, stream>>>(cnt, rowptr);
  k_copy_i<<<(NN + 255) / 256, 256, 0, stream>>>(rowptr, cursor, NN);
  k_csr_fill<<<(NE + 255) / 256, 256, 0, stream>>>(src, dst, cursor, csr);

  k_edge_proj<<<NE * 32 / 256, 256, 0, stream>>>(eattr, epW, epb, e);

  const float* xin = mesh;
  float* post = xb;
  for (int l = 0; l < 4; ++l) {
    const float *att_p, *Wres_p, *bn_p, *bu1_p, *bu2_p;
    if (l == 0) {
      att_p = att0; Wres_p = Wres0; bn_p = bn0; bu1_p = bu1_0; bu2_p = bu2_0;
    } else {
      int i = l - 1;
      att_p = attL + (size_t)i * HDIM;
      Wres_p = WresL + (size_t)i * CH * CH;
      bn_p = bnL + (size_t)i * CH;
      bu1_p = bu1L + (size_t)i * HDIM;
      bu2_p = bu2L + (size_t)i * HDIM;
    }

    if (l == 0)
      k_node_proj0_mfma<<<(NN + MT - 1) / MT, 256, 0, stream>>>(
          mesh, wall + (size_t)4 * 65536, wall + (size_t)5 * 65536, xl, xr);
    else
      k_node_projS_mfma<<<(NN + MT - 1) / MT, 256, 0, stream>>>(
          xin, w32s + (size_t)((l - 1) * 2 + 0) * 8192,
          w32s + (size_t)((l - 1) * 2 + 1) * 8192, xl, xr);

    k_edge_score_mfma<<<NE / MT, 512, 0, stream>>>(e, wall + (size_t)l * 65536,
                                                   xl, xr, att_p, src, dst, sbuf);

    if (l == 0)
      k_gat_out<HDIM, true><<<NN, 256, 0, stream>>>(rowptr, csr, sbuf, xl, xin, Wres_p,
                                                    bn_p, lng, lnb, xa, post);
    else if (l < 3)
      k_gat_out<CH, true><<<NN, 256, 0, stream>>>(rowptr, csr, sbuf, xl, xin, Wres_p,
                                                  bn_p, lng + (size_t)l * CH,
                                                  lnb + (size_t)l * CH, xa, post);
    else
      k_gat_out<CH, false><<<NN, 256, 0, stream>>>(rowptr, csr, sbuf, xl, xin, Wres_p,
                                                   bn_p, nullptr, nullptr, xa, nullptr);

    if (l < 3)
      k_edge_mlp_mfma<<<NE / MT, 512, 0, stream>>>(e, xa, src, dst,
                                                   w1s + (size_t)l * 320 * 256, bu1_p,
                                                   w2s + (size_t)l * 256 * 256, bu2_p);

    xin = post;
    post = (post == xb) ? xc : xb;
  }
  // final GAT output (no LN) is in xa

  k_sg_qkv_mfma<<<(NN + MT - 1) / MT, 256, 0, stream>>>(
      mesh, wall + (size_t)6 * 65536, wall + (size_t)7 * 65536,
      wall + (size_t)8 * 65536, xl, xr, vvb);
  k_sg_kv1<<<KVB, 256, 0, stream>>>(xr, vvb, kvpart);
  k_sg_kv2<<<33, 256, 0, stream>>>(kvpart, kv, ksum);
  k_sg_final<<<(NN + 7) / 8, 256, 0, stream>>>(xl, vvb, kv, ksum, xa, alphap, cng, cnb,
                                               (float*)d_out);
}

// Round 10
// 1600.832 us; speedup vs baseline: 6.9541x; 1.0552x over previous
//
#include <hip/hip_runtime.h>
#include <hip/hip_bf16.h>
#include <math.h>

typedef __hip_bfloat16 bf16;
typedef __attribute__((ext_vector_type(8))) __bf16 bf16x8;
typedef __attribute__((ext_vector_type(4))) float f32x4;

#define NN 40962
#define NE 245760
#define HDIM 256
#define NH 8
#define CH 32

#define MT 64     // rows per block in MFMA kernels
#define KVB 512   // stage-1 blocks for sg_kv partial reduction

__device__ __forceinline__ float b2f(bf16 v) { return __bfloat162float(v); }
__device__ __forceinline__ bf16 f2b(float v) { return __float2bfloat16(v); }
__device__ __forceinline__ unsigned short f2bs(float v) {
  bf16 b = __float2bfloat16(v);
  return __builtin_bit_cast(unsigned short, b);
}
__device__ __forceinline__ float bs2f(unsigned short u) {
  return __bfloat162float(__builtin_bit_cast(bf16, u));
}

// gelu (tanh form) with native exp2: tanh(g) = (e^{2g}-1)/(e^{2g}+1)
__device__ __forceinline__ float fast_gelu(float x) {
  float x2 = x * x;
  float g = x * (0.7978845608028654f + 0.0356774081f * x2);
  float y = fminf(g * 2.885390081777927f, 60.f);   // 2*log2(e)*g, clamped
  float t = exp2f(y);
  float th = (t - 1.f) * __builtin_amdgcn_rcpf(t + 1.f);
  return 0.5f * x * (1.f + th);
}

// ---- edge input projection (vectorized): 8 cols/thread, uint4 stores ----------------
__global__ void k_edge_proj(const float* __restrict__ attr, const float* __restrict__ W,
                            const float* __restrict__ b, bf16* __restrict__ e) {
  int t = blockIdx.x * 256 + threadIdx.x;
  int ed = t >> 5;
  int q  = t & 31;
  int j0 = q * 8;
  float acc[8];
#pragma unroll
  for (int i = 0; i < 8; ++i) acc[i] = b[j0 + i];
  float ar[16];
#pragma unroll
  for (int k = 0; k < 16; ++k) ar[k] = attr[ed * 16 + k];
#pragma unroll
  for (int k = 0; k < 16; ++k) {
    float4 w0 = *reinterpret_cast<const float4*>(&W[k * HDIM + j0]);
    float4 w1 = *reinterpret_cast<const float4*>(&W[k * HDIM + j0 + 4]);
    acc[0] += ar[k] * w0.x; acc[1] += ar[k] * w0.y;
    acc[2] += ar[k] * w0.z; acc[3] += ar[k] * w0.w;
    acc[4] += ar[k] * w1.x; acc[5] += ar[k] * w1.y;
    acc[6] += ar[k] * w1.z; acc[7] += ar[k] * w1.w;
  }
  unsigned short ov[8];
#pragma unroll
  for (int i = 0; i < 8; ++i) ov[i] = f2bs(acc[i]);
  *reinterpret_cast<uint4*>(&e[(size_t)ed * HDIM + j0]) =
      *reinterpret_cast<const uint4*>(ov);
}

// ---- CSR build: count, scan(+cursor), fill ------------------------------------------
__global__ void k_csr_count(const int* __restrict__ dst, int* __restrict__ cnt) {
  int e = blockIdx.x * 256 + threadIdx.x;
  if (e < NE) atomicAdd(&cnt[dst[e]], 1);
}
__global__ void k_csr_scan(const int* __restrict__ cnt, int* __restrict__ rowptr,
                           int* __restrict__ cursor) {
  __shared__ int part[256];
  __shared__ int tot;
  int t = threadIdx.x;
  const int CHUNK = (NN + 255) / 256;
  int lo = t * CHUNK, hi = lo + CHUNK; if (hi > NN) hi = NN; if (lo > NN) lo = NN;
  int s = 0;
  for (int i = lo; i < hi; ++i) s += cnt[i];
  part[t] = s;
  __syncthreads();
  if (t == 0) {
    int run = 0;
    for (int i = 0; i < 256; ++i) { int v = part[i]; part[i] = run; run += v; }
    tot = run;
  }
  __syncthreads();
  int run = part[t];
  for (int i = lo; i < hi; ++i) { rowptr[i] = run; cursor[i] = run; run += cnt[i]; }
  if (t == 0) rowptr[NN] = tot;
}
__global__ void k_csr_fill(const int* __restrict__ src, const int* __restrict__ dst,
                           int* __restrict__ cursor, int2* __restrict__ csr) {
  int e = blockIdx.x * 256 + threadIdx.x;
  if (e >= NE) return;
  int p = atomicAdd(&cursor[dst[e]], 1);
  int2 v; v.x = e; v.y = src[e];
  csr[p] = v;
}

// ---- fused weight swizzle (all matrices) + cnt zeroing ------------------------------
struct SwzP {
  const float *We0, *WeL, *Wl0, *Wr0, *Wq, *Wk, *Wv;
  const float *Wu1_0, *Wu1L, *Wu2_0, *Wu2L, *WlL, *WrL;
  unsigned short *wall, *w1s, *w2s, *w32s;
  int* cnt;
};
__device__ __forceinline__ void swz1(const float* __restrict__ W,
                                     unsigned short* __restrict__ out, int t, int Kdiv32) {
  int i = t & 7, l = (t >> 3) & 63;
  int k0 = (t >> 9) % Kdiv32;
  int n0 = t / (512 * Kdiv32);
  int k = k0 * 32 + (l >> 4) * 8 + i;
  int n = n0 * 16 + (l & 15);
  out[t] = f2bs(W[k * 256 + n]);
}
#define SWZ_NW (9 * 65536)
#define SWZ_N1 (3 * 81920)
#define SWZ_N2 (3 * 65536)
#define SWZ_N3 (6 * 8192)
__global__ void k_swz_fused(SwzP P) {
  int gid = blockIdx.x * 256 + threadIdx.x;
  if (gid < SWZ_NW) {
    int mat = gid >> 16, t = gid & 65535;
    const float* W;
    switch (mat) {
      case 0: W = P.We0; break;
      case 1: W = P.WeL; break;
      case 2: W = P.WeL + 65536; break;
      case 3: W = P.WeL + 131072; break;
      case 4: W = P.Wl0; break;
      case 5: W = P.Wr0; break;
      case 6: W = P.Wq; break;
      case 7: W = P.Wk; break;
      default: W = P.Wv; break;
    }
    swz1(W, P.wall + (size_t)mat * 65536, t, 8);
  } else if (gid < SWZ_NW + SWZ_N1) {
    int idx = gid - SWZ_NW;
    int mat = idx / 81920, t = idx % 81920;
    const float* W = (mat == 0) ? P.Wu1_0 : P.Wu1L + (size_t)(mat - 1) * 81920;
    swz1(W, P.w1s + (size_t)mat * 81920, t, 10);
  } else if (gid < SWZ_NW + SWZ_N1 + SWZ_N2) {
    int idx = gid - SWZ_NW - SWZ_N1;
    int mat = idx >> 16, t = idx & 65535;
    const float* W = (mat == 0) ? P.Wu2_0 : P.Wu2L + (size_t)(mat - 1) * 65536;
    swz1(W, P.w2s + (size_t)mat * 65536, t, 8);
  } else if (gid < SWZ_NW + SWZ_N1 + SWZ_N2 + SWZ_N3) {
    int idx = gid - SWZ_NW - SWZ_N1 - SWZ_N2;
    int mat = idx >> 13, t = idx & 8191;
    int i = mat >> 1;
    const float* W = (mat & 1) ? P.WrL + (size_t)i * 8192 : P.WlL + (size_t)i * 8192;
    swz1(W, P.w32s + (size_t)mat * 8192, t, 1);
  } else {
    int i = gid - (SWZ_NW + SWZ_N1 + SWZ_N2 + SWZ_N3);
    if (i < NN) P.cnt[i] = 0;
  }
}

// ---- MFMA edge score (8 waves x 32-col stripes, aliased LDS) -> sx = exp(s) ---------
__global__ __launch_bounds__(512) void k_edge_score_mfma(
    const bf16* __restrict__ e, const unsigned short* __restrict__ Wes,
    const bf16* __restrict__ xl, const bf16* __restrict__ xr,
    const float* __restrict__ att, const int* __restrict__ src,
    const int* __restrict__ dst, float* __restrict__ sx) {
  __shared__ unsigned short Ae[MT][264];   // e-tile, then reused as scoreboard
  __shared__ float attS[HDIM];
  __shared__ int sidx[MT], didx[MT];
  int tid = threadIdx.x, l = tid & 63, w = tid >> 6;
  int lr = l & 15, lk = l >> 4;
  int base = blockIdx.x * MT;
  if (tid < HDIM) attS[tid] = att[tid];
  if (tid < MT) sidx[tid] = src[base + tid];
  else if (tid < 2 * MT) didx[tid - MT] = dst[base + tid - MT];
  for (int t = tid; t < MT * 32; t += 512) {
    int p = t >> 5, c = t & 31;
    *reinterpret_cast<uint4*>(&Ae[p][c * 8]) =
        *reinterpret_cast<const uint4*>(&e[(size_t)(base + p) * HDIM + c * 8]);
  }
  __syncthreads();

  f32x4 acc[4][2];
#pragma unroll
  for (int m = 0; m < 4; ++m)
#pragma unroll
    for (int n = 0; n < 2; ++n)
#pragma unroll
      for (int r = 0; r < 4; ++r) acc[m][n][r] = 0.f;
  for (int k0 = 0; k0 < 8; ++k0) {
    bf16x8 a[4], b[2];
#pragma unroll
    for (int m = 0; m < 4; ++m)
      a[m] = *reinterpret_cast<const bf16x8*>(&Ae[m * 16 + lr][k0 * 32 + lk * 8]);
#pragma unroll
    for (int n = 0; n < 2; ++n) {
      int nt = w * 2 + n;
      b[n] = *reinterpret_cast<const bf16x8*>(Wes + ((size_t)(nt * 8 + k0) * 64 + l) * 8);
    }
#pragma unroll
    for (int m = 0; m < 4; ++m)
#pragma unroll
      for (int n = 0; n < 2; ++n)
        acc[m][n] = __builtin_amdgcn_mfma_f32_16x16x32_bf16(a[m], b[n], acc[m][n], 0, 0, 0);
  }
  __syncthreads();   // all Ae reads complete before scoreboard overwrite

  // epilogue: xl/xr read directly from global (L2-hot), scoreboard into Ae alias
#pragma unroll
  for (int n = 0; n < 2; ++n) {
    int col = w * 32 + n * 16 + lr;
    float av = attS[col];
#pragma unroll
    for (int m = 0; m < 4; ++m)
#pragma unroll
      for (int r = 0; r < 4; ++r) {
        int row = m * 16 + lk * 4 + r;
        float xs = b2f(xl[(size_t)sidx[row] * HDIM + col]) +
                   b2f(xr[(size_t)didx[row] * HDIM + col]);
        float mm = acc[m][n][r] + xs;
        mm = (mm > 0.f) ? mm : 0.2f * mm;
        Ae[row][col] = f2bs(mm * av);
      }
  }
  __syncthreads();
  for (int pair = tid; pair < MT * NH; pair += 512) {
    int ed = pair >> 3, h = pair & 7;
    float s = 0.f;
#pragma unroll
    for (int c = 0; c < CH; ++c) s += bs2f(Ae[ed][h * CH + c]);
    sx[(size_t)(base + ed) * NH + h] = expf(s);
  }
}

// ---- fused CSR aggregate + node output + optional LN --------------------------------
template <int ID, bool LN>
__global__ __launch_bounds__(256) void k_gat_out(
    const int* __restrict__ rowptr, const int2* __restrict__ csr,
    const float* __restrict__ sx, const bf16* __restrict__ xl,
    const float* __restrict__ x, const float* __restrict__ Wres,
    const float* __restrict__ bn, const float* __restrict__ lng,
    const float* __restrict__ lnb, float* __restrict__ xpre,
    float* __restrict__ xpost) {
  int n = blockIdx.x;
  int j = threadIdx.x;
  int h = j >> 5, c = j & 31;
  int p0 = rowptr[n], p1 = rowptr[n + 1];
  float a = 0.f, dsum = 0.f;
  for (int p = p0; p < p1; ++p) {
    int2 es = csr[p];
    float ex = sx[(size_t)es.x * NH + h];
    a += ex * b2f(xl[(size_t)es.y * HDIM + j]);
    dsum += ex;
  }
  __shared__ float oh[HDIM];
  __shared__ float rs[NH][CH];
  __shared__ float oc[CH + 1];
  oh[j] = a / (dsum + 1e-16f);
  const int KS = ID / NH;
  float r = 0.f;
  for (int k = h * KS; k < (h + 1) * KS; ++k)
    r += x[(size_t)n * ID + k] * Wres[k * CH + c];
  rs[h][c] = r;
  __syncthreads();
  if (j < CH) {
    float o = 0.f;
#pragma unroll
    for (int hh = 0; hh < NH; ++hh) o += oh[hh * CH + j];
    o *= (1.f / NH);
    float rr = 0.f;
#pragma unroll
    for (int hh = 0; hh < NH; ++hh) rr += rs[hh][j];
    o += rr + bn[j];
    xpre[(size_t)n * CH + j] = o;
    oc[j] = o;
  }
  __syncthreads();
  if (LN && j < CH) {
    float mu = 0.f;
#pragma unroll
    for (int k = 0; k < CH; ++k) mu += oc[k];
    mu *= (1.f / CH);
    float var = 0.f;
#pragma unroll
    for (int k = 0; k < CH; ++k) { float d = oc[k] - mu; var += d * d; }
    var *= (1.f / CH);
    xpost[(size_t)n * CH + j] = (oc[j] - mu) * rsqrtf(var + 1e-5f) * lng[j] + lnb[j];
  }
}

// ---- MFMA residual edge MLP (8 waves, single aliased 42KB LDS buffer) ---------------
__global__ __launch_bounds__(512) void k_edge_mlp_mfma(
    bf16* __restrict__ e, const float* __restrict__ xo,
    const int* __restrict__ src, const int* __restrict__ dst,
    const unsigned short* __restrict__ W1s, const float* __restrict__ bu1,
    const unsigned short* __restrict__ W2s, const float* __restrict__ bu2) {
  __shared__ unsigned short buf[MT][328];   // A1 (xo|e), then gelu(h1), then delta
  __shared__ int sidx[MT], didx[MT];
  int tid = threadIdx.x;
  int l = tid & 63;
  int w = tid >> 6;
  int base = blockIdx.x * MT;
  int lr = l & 15;
  int lk = l >> 4;

  if (tid < MT) sidx[tid] = src[base + tid];
  else if (tid < 2 * MT) didx[tid - MT] = dst[base + tid - MT];
  __syncthreads();

  for (int t = tid; t < MT * 32; t += 512) {
    int p = t >> 5, cc = t & 31;
    uint4 v = *reinterpret_cast<const uint4*>(&e[(size_t)(base + p) * HDIM + cc * 8]);
    *reinterpret_cast<uint4*>(&buf[p][64 + cc * 8]) = v;
  }
  for (int t = tid; t < MT * 64; t += 512) {
    int p = t >> 6, c = t & 63;
    float v = (c < CH) ? xo[(size_t)sidx[p] * CH + c]
                       : xo[(size_t)didx[p] * CH + (c - CH)];
    buf[p][c] = f2bs(v);
  }
  __syncthreads();

  int j0 = w * 32;

  f32x4 acc[4][2];
#pragma unroll
  for (int m = 0; m < 4; ++m)
#pragma unroll
    for (int n = 0; n < 2; ++n)
#pragma unroll
      for (int r = 0; r < 4; ++r) acc[m][n][r] = 0.f;

  for (int k0 = 0; k0 < 10; ++k0) {
    bf16x8 a[4], b[2];
#pragma unroll
    for (int m = 0; m < 4; ++m)
      a[m] = *reinterpret_cast<const bf16x8*>(&buf[m * 16 + lr][k0 * 32 + lk * 8]);
#pragma unroll
    for (int n = 0; n < 2; ++n) {
      int nt = w * 2 + n;
      b[n] = *reinterpret_cast<const bf16x8*>(W1s + ((size_t)(nt * 10 + k0) * 64 + l) * 8);
    }
#pragma unroll
    for (int m = 0; m < 4; ++m)
#pragma unroll
      for (int n = 0; n < 2; ++n)
        acc[m][n] = __builtin_amdgcn_mfma_f32_16x16x32_bf16(a[m], b[n], acc[m][n], 0, 0, 0);
  }
  __syncthreads();   // all A1 reads complete before overwrite

  // gelu(h1 + bu1) -> buf alias (cols 0..255)
#pragma unroll
  for (int n = 0; n < 2; ++n) {
    float bv = bu1[j0 + n * 16 + lr];
#pragma unroll
    for (int m = 0; m < 4; ++m)
#pragma unroll
      for (int r = 0; r < 4; ++r) {
        float g = fast_gelu(acc[m][n][r] + bv);
        buf[m * 16 + lk * 4 + r][j0 + n * 16 + lr] = f2bs(g);
      }
  }
  __syncthreads();

#pragma unroll
  for (int m = 0; m < 4; ++m)
#pragma unroll
    for (int n = 0; n < 2; ++n)
#pragma unroll
      for (int r = 0; r < 4; ++r) acc[m][n][r] = 0.f;

  for (int k0 = 0; k0 < 8; ++k0) {
    bf16x8 a[4], b[2];
#pragma unroll
    for (int m = 0; m < 4; ++m)
      a[m] = *reinterpret_cast<const bf16x8*>(&buf[m * 16 + lr][k0 * 32 + lk * 8]);
#pragma unroll
    for (int n = 0; n < 2; ++n) {
      int nt = w * 2 + n;
      b[n] = *reinterpret_cast<const bf16x8*>(W2s + ((size_t)(nt * 8 + k0) * 64 + l) * 8);
    }
#pragma unroll
    for (int m = 0; m < 4; ++m)
#pragma unroll
      for (int n = 0; n < 2; ++n)
        acc[m][n] = __builtin_amdgcn_mfma_f32_16x16x32_bf16(a[m], b[n], acc[m][n], 0, 0, 0);
  }
  __syncthreads();   // all gelu reads done before delta overwrite

  // delta = acc + bu2 -> buf alias
#pragma unroll
  for (int n = 0; n < 2; ++n) {
    int col = j0 + n * 16 + lr;
    float bv = bu2[col];
#pragma unroll
    for (int m = 0; m < 4; ++m)
#pragma unroll
      for (int r = 0; r < 4; ++r)
        buf[m * 16 + lk * 4 + r][col] = f2bs(acc[m][n][r] + bv);
  }
  __syncthreads();

  // store: e_new = e_old (global re-read, L2-hot) + delta
  for (int t = tid; t < MT * 32; t += 512) {
    int p = t >> 5, cc = t & 31;
    uint4 dv = *reinterpret_cast<const uint4*>(&buf[p][cc * 8]);
    uint4 ev = *reinterpret_cast<const uint4*>(&e[(size_t)(base + p) * HDIM + cc * 8]);
    const unsigned short* dd = (const unsigned short*)&dv;
    const unsigned short* ee = (const unsigned short*)&ev;
    unsigned short ov[8];
#pragma unroll
    for (int i = 0; i < 8; ++i) ov[i] = f2bs(bs2f(ee[i]) + bs2f(dd[i]));
    *reinterpret_cast<uint4*>(&e[(size_t)(base + p) * HDIM + cc * 8]) =
        *reinterpret_cast<const uint4*>(ov);
  }
}

// ---- MFMA layer-0 node projection ---------------------------------------------------
__global__ __launch_bounds__(256) void k_node_proj0_mfma(
    const float* __restrict__ x, const unsigned short* __restrict__ Wls,
    const unsigned short* __restrict__ Wrs, bf16* __restrict__ xl,
    bf16* __restrict__ xr) {
  __shared__ unsigned short A[MT][264];
  __shared__ unsigned short O[MT][264];
  int tid = threadIdx.x, l = tid & 63, w = tid >> 6;
  int lr = l & 15, lk = l >> 4;
  int base = blockIdx.x * MT;
  for (int t = tid; t < MT * 64; t += 256) {
    int p = t >> 6, c = t & 63;
    int row = base + p; if (row >= NN) row = NN - 1;
    float4 v = *reinterpret_cast<const float4*>(&x[(size_t)row * HDIM + c * 4]);
    unsigned short tmp[4] = {f2bs(v.x), f2bs(v.y), f2bs(v.z), f2bs(v.w)};
    *reinterpret_cast<uint2*>(&A[p][c * 4]) = *reinterpret_cast<const uint2*>(tmp);
  }
  __syncthreads();
  int j0 = w * 64;
#pragma unroll
  for (int mtx = 0; mtx < 2; ++mtx) {
    const unsigned short* Ws = (mtx == 0) ? Wls : Wrs;
    bf16* outp = (mtx == 0) ? xl : xr;
    f32x4 acc[4][4];
#pragma unroll
    for (int m = 0; m < 4; ++m)
#pragma unroll
      for (int n = 0; n < 4; ++n)
#pragma unroll
        for (int r = 0; r < 4; ++r) acc[m][n][r] = 0.f;
    for (int k0 = 0; k0 < 8; ++k0) {
      bf16x8 a[4], b[4];
#pragma unroll
      for (int m = 0; m < 4; ++m)
        a[m] = *reinterpret_cast<const bf16x8*>(&A[m * 16 + lr][k0 * 32 + lk * 8]);
#pragma unroll
      for (int n = 0; n < 4; ++n) {
        int nt = (j0 >> 4) + n;
        b[n] = *reinterpret_cast<const bf16x8*>(Ws + ((size_t)(nt * 8 + k0) * 64 + l) * 8);
      }
#pragma unroll
      for (int m = 0; m < 4; ++m)
#pragma unroll
        for (int n = 0; n < 4; ++n)
          acc[m][n] = __builtin_amdgcn_mfma_f32_16x16x32_bf16(a[m], b[n], acc[m][n], 0, 0, 0);
    }
#pragma unroll
    for (int n = 0; n < 4; ++n)
#pragma unroll
      for (int m = 0; m < 4; ++m)
#pragma unroll
        for (int r = 0; r < 4; ++r)
          O[m * 16 + lk * 4 + r][j0 + n * 16 + lr] = f2bs(acc[m][n][r]);
    __syncthreads();
    for (int t = tid; t < MT * 32; t += 256) {
      int p = t >> 5, c = t & 31;
      if (base + p < NN)
        *reinterpret_cast<uint4*>(&outp[(size_t)(base + p) * HDIM + c * 8]) =
            *reinterpret_cast<const uint4*>(&O[p][c * 8]);
    }
    __syncthreads();
  }
}

// ---- MFMA small node projection (layers 1..3, K=32) ---------------------------------
__global__ __launch_bounds__(256) void k_node_projS_mfma(
    const float* __restrict__ x, const unsigned short* __restrict__ Wls,
    const unsigned short* __restrict__ Wrs, bf16* __restrict__ xl,
    bf16* __restrict__ xr) {
  __shared__ unsigned short A[MT][40];
  __shared__ unsigned short O[MT][264];
  int tid = threadIdx.x, l = tid & 63, w = tid >> 6;
  int lr = l & 15, lk = l >> 4;
  int base = blockIdx.x * MT;
  for (int t = tid; t < MT * 8; t += 256) {
    int p = t >> 3, q = t & 7;
    int row = base + p; if (row >= NN) row = NN - 1;
    float4 v = *reinterpret_cast<const float4*>(&x[(size_t)row * CH + q * 4]);
    unsigned short tmp[4] = {f2bs(v.x), f2bs(v.y), f2bs(v.z), f2bs(v.w)};
    *reinterpret_cast<uint2*>(&A[p][q * 4]) = *reinterpret_cast<const uint2*>(tmp);
  }
  __syncthreads();
  int j0 = w * 64;
#pragma unroll
  for (int mtx = 0; mtx < 2; ++mtx) {
    const unsigned short* Ws = (mtx == 0) ? Wls : Wrs;
    bf16* outp = (mtx == 0) ? xl : xr;
    f32x4 acc[4][4];
#pragma unroll
    for (int m = 0; m < 4; ++m)
#pragma unroll
      for (int n = 0; n < 4; ++n)
#pragma unroll
        for (int r = 0; r < 4; ++r) acc[m][n][r] = 0.f;
    bf16x8 a[4], b[4];
#pragma unroll
    for (int m = 0; m < 4; ++m)
      a[m] = *reinterpret_cast<const bf16x8*>(&A[m * 16 + lr][lk * 8]);
#pragma unroll
    for (int n = 0; n < 4; ++n) {
      int nt = (j0 >> 4) + n;
      b[n] = *reinterpret_cast<const bf16x8*>(Ws + ((size_t)nt * 64 + l) * 8);
    }
#pragma unroll
    for (int m = 0; m < 4; ++m)
#pragma unroll
      for (int n = 0; n < 4; ++n)
        acc[m][n] = __builtin_amdgcn_mfma_f32_16x16x32_bf16(a[m], b[n], acc[m][n], 0, 0, 0);
#pragma unroll
    for (int n = 0; n < 4; ++n)
#pragma unroll
      for (int m = 0; m < 4; ++m)
#pragma unroll
        for (int r = 0; r < 4; ++r)
          O[m * 16 + lk * 4 + r][j0 + n * 16 + lr] = f2bs(acc[m][n][r]);
    __syncthreads();
    for (int t = tid; t < MT * 32; t += 256) {
      int p = t >> 5, c = t & 31;
      if (base + p < NN)
        *reinterpret_cast<uint4*>(&outp[(size_t)(base + p) * HDIM + c * 8]) =
            *reinterpret_cast<const uint4*>(&O[p][c * 8]);
    }
    __syncthreads();
  }
}

// ---- MFMA SGFormer qkv --------------------------------------------------------------
__global__ __launch_bounds__(256) void k_sg_qkv_mfma(
    const float* __restrict__ x, const unsigned short* __restrict__ Wqs,
    const unsigned short* __restrict__ Wks, const unsigned short* __restrict__ Wvs,
    bf16* __restrict__ qs, bf16* __restrict__ ks, bf16* __restrict__ vv) {
  __shared__ unsigned short A[MT][264];
  __shared__ unsigned short O[MT][264];
  int tid = threadIdx.x, l = tid & 63, w = tid >> 6;
  int lr = l & 15, lk = l >> 4;
  int base = blockIdx.x * MT;
  for (int t = tid; t < MT * 64; t += 256) {
    int p = t >> 6, c = t & 63;
    int row = base + p; if (row >= NN) row = NN - 1;
    float4 v = *reinterpret_cast<const float4*>(&x[(size_t)row * HDIM + c * 4]);
    unsigned short tmp[4] = {f2bs(v.x), f2bs(v.y), f2bs(v.z), f2bs(v.w)};
    *reinterpret_cast<uint2*>(&A[p][c * 4]) = *reinterpret_cast<const uint2*>(tmp);
  }
  __syncthreads();
  int j0 = w * 64;
#pragma unroll
  for (int mtx = 0; mtx < 3; ++mtx) {
    const unsigned short* Ws = (mtx == 0) ? Wqs : (mtx == 1) ? Wks : Wvs;
    bf16* outp = (mtx == 0) ? qs : (mtx == 1) ? ks : vv;
    f32x4 acc[4][4];
#pragma unroll
    for (int m = 0; m < 4; ++m)
#pragma unroll
      for (int n = 0; n < 4; ++n)
#pragma unroll
        for (int r = 0; r < 4; ++r) acc[m][n][r] = 0.f;
    for (int k0 = 0; k0 < 8; ++k0) {
      bf16x8 a[4], b[4];
#pragma unroll
      for (int m = 0; m < 4; ++m)
        a[m] = *reinterpret_cast<const bf16x8*>(&A[m * 16 + lr][k0 * 32 + lk * 8]);
#pragma unroll
      for (int n = 0; n < 4; ++n) {
        int nt = (j0 >> 4) + n;
        b[n] = *reinterpret_cast<const bf16x8*>(Ws + ((size_t)(nt * 8 + k0) * 64 + l) * 8);
      }
#pragma unroll
      for (int m = 0; m < 4; ++m)
#pragma unroll
        for (int n = 0; n < 4; ++n)
          acc[m][n] = __builtin_amdgcn_mfma_f32_16x16x32_bf16(a[m], b[n], acc[m][n], 0, 0, 0);
    }
    if (mtx < 2) {
      float pa[4][4], pb[4][4];
#pragma unroll
      for (int m = 0; m < 4; ++m)
#pragma unroll
        for (int r = 0; r < 4; ++r) {
          pa[m][r] = acc[m][0][r] * acc[m][0][r] + acc[m][1][r] * acc[m][1][r];
          pb[m][r] = acc[m][2][r] * acc[m][2][r] + acc[m][3][r] * acc[m][3][r];
        }
#pragma unroll
      for (int off = 1; off < 16; off <<= 1) {
#pragma unroll
        for (int m = 0; m < 4; ++m)
#pragma unroll
          for (int r = 0; r < 4; ++r) {
            pa[m][r] += __shfl_xor(pa[m][r], off);
            pb[m][r] += __shfl_xor(pb[m][r], off);
          }
      }
#pragma unroll
      for (int m = 0; m < 4; ++m)
#pragma unroll
        for (int r = 0; r < 4; ++r) {
          float ra = 1.f / (sqrtf(pa[m][r]) + 1e-6f);
          float rb = 1.f / (sqrtf(pb[m][r]) + 1e-6f);
          acc[m][0][r] *= ra; acc[m][1][r] *= ra;
          acc[m][2][r] *= rb; acc[m][3][r] *= rb;
        }
    }
#pragma unroll
    for (int n = 0; n < 4; ++n)
#pragma unroll
      for (int m = 0; m < 4; ++m)
#pragma unroll
        for (int r = 0; r < 4; ++r)
          O[m * 16 + lk * 4 + r][j0 + n * 16 + lr] = f2bs(acc[m][n][r]);
    __syncthreads();
    for (int t = tid; t < MT * 32; t += 256) {
      int p = t >> 5, c = t & 31;
      if (base + p < NN)
        *reinterpret_cast<uint4*>(&outp[(size_t)(base + p) * HDIM + c * 8]) =
            *reinterpret_cast<const uint4*>(&O[p][c * 8]);
    }
    __syncthreads();
  }
}

// ---- sg_kv stage 1: per-block partials (NO atomics) ---------------------------------
__global__ void k_sg_kv1(const bf16* __restrict__ ks, const bf16* __restrict__ vv,
                         float* __restrict__ part) {
  int t = threadIdx.x;
  int h = t >> 5;
  float kvloc[CH];
  float ksl = 0.f;
#pragma unroll
  for (int d = 0; d < CH; ++d) kvloc[d] = 0.f;
  __shared__ float krow[HDIM], vrow[HDIM];
  for (int n = blockIdx.x; n < NN; n += KVB) {
    krow[t] = b2f(ks[(size_t)n * HDIM + t]);
    vrow[t] = b2f(vv[(size_t)n * HDIM + t]);
    __syncthreads();
    float kc = krow[t];
    ksl += kc;
#pragma unroll
    for (int d = 0; d < CH; ++d) kvloc[d] += kc * vrow[h * CH + d];
    __syncthreads();
  }
  float* dstp = part + (size_t)blockIdx.x * 8448;
#pragma unroll
  for (int d = 0; d < CH; d += 4)
    *reinterpret_cast<float4*>(&dstp[t * CH + d]) =
        *reinterpret_cast<const float4*>(&kvloc[d]);
  dstp[8192 + t] = ksl;
}

// ---- sg_kv stage 2: deterministic reduce over KVB partials --------------------------
__global__ void k_sg_kv2(const float* __restrict__ part, float* __restrict__ kv,
                         float* __restrict__ ksum) {
  int idx = blockIdx.x * 256 + threadIdx.x;
  if (idx >= 8448) return;
  float s = 0.f;
  for (int b = 0; b < KVB; ++b) s += part[(size_t)b * 8448 + idx];
  if (idx < 8192) kv[idx] = s;
  else ksum[idx - 8192] = s;
}

// ---- trans + combine + LN -> f32 out ------------------------------------------------
__global__ void k_sg_final(const bf16* __restrict__ qs, const bf16* __restrict__ vv,
                           const float* __restrict__ kv, const float* __restrict__ ksum,
                           const float* __restrict__ xg, const float* __restrict__ alphap,
                           const float* __restrict__ cng, const float* __restrict__ cnb,
                           float* __restrict__ out) {
  int t = threadIdx.x;
  int d = t & 31, sub = t >> 5;
  __shared__ float qrow[8][HDIM];
  __shared__ float crow[8][CH];
  int n = blockIdx.x * 8 + sub;
  for (int tt = t; tt < 8 * HDIM; tt += 256) {
    int p = tt >> 8, k = tt & 255;
    int n2 = blockIdx.x * 8 + p;
    if (n2 < NN) qrow[p][k] = b2f(qs[(size_t)n2 * HDIM + k]);
  }
  __syncthreads();
  float alpha = 1.f / (1.f + expf(-alphap[0]));
  const float Nf = (float)NN;
  float comb = 0.f;
  if (n < NN) {
    float acc = 0.f;
#pragma unroll
    for (int h = 0; h < NH; ++h) {
      float nm = 0.f, dp = 0.f;
#pragma unroll 8
      for (int c = 0; c < CH; ++c) {
        float qv = qrow[sub][h * CH + c];
        nm += qv * kv[(h * CH + c) * CH + d];
        dp += qv * ksum[h * CH + c];
      }
      nm += Nf * b2f(vv[(size_t)n * HDIM + h * CH + d]);
      acc += nm / (dp + Nf);
    }
    float trans = acc * (1.f / NH);
    comb = alpha * xg[(size_t)n * CH + d] + (1.f - alpha) * trans;
    crow[sub][d] = comb;
  }
  __syncthreads();
  if (n < NN) {
    float mu = 0.f;
#pragma unroll
    for (int k = 0; k < CH; ++k) mu += crow[sub][k];
    mu *= (1.f / CH);
    float var = 0.f;
#pragma unroll
    for (int k = 0; k < CH; ++k) { float dv = crow[sub][k] - mu; var += dv * dv; }
    var *= (1.f / CH);
    float o = (comb - mu) * rsqrtf(var + 1e-5f) * cng[d] + cnb[d];
    out[(size_t)n * CH + d] = o;
  }
}

extern "C" void kernel_launch(void* const* d_in, const int* in_sizes, int n_in,
                              void* d_out, int out_size, void* d_ws, size_t ws_size,
                              hipStream_t stream) {
  const float* mesh  = (const float*)d_in[0];
  const int*   eidx  = (const int*)d_in[1];
  const float* eattr = (const float*)d_in[2];
  const float* epW   = (const float*)d_in[3];
  const float* epb   = (const float*)d_in[4];
  const float* Wl0   = (const float*)d_in[5];
  const float* Wr0   = (const float*)d_in[6];
  const float* WlL   = (const float*)d_in[7];
  const float* WrL   = (const float*)d_in[8];
  const float* We0   = (const float*)d_in[9];
  const float* WeL   = (const float*)d_in[10];
  const float* att0  = (const float*)d_in[11];
  const float* attL  = (const float*)d_in[12];
  const float* Wres0 = (const float*)d_in[13];
  const float* WresL = (const float*)d_in[14];
  const float* bn0   = (const float*)d_in[15];
  const float* bnL   = (const float*)d_in[16];
  const float* Wu1_0 = (const float*)d_in[17];
  const float* Wu1L  = (const float*)d_in[18];
  const float* bu1_0 = (const float*)d_in[19];
  const float* bu1L  = (const float*)d_in[20];
  const float* Wu2_0 = (const float*)d_in[21];
  const float* Wu2L  = (const float*)d_in[22];
  const float* bu2_0 = (const float*)d_in[23];
  const float* bu2L  = (const float*)d_in[24];
  const float* lng   = (const float*)d_in[25];
  const float* lnb   = (const float*)d_in[26];
  const float* Wq    = (const float*)d_in[27];
  const float* Wk    = (const float*)d_in[28];
  const float* Wv    = (const float*)d_in[29];
  const float* alphap= (const float*)d_in[30];
  const float* cng   = (const float*)d_in[31];
  const float* cnb   = (const float*)d_in[32];

  const int* src = eidx;
  const int* dst = eidx + NE;

  char* base = (char*)d_ws;
  size_t o = 0;
  auto alloc = [&](size_t bytes) -> char* {
    o = (o + 255) & ~(size_t)255;
    char* p = base + o;
    o += bytes;
    return p;
  };
  bf16* e    = (bf16*)alloc((size_t)NE * HDIM * 2);
  bf16* xl   = (bf16*)alloc((size_t)NN * HDIM * 2);   // reused: qs
  bf16* xr   = (bf16*)alloc((size_t)NN * HDIM * 2);   // reused: ks
  bf16* vvb  = (bf16*)alloc((size_t)NN * HDIM * 2);   // SGFormer v
  float* sbuf= (float*)alloc((size_t)NE * NH * 4);    // exp(scores)
  float* xa  = (float*)alloc((size_t)NN * CH * 4);
  float* xb  = (float*)alloc((size_t)NN * CH * 4);
  float* xc  = (float*)alloc((size_t)NN * CH * 4);
  float* kv  = (float*)alloc(NH * CH * CH * 4);
  float* ksum= (float*)alloc(NH * CH * 4);
  float* kvpart = (float*)alloc((size_t)KVB * 8448 * 4);   // 17.3 MB
  unsigned short* w1s = (unsigned short*)alloc((size_t)3 * 320 * 256 * 2);
  unsigned short* w2s = (unsigned short*)alloc((size_t)3 * 256 * 256 * 2);
  unsigned short* wall= (unsigned short*)alloc((size_t)9 * 65536 * 2);
  unsigned short* w32s= (unsigned short*)alloc((size_t)6 * 32 * 256 * 2);
  int* cnt    = (int*)alloc((size_t)NN * 4);
  int* rowptr = (int*)alloc((size_t)(NN + 1) * 4);
  int* cursor = (int*)alloc((size_t)NN * 4);
  int2* csr   = (int2*)alloc((size_t)NE * 8);
  if (ws_size < o) return;   // fail cleanly if ws too small

  // fused pre-pass: all weight swizzles + cnt zeroing in ONE launch
  SwzP P;
  P.We0 = We0; P.WeL = WeL; P.Wl0 = Wl0; P.Wr0 = Wr0; P.Wq = Wq; P.Wk = Wk; P.Wv = Wv;
  P.Wu1_0 = Wu1_0; P.Wu1L = Wu1L; P.Wu2_0 = Wu2_0; P.Wu2L = Wu2L;
  P.WlL = WlL; P.WrL = WrL;
  P.wall = wall; P.w1s = w1s; P.w2s = w2s; P.w32s = w32s; P.cnt = cnt;
  int swz_total = SWZ_NW + SWZ_N1 + SWZ_N2 + SWZ_N3 + NN;
  k_swz_fused<<<(swz_total + 255) / 256, 256, 0, stream>>>(P);

  // CSR build (graph constant across layers)
  k_csr_count<<<(NE + 255) / 256, 256, 0, stream>>>(dst, cnt);
  k_csr_scan<<<1, 256, 0, stream>>>(cnt, rowptr, cursor);
  k_csr_fill<<<(NE + 255) / 256, 256, 0, stream>>>(src, dst, cursor, csr);

  k_edge_proj<<<NE * 32 / 256, 256, 0, stream>>>(eattr, epW, epb, e);

  const float* xin = mesh;
  float* post = xb;
  for (int l = 0; l < 4; ++l) {
    const float *att_p, *Wres_p, *bn_p, *bu1_p, *bu2_p;
    if (l == 0) {
      att_p = att0; Wres_p = Wres0; bn_p = bn0; bu1_p = bu1_0; bu2_p = bu2_0;
    } else {
      int i = l - 1;
      att_p = attL + (size_t)i * HDIM;
      Wres_p = WresL + (size_t)i * CH * CH;
      bn_p = bnL + (size_t)i * CH;
      bu1_p = bu1L + (size_t)i * HDIM;
      bu2_p = bu2L + (size_t)i * HDIM;
    }

    if (l == 0)
      k_node_proj0_mfma<<<(NN + MT - 1) / MT, 256, 0, stream>>>(
          mesh, wall + (size_t)4 * 65536, wall + (size_t)5 * 65536, xl, xr);
    else
      k_node_projS_mfma<<<(NN + MT - 1) / MT, 256, 0, stream>>>(
          xin, w32s + (size_t)((l - 1) * 2 + 0) * 8192,
          w32s + (size_t)((l - 1) * 2 + 1) * 8192, xl, xr);

    k_edge_score_mfma<<<NE / MT, 512, 0, stream>>>(e, wall + (size_t)l * 65536,
                                                   xl, xr, att_p, src, dst, sbuf);

    if (l == 0)
      k_gat_out<HDIM, true><<<NN, 256, 0, stream>>>(rowptr, csr, sbuf, xl, xin, Wres_p,
                                                    bn_p, lng, lnb, xa, post);
    else if (l < 3)
      k_gat_out<CH, true><<<NN, 256, 0, stream>>>(rowptr, csr, sbuf, xl, xin, Wres_p,
                                                  bn_p, lng + (size_t)l * CH,
                                                  lnb + (size_t)l * CH, xa, post);
    else
      k_gat_out<CH, false><<<NN, 256, 0, stream>>>(rowptr, csr, sbuf, xl, xin, Wres_p,
                                                   bn_p, nullptr, nullptr, xa, nullptr);

    if (l < 3)
      k_edge_mlp_mfma<<<NE / MT, 512, 0, stream>>>(e, xa, src, dst,
                                                   w1s + (size_t)l * 320 * 256, bu1_p,
                                                   w2s + (size_t)l * 256 * 256, bu2_p);

    xin = post;
    post = (post == xb) ? xc : xb;
  }
  // final GAT output (no LN) is in xa

  k_sg_qkv_mfma<<<(NN + MT - 1) / MT, 256, 0, stream>>>(
      mesh, wall + (size_t)6 * 65536, wall + (size_t)7 * 65536,
      wall + (size_t)8 * 65536, xl, xr, vvb);
  k_sg_kv1<<<KVB, 256, 0, stream>>>(xr, vvb, kvpart);
  k_sg_kv2<<<33, 256, 0, stream>>>(kvpart, kv, ksum);
  k_sg_final<<<(NN + 7) / 8, 256, 0, stream>>>(xl, vvb, kv, ksum, xa, alphap, cng, cnb,
                                               (float*)d_out);
}

// Round 11
// 1492.063 us; speedup vs baseline: 7.4610x; 1.0729x over previous
//
#include <hip/hip_runtime.h>
#include <hip/hip_bf16.h>
#include <math.h>

typedef __hip_bfloat16 bf16;
typedef __attribute__((ext_vector_type(8))) __bf16 bf16x8;
typedef __attribute__((ext_vector_type(4))) float f32x4;

#define NN 40962
#define NE 245760
#define HDIM 256
#define NH 8
#define CH 32

#define MT 64     // rows per block in MFMA kernels
#define KVB 512   // stage-1 blocks for sg_kv partial reduction

__device__ __forceinline__ float b2f(bf16 v) { return __bfloat162float(v); }
__device__ __forceinline__ bf16 f2b(float v) { return __float2bfloat16(v); }
__device__ __forceinline__ unsigned short f2bs(float v) {
  bf16 b = __float2bfloat16(v);
  return __builtin_bit_cast(unsigned short, b);
}
__device__ __forceinline__ float bs2f(unsigned short u) {
  return __bfloat162float(__builtin_bit_cast(bf16, u));
}

// gelu (tanh form) with native exp2: tanh(g) = (e^{2g}-1)/(e^{2g}+1)
__device__ __forceinline__ float fast_gelu(float x) {
  float x2 = x * x;
  float g = x * (0.7978845608028654f + 0.0356774081f * x2);
  float y = fminf(g * 2.885390081777927f, 60.f);   // 2*log2(e)*g, clamped
  float t = exp2f(y);
  float th = (t - 1.f) * __builtin_amdgcn_rcpf(t + 1.f);
  return 0.5f * x * (1.f + th);
}

// ---- MFMA edge input projection: e = attr @ epW + epb (K=16 zero-padded to 32) ------
__global__ __launch_bounds__(512) void k_edge_proj_mfma(
    const float* __restrict__ attr, const unsigned short* __restrict__ Weps,
    const float* __restrict__ bias, bf16* __restrict__ e) {
  __shared__ unsigned short At[MT][40];    // 64 x 32 (cols 16..31 zero) + pad
  __shared__ unsigned short O[MT][264];
  int tid = threadIdx.x, l = tid & 63, w = tid >> 6;
  int lr = l & 15, lk = l >> 4;
  int base = blockIdx.x * MT;              // NE % 64 == 0
  {
    int p = tid >> 3, q = tid & 7;         // 512 threads = 64 x 8 exactly
    if (q < 4) {
      float4 v = *reinterpret_cast<const float4*>(&attr[(size_t)(base + p) * 16 + q * 4]);
      unsigned short tmp[4] = {f2bs(v.x), f2bs(v.y), f2bs(v.z), f2bs(v.w)};
      *reinterpret_cast<uint2*>(&At[p][q * 4]) = *reinterpret_cast<const uint2*>(tmp);
    } else {
      unsigned short z[4] = {0, 0, 0, 0};
      *reinterpret_cast<uint2*>(&At[p][q * 4]) = *reinterpret_cast<const uint2*>(z);
    }
  }
  __syncthreads();

  int j0 = w * 32;
  f32x4 acc[4][2];
#pragma unroll
  for (int m = 0; m < 4; ++m)
#pragma unroll
    for (int n = 0; n < 2; ++n)
#pragma unroll
      for (int r = 0; r < 4; ++r) acc[m][n][r] = 0.f;
  {
    bf16x8 a[4], b[2];
#pragma unroll
    for (int m = 0; m < 4; ++m)
      a[m] = *reinterpret_cast<const bf16x8*>(&At[m * 16 + lr][lk * 8]);
#pragma unroll
    for (int n = 0; n < 2; ++n) {
      int nt = w * 2 + n;
      b[n] = *reinterpret_cast<const bf16x8*>(Weps + ((size_t)nt * 64 + l) * 8);
    }
#pragma unroll
    for (int m = 0; m < 4; ++m)
#pragma unroll
      for (int n = 0; n < 2; ++n)
        acc[m][n] = __builtin_amdgcn_mfma_f32_16x16x32_bf16(a[m], b[n], acc[m][n], 0, 0, 0);
  }
#pragma unroll
  for (int n = 0; n < 2; ++n) {
    int col = j0 + n * 16 + lr;
    float bv = bias[col];
#pragma unroll
    for (int m = 0; m < 4; ++m)
#pragma unroll
      for (int r = 0; r < 4; ++r)
        O[m * 16 + lk * 4 + r][col] = f2bs(acc[m][n][r] + bv);
  }
  __syncthreads();
  for (int t = tid; t < MT * 32; t += 512) {
    int p = t >> 5, c = t & 31;
    *reinterpret_cast<uint4*>(&e[(size_t)(base + p) * HDIM + c * 8]) =
        *reinterpret_cast<const uint4*>(&O[p][c * 8]);
  }
}

// ---- CSR build: count, scan(+cursor), fill ------------------------------------------
__global__ void k_csr_count(const int* __restrict__ dst, int* __restrict__ cnt) {
  int e = blockIdx.x * 256 + threadIdx.x;
  if (e < NE) atomicAdd(&cnt[dst[e]], 1);
}
__global__ void k_csr_scan(const int* __restrict__ cnt, int* __restrict__ rowptr,
                           int* __restrict__ cursor) {
  __shared__ int part[256];
  __shared__ int tot;
  int t = threadIdx.x;
  const int CHUNK = (NN + 255) / 256;
  int lo = t * CHUNK, hi = lo + CHUNK; if (hi > NN) hi = NN; if (lo > NN) lo = NN;
  int s = 0;
  for (int i = lo; i < hi; ++i) s += cnt[i];
  part[t] = s;
  __syncthreads();
  if (t == 0) {
    int run = 0;
    for (int i = 0; i < 256; ++i) { int v = part[i]; part[i] = run; run += v; }
    tot = run;
  }
  __syncthreads();
  int run = part[t];
  for (int i = lo; i < hi; ++i) { rowptr[i] = run; cursor[i] = run; run += cnt[i]; }
  if (t == 0) rowptr[NN] = tot;
}
__global__ void k_csr_fill(const int* __restrict__ src, const int* __restrict__ dst,
                           int* __restrict__ cursor, int2* __restrict__ csr) {
  int e = blockIdx.x * 256 + threadIdx.x;
  if (e >= NE) return;
  int p = atomicAdd(&cursor[dst[e]], 1);
  int2 v; v.x = e; v.y = src[e];
  csr[p] = v;
}

// ---- fused weight swizzle (all matrices) + cnt zeroing ------------------------------
struct SwzP {
  const float *We0, *WeL, *Wl0, *Wr0, *Wq, *Wk, *Wv;
  const float *Wu1_0, *Wu1L, *Wu2_0, *Wu2L, *WlL, *WrL, *epW;
  unsigned short *wall, *w1s, *w2s, *w32s, *wep;
  int* cnt;
};
__device__ __forceinline__ void swz1(const float* __restrict__ W,
                                     unsigned short* __restrict__ out, int t, int Kdiv32) {
  int i = t & 7, l = (t >> 3) & 63;
  int k0 = (t >> 9) % Kdiv32;
  int n0 = t / (512 * Kdiv32);
  int k = k0 * 32 + (l >> 4) * 8 + i;
  int n = n0 * 16 + (l & 15);
  out[t] = f2bs(W[k * 256 + n]);
}
#define SWZ_NW (9 * 65536)
#define SWZ_N1 (3 * 81920)
#define SWZ_N2 (3 * 65536)
#define SWZ_N3 (6 * 8192)
#define SWZ_N4 8192
__global__ void k_swz_fused(SwzP P) {
  int gid = blockIdx.x * 256 + threadIdx.x;
  if (gid < SWZ_NW) {
    int mat = gid >> 16, t = gid & 65535;
    const float* W;
    switch (mat) {
      case 0: W = P.We0; break;
      case 1: W = P.WeL; break;
      case 2: W = P.WeL + 65536; break;
      case 3: W = P.WeL + 131072; break;
      case 4: W = P.Wl0; break;
      case 5: W = P.Wr0; break;
      case 6: W = P.Wq; break;
      case 7: W = P.Wk; break;
      default: W = P.Wv; break;
    }
    swz1(W, P.wall + (size_t)mat * 65536, t, 8);
  } else if (gid < SWZ_NW + SWZ_N1) {
    int idx = gid - SWZ_NW;
    int mat = idx / 81920, t = idx % 81920;
    const float* W = (mat == 0) ? P.Wu1_0 : P.Wu1L + (size_t)(mat - 1) * 81920;
    swz1(W, P.w1s + (size_t)mat * 81920, t, 10);
  } else if (gid < SWZ_NW + SWZ_N1 + SWZ_N2) {
    int idx = gid - SWZ_NW - SWZ_N1;
    int mat = idx >> 16, t = idx & 65535;
    const float* W = (mat == 0) ? P.Wu2_0 : P.Wu2L + (size_t)(mat - 1) * 65536;
    swz1(W, P.w2s + (size_t)mat * 65536, t, 8);
  } else if (gid < SWZ_NW + SWZ_N1 + SWZ_N2 + SWZ_N3) {
    int idx = gid - SWZ_NW - SWZ_N1 - SWZ_N2;
    int mat = idx >> 13, t = idx & 8191;
    int i = mat >> 1;
    const float* W = (mat & 1) ? P.WrL + (size_t)i * 8192 : P.WlL + (size_t)i * 8192;
    swz1(W, P.w32s + (size_t)mat * 8192, t, 1);
  } else if (gid < SWZ_NW + SWZ_N1 + SWZ_N2 + SWZ_N3 + SWZ_N4) {
    // epW [16][256] zero-padded to K=32 fragment layout
    int t = gid - (SWZ_NW + SWZ_N1 + SWZ_N2 + SWZ_N3);
    int i = t & 7, l = (t >> 3) & 63;
    int n0 = t >> 9;
    int k = (l >> 4) * 8 + i;
    int n = n0 * 16 + (l & 15);
    P.wep[t] = (k < 16) ? f2bs(P.epW[k * 256 + n]) : (unsigned short)0;
  } else {
    int i = gid - (SWZ_NW + SWZ_N1 + SWZ_N2 + SWZ_N3 + SWZ_N4);
    if (i < NN) P.cnt[i] = 0;
  }
}

// ---- MFMA edge score (8 waves x 32-col stripes, aliased LDS) -> sx = exp(s) ---------
__global__ __launch_bounds__(512) void k_edge_score_mfma(
    const bf16* __restrict__ e, const unsigned short* __restrict__ Wes,
    const bf16* __restrict__ xl, const bf16* __restrict__ xr,
    const float* __restrict__ att, const int* __restrict__ src,
    const int* __restrict__ dst, float* __restrict__ sx) {
  __shared__ unsigned short Ae[MT][264];   // e-tile, then reused as scoreboard
  __shared__ float attS[HDIM];
  __shared__ int sidx[MT], didx[MT];
  int tid = threadIdx.x, l = tid & 63, w = tid >> 6;
  int lr = l & 15, lk = l >> 4;
  int base = blockIdx.x * MT;
  if (tid < HDIM) attS[tid] = att[tid];
  if (tid < MT) sidx[tid] = src[base + tid];
  else if (tid < 2 * MT) didx[tid - MT] = dst[base + tid - MT];
  for (int t = tid; t < MT * 32; t += 512) {
    int p = t >> 5, c = t & 31;
    *reinterpret_cast<uint4*>(&Ae[p][c * 8]) =
        *reinterpret_cast<const uint4*>(&e[(size_t)(base + p) * HDIM + c * 8]);
  }
  __syncthreads();

  f32x4 acc[4][2];
#pragma unroll
  for (int m = 0; m < 4; ++m)
#pragma unroll
    for (int n = 0; n < 2; ++n)
#pragma unroll
      for (int r = 0; r < 4; ++r) acc[m][n][r] = 0.f;
  for (int k0 = 0; k0 < 8; ++k0) {
    bf16x8 a[4], b[2];
#pragma unroll
    for (int m = 0; m < 4; ++m)
      a[m] = *reinterpret_cast<const bf16x8*>(&Ae[m * 16 + lr][k0 * 32 + lk * 8]);
#pragma unroll
    for (int n = 0; n < 2; ++n) {
      int nt = w * 2 + n;
      b[n] = *reinterpret_cast<const bf16x8*>(Wes + ((size_t)(nt * 8 + k0) * 64 + l) * 8);
    }
#pragma unroll
    for (int m = 0; m < 4; ++m)
#pragma unroll
      for (int n = 0; n < 2; ++n)
        acc[m][n] = __builtin_amdgcn_mfma_f32_16x16x32_bf16(a[m], b[n], acc[m][n], 0, 0, 0);
  }
  __syncthreads();   // all Ae reads complete before scoreboard overwrite

  // epilogue: xl/xr read directly from global (L2-hot), scoreboard into Ae alias
#pragma unroll
  for (int n = 0; n < 2; ++n) {
    int col = w * 32 + n * 16 + lr;
    float av = attS[col];
#pragma unroll
    for (int m = 0; m < 4; ++m)
#pragma unroll
      for (int r = 0; r < 4; ++r) {
        int row = m * 16 + lk * 4 + r;
        float xs = b2f(xl[(size_t)sidx[row] * HDIM + col]) +
                   b2f(xr[(size_t)didx[row] * HDIM + col]);
        float mm = acc[m][n][r] + xs;
        mm = (mm > 0.f) ? mm : 0.2f * mm;
        Ae[row][col] = f2bs(mm * av);
      }
  }
  __syncthreads();
  for (int pair = tid; pair < MT * NH; pair += 512) {
    int ed = pair >> 3, h = pair & 7;
    float s = 0.f;
#pragma unroll
    for (int c = 0; c < CH; ++c) s += bs2f(Ae[ed][h * CH + c]);
    sx[(size_t)(base + ed) * NH + h] = expf(s);
  }
}

// ---- fused CSR aggregate + node output + optional LN --------------------------------
template <int ID, bool LN>
__global__ __launch_bounds__(256) void k_gat_out(
    const int* __restrict__ rowptr, const int2* __restrict__ csr,
    const float* __restrict__ sx, const bf16* __restrict__ xl,
    const float* __restrict__ x, const float* __restrict__ Wres,
    const float* __restrict__ bn, const float* __restrict__ lng,
    const float* __restrict__ lnb, float* __restrict__ xpre,
    float* __restrict__ xpost) {
  int n = blockIdx.x;
  int j = threadIdx.x;
  int h = j >> 5, c = j & 31;
  int p0 = rowptr[n], p1 = rowptr[n + 1];
  float a = 0.f, dsum = 0.f;
  for (int p = p0; p < p1; ++p) {
    int2 es = csr[p];
    float ex = sx[(size_t)es.x * NH + h];
    a += ex * b2f(xl[(size_t)es.y * HDIM + j]);
    dsum += ex;
  }
  __shared__ float oh[HDIM];
  __shared__ float rs[NH][CH];
  __shared__ float oc[CH + 1];
  oh[j] = a / (dsum + 1e-16f);
  const int KS = ID / NH;
  float r = 0.f;
  for (int k = h * KS; k < (h + 1) * KS; ++k)
    r += x[(size_t)n * ID + k] * Wres[k * CH + c];
  rs[h][c] = r;
  __syncthreads();
  if (j < CH) {
    float o = 0.f;
#pragma unroll
    for (int hh = 0; hh < NH; ++hh) o += oh[hh * CH + j];
    o *= (1.f / NH);
    float rr = 0.f;
#pragma unroll
    for (int hh = 0; hh < NH; ++hh) rr += rs[hh][j];
    o += rr + bn[j];
    xpre[(size_t)n * CH + j] = o;
    oc[j] = o;
  }
  __syncthreads();
  if (LN && j < CH) {
    float mu = 0.f;
#pragma unroll
    for (int k = 0; k < CH; ++k) mu += oc[k];
    mu *= (1.f / CH);
    float var = 0.f;
#pragma unroll
    for (int k = 0; k < CH; ++k) { float d = oc[k] - mu; var += d * d; }
    var *= (1.f / CH);
    xpost[(size_t)n * CH + j] = (oc[j] - mu) * rsqrtf(var + 1e-5f) * lng[j] + lnb[j];
  }
}

// ---- MFMA residual edge MLP (8 waves, single aliased 42KB LDS buffer) ---------------
__global__ __launch_bounds__(512) void k_edge_mlp_mfma(
    bf16* __restrict__ e, const float* __restrict__ xo,
    const int* __restrict__ src, const int* __restrict__ dst,
    const unsigned short* __restrict__ W1s, const float* __restrict__ bu1,
    const unsigned short* __restrict__ W2s, const float* __restrict__ bu2) {
  __shared__ unsigned short buf[MT][328];   // A1 (xo|e), then gelu(h1), then delta
  __shared__ int sidx[MT], didx[MT];
  int tid = threadIdx.x;
  int l = tid & 63;
  int w = tid >> 6;
  int base = blockIdx.x * MT;
  int lr = l & 15;
  int lk = l >> 4;

  if (tid < MT) sidx[tid] = src[base + tid];
  else if (tid < 2 * MT) didx[tid - MT] = dst[base + tid - MT];
  __syncthreads();

  for (int t = tid; t < MT * 32; t += 512) {
    int p = t >> 5, cc = t & 31;
    uint4 v = *reinterpret_cast<const uint4*>(&e[(size_t)(base + p) * HDIM + cc * 8]);
    *reinterpret_cast<uint4*>(&buf[p][64 + cc * 8]) = v;
  }
  for (int t = tid; t < MT * 64; t += 512) {
    int p = t >> 6, c = t & 63;
    float v = (c < CH) ? xo[(size_t)sidx[p] * CH + c]
                       : xo[(size_t)didx[p] * CH + (c - CH)];
    buf[p][c] = f2bs(v);
  }
  __syncthreads();

  int j0 = w * 32;

  f32x4 acc[4][2];
#pragma unroll
  for (int m = 0; m < 4; ++m)
#pragma unroll
    for (int n = 0; n < 2; ++n)
#pragma unroll
      for (int r = 0; r < 4; ++r) acc[m][n][r] = 0.f;

  for (int k0 = 0; k0 < 10; ++k0) {
    bf16x8 a[4], b[2];
#pragma unroll
    for (int m = 0; m < 4; ++m)
      a[m] = *reinterpret_cast<const bf16x8*>(&buf[m * 16 + lr][k0 * 32 + lk * 8]);
#pragma unroll
    for (int n = 0; n < 2; ++n) {
      int nt = w * 2 + n;
      b[n] = *reinterpret_cast<const bf16x8*>(W1s + ((size_t)(nt * 10 + k0) * 64 + l) * 8);
    }
#pragma unroll
    for (int m = 0; m < 4; ++m)
#pragma unroll
      for (int n = 0; n < 2; ++n)
        acc[m][n] = __builtin_amdgcn_mfma_f32_16x16x32_bf16(a[m], b[n], acc[m][n], 0, 0, 0);
  }
  __syncthreads();   // all A1 reads complete before overwrite

  // gelu(h1 + bu1) -> buf alias (cols 0..255)
#pragma unroll
  for (int n = 0; n < 2; ++n) {
    float bv = bu1[j0 + n * 16 + lr];
#pragma unroll
    for (int m = 0; m < 4; ++m)
#pragma unroll
      for (int r = 0; r < 4; ++r) {
        float g = fast_gelu(acc[m][n][r] + bv);
        buf[m * 16 + lk * 4 + r][j0 + n * 16 + lr] = f2bs(g);
      }
  }
  __syncthreads();

#pragma unroll
  for (int m = 0; m < 4; ++m)
#pragma unroll
    for (int n = 0; n < 2; ++n)
#pragma unroll
      for (int r = 0; r < 4; ++r) acc[m][n][r] = 0.f;

  for (int k0 = 0; k0 < 8; ++k0) {
    bf16x8 a[4], b[2];
#pragma unroll
    for (int m = 0; m < 4; ++m)
      a[m] = *reinterpret_cast<const bf16x8*>(&buf[m * 16 + lr][k0 * 32 + lk * 8]);
#pragma unroll
    for (int n = 0; n < 2; ++n) {
      int nt = w * 2 + n;
      b[n] = *reinterpret_cast<const bf16x8*>(W2s + ((size_t)(nt * 8 + k0) * 64 + l) * 8);
    }
#pragma unroll
    for (int m = 0; m < 4; ++m)
#pragma unroll
      for (int n = 0; n < 2; ++n)
        acc[m][n] = __builtin_amdgcn_mfma_f32_16x16x32_bf16(a[m], b[n], acc[m][n], 0, 0, 0);
  }
  __syncthreads();   // all gelu reads done before delta overwrite

  // delta = acc + bu2 -> buf alias
#pragma unroll
  for (int n = 0; n < 2; ++n) {
    int col = j0 + n * 16 + lr;
    float bv = bu2[col];
#pragma unroll
    for (int m = 0; m < 4; ++m)
#pragma unroll
      for (int r = 0; r < 4; ++r)
        buf[m * 16 + lk * 4 + r][col] = f2bs(acc[m][n][r] + bv);
  }
  __syncthreads();

  // store: e_new = e_old (global re-read, L2-hot) + delta
  for (int t = tid; t < MT * 32; t += 512) {
    int p = t >> 5, cc = t & 31;
    uint4 dv = *reinterpret_cast<const uint4*>(&buf[p][cc * 8]);
    uint4 ev = *reinterpret_cast<const uint4*>(&e[(size_t)(base + p) * HDIM + cc * 8]);
    const unsigned short* dd = (const unsigned short*)&dv;
    const unsigned short* ee = (const unsigned short*)&ev;
    unsigned short ov[8];
#pragma unroll
    for (int i = 0; i < 8; ++i) ov[i] = f2bs(bs2f(ee[i]) + bs2f(dd[i]));
    *reinterpret_cast<uint4*>(&e[(size_t)(base + p) * HDIM + cc * 8]) =
        *reinterpret_cast<const uint4*>(ov);
  }
}

// ---- MFMA layer-0 node projection ---------------------------------------------------
__global__ __launch_bounds__(256) void k_node_proj0_mfma(
    const float* __restrict__ x, const unsigned short* __restrict__ Wls,
    const unsigned short* __restrict__ Wrs, bf16* __restrict__ xl,
    bf16* __restrict__ xr) {
  __shared__ unsigned short A[MT][264];
  __shared__ unsigned short O[MT][264];
  int tid = threadIdx.x, l = tid & 63, w = tid >> 6;
  int lr = l & 15, lk = l >> 4;
  int base = blockIdx.x * MT;
  for (int t = tid; t < MT * 64; t += 256) {
    int p = t >> 6, c = t & 63;
    int row = base + p; if (row >= NN) row = NN - 1;
    float4 v = *reinterpret_cast<const float4*>(&x[(size_t)row * HDIM + c * 4]);
    unsigned short tmp[4] = {f2bs(v.x), f2bs(v.y), f2bs(v.z), f2bs(v.w)};
    *reinterpret_cast<uint2*>(&A[p][c * 4]) = *reinterpret_cast<const uint2*>(tmp);
  }
  __syncthreads();
  int j0 = w * 64;
#pragma unroll
  for (int mtx = 0; mtx < 2; ++mtx) {
    const unsigned short* Ws = (mtx == 0) ? Wls : Wrs;
    bf16* outp = (mtx == 0) ? xl : xr;
    f32x4 acc[4][4];
#pragma unroll
    for (int m = 0; m < 4; ++m)
#pragma unroll
      for (int n = 0; n < 4; ++n)
#pragma unroll
        for (int r = 0; r < 4; ++r) acc[m][n][r] = 0.f;
    for (int k0 = 0; k0 < 8; ++k0) {
      bf16x8 a[4], b[4];
#pragma unroll
      for (int m = 0; m < 4; ++m)
        a[m] = *reinterpret_cast<const bf16x8*>(&A[m * 16 + lr][k0 * 32 + lk * 8]);
#pragma unroll
      for (int n = 0; n < 4; ++n) {
        int nt = (j0 >> 4) + n;
        b[n] = *reinterpret_cast<const bf16x8*>(Ws + ((size_t)(nt * 8 + k0) * 64 + l) * 8);
      }
#pragma unroll
      for (int m = 0; m < 4; ++m)
#pragma unroll
        for (int n = 0; n < 4; ++n)
          acc[m][n] = __builtin_amdgcn_mfma_f32_16x16x32_bf16(a[m], b[n], acc[m][n], 0, 0, 0);
    }
#pragma unroll
    for (int n = 0; n < 4; ++n)
#pragma unroll
      for (int m = 0; m < 4; ++m)
#pragma unroll
        for (int r = 0; r < 4; ++r)
          O[m * 16 + lk * 4 + r][j0 + n * 16 + lr] = f2bs(acc[m][n][r]);
    __syncthreads();
    for (int t = tid; t < MT * 32; t += 256) {
      int p = t >> 5, c = t & 31;
      if (base + p < NN)
        *reinterpret_cast<uint4*>(&outp[(size_t)(base + p) * HDIM + c * 8]) =
            *reinterpret_cast<const uint4*>(&O[p][c * 8]);
    }
    __syncthreads();
  }
}

// ---- MFMA small node projection (layers 1..3, K=32) ---------------------------------
__global__ __launch_bounds__(256) void k_node_projS_mfma(
    const float* __restrict__ x, const unsigned short* __restrict__ Wls,
    const unsigned short* __restrict__ Wrs, bf16* __restrict__ xl,
    bf16* __restrict__ xr) {
  __shared__ unsigned short A[MT][40];
  __shared__ unsigned short O[MT][264];
  int tid = threadIdx.x, l = tid & 63, w = tid >> 6;
  int lr = l & 15, lk = l >> 4;
  int base = blockIdx.x * MT;
  for (int t = tid; t < MT * 8; t += 256) {
    int p = t >> 3, q = t & 7;
    int row = base + p; if (row >= NN) row = NN - 1;
    float4 v = *reinterpret_cast<const float4*>(&x[(size_t)row * CH + q * 4]);
    unsigned short tmp[4] = {f2bs(v.x), f2bs(v.y), f2bs(v.z), f2bs(v.w)};
    *reinterpret_cast<uint2*>(&A[p][q * 4]) = *reinterpret_cast<const uint2*>(tmp);
  }
  __syncthreads();
  int j0 = w * 64;
#pragma unroll
  for (int mtx = 0; mtx < 2; ++mtx) {
    const unsigned short* Ws = (mtx == 0) ? Wls : Wrs;
    bf16* outp = (mtx == 0) ? xl : xr;
    f32x4 acc[4][4];
#pragma unroll
    for (int m = 0; m < 4; ++m)
#pragma unroll
      for (int n = 0; n < 4; ++n)
#pragma unroll
        for (int r = 0; r < 4; ++r) acc[m][n][r] = 0.f;
    bf16x8 a[4], b[4];
#pragma unroll
    for (int m = 0; m < 4; ++m)
      a[m] = *reinterpret_cast<const bf16x8*>(&A[m * 16 + lr][lk * 8]);
#pragma unroll
    for (int n = 0; n < 4; ++n) {
      int nt = (j0 >> 4) + n;
      b[n] = *reinterpret_cast<const bf16x8*>(Ws + ((size_t)nt * 64 + l) * 8);
    }
#pragma unroll
    for (int m = 0; m < 4; ++m)
#pragma unroll
      for (int n = 0; n < 4; ++n)
        acc[m][n] = __builtin_amdgcn_mfma_f32_16x16x32_bf16(a[m], b[n], acc[m][n], 0, 0, 0);
#pragma unroll
    for (int n = 0; n < 4; ++n)
#pragma unroll
      for (int m = 0; m < 4; ++m)
#pragma unroll
        for (int r = 0; r < 4; ++r)
          O[m * 16 + lk * 4 + r][j0 + n * 16 + lr] = f2bs(acc[m][n][r]);
    __syncthreads();
    for (int t = tid; t < MT * 32; t += 256) {
      int p = t >> 5, c = t & 31;
      if (base + p < NN)
        *reinterpret_cast<uint4*>(&outp[(size_t)(base + p) * HDIM + c * 8]) =
            *reinterpret_cast<const uint4*>(&O[p][c * 8]);
    }
    __syncthreads();
  }
}

// ---- MFMA SGFormer qkv --------------------------------------------------------------
__global__ __launch_bounds__(256) void k_sg_qkv_mfma(
    const float* __restrict__ x, const unsigned short* __restrict__ Wqs,
    const unsigned short* __restrict__ Wks, const unsigned short* __restrict__ Wvs,
    bf16* __restrict__ qs, bf16* __restrict__ ks, bf16* __restrict__ vv) {
  __shared__ unsigned short A[MT][264];
  __shared__ unsigned short O[MT][264];
  int tid = threadIdx.x, l = tid & 63, w = tid >> 6;
  int lr = l & 15, lk = l >> 4;
  int base = blockIdx.x * MT;
  for (int t = tid; t < MT * 64; t += 256) {
    int p = t >> 6, c = t & 63;
    int row = base + p; if (row >= NN) row = NN - 1;
    float4 v = *reinterpret_cast<const float4*>(&x[(size_t)row * HDIM + c * 4]);
    unsigned short tmp[4] = {f2bs(v.x), f2bs(v.y), f2bs(v.z), f2bs(v.w)};
    *reinterpret_cast<uint2*>(&A[p][c * 4]) = *reinterpret_cast<const uint2*>(tmp);
  }
  __syncthreads();
  int j0 = w * 64;
#pragma unroll
  for (int mtx = 0; mtx < 3; ++mtx) {
    const unsigned short* Ws = (mtx == 0) ? Wqs : (mtx == 1) ? Wks : Wvs;
    bf16* outp = (mtx == 0) ? qs : (mtx == 1) ? ks : vv;
    f32x4 acc[4][4];
#pragma unroll
    for (int m = 0; m < 4; ++m)
#pragma unroll
      for (int n = 0; n < 4; ++n)
#pragma unroll
        for (int r = 0; r < 4; ++r) acc[m][n][r] = 0.f;
    for (int k0 = 0; k0 < 8; ++k0) {
      bf16x8 a[4], b[4];
#pragma unroll
      for (int m = 0; m < 4; ++m)
        a[m] = *reinterpret_cast<const bf16x8*>(&A[m * 16 + lr][k0 * 32 + lk * 8]);
#pragma unroll
      for (int n = 0; n < 4; ++n) {
        int nt = (j0 >> 4) + n;
        b[n] = *reinterpret_cast<const bf16x8*>(Ws + ((size_t)(nt * 8 + k0) * 64 + l) * 8);
      }
#pragma unroll
      for (int m = 0; m < 4; ++m)
#pragma unroll
        for (int n = 0; n < 4; ++n)
          acc[m][n] = __builtin_amdgcn_mfma_f32_16x16x32_bf16(a[m], b[n], acc[m][n], 0, 0, 0);
    }
    if (mtx < 2) {
      float pa[4][4], pb[4][4];
#pragma unroll
      for (int m = 0; m < 4; ++m)
#pragma unroll
        for (int r = 0; r < 4; ++r) {
          pa[m][r] = acc[m][0][r] * acc[m][0][r] + acc[m][1][r] * acc[m][1][r];
          pb[m][r] = acc[m][2][r] * acc[m][2][r] + acc[m][3][r] * acc[m][3][r];
        }
#pragma unroll
      for (int off = 1; off < 16; off <<= 1) {
#pragma unroll
        for (int m = 0; m < 4; ++m)
#pragma unroll
          for (int r = 0; r < 4; ++r) {
            pa[m][r] += __shfl_xor(pa[m][r], off);
            pb[m][r] += __shfl_xor(pb[m][r], off);
          }
      }
#pragma unroll
      for (int m = 0; m < 4; ++m)
#pragma unroll
        for (int r = 0; r < 4; ++r) {
          float ra = 1.f / (sqrtf(pa[m][r]) + 1e-6f);
          float rb = 1.f / (sqrtf(pb[m][r]) + 1e-6f);
          acc[m][0][r] *= ra; acc[m][1][r] *= ra;
          acc[m][2][r] *= rb; acc[m][3][r] *= rb;
        }
    }
#pragma unroll
    for (int n = 0; n < 4; ++n)
#pragma unroll
      for (int m = 0; m < 4; ++m)
#pragma unroll
        for (int r = 0; r < 4; ++r)
          O[m * 16 + lk * 4 + r][j0 + n * 16 + lr] = f2bs(acc[m][n][r]);
    __syncthreads();
    for (int t = tid; t < MT * 32; t += 256) {
      int p = t >> 5, c = t & 31;
      if (base + p < NN)
        *reinterpret_cast<uint4*>(&outp[(size_t)(base + p) * HDIM + c * 8]) =
            *reinterpret_cast<const uint4*>(&O[p][c * 8]);
    }
    __syncthreads();
  }
}

// ---- sg_kv stage 1: per-block partials (NO atomics) ---------------------------------
__global__ void k_sg_kv1(const bf16* __restrict__ ks, const bf16* __restrict__ vv,
                         float* __restrict__ part) {
  int t = threadIdx.x;
  int h = t >> 5;
  float kvloc[CH];
  float ksl = 0.f;
#pragma unroll
  for (int d = 0; d < CH; ++d) kvloc[d] = 0.f;
  __shared__ float krow[HDIM], vrow[HDIM];
  for (int n = blockIdx.x; n < NN; n += KVB) {
    krow[t] = b2f(ks[(size_t)n * HDIM + t]);
    vrow[t] = b2f(vv[(size_t)n * HDIM + t]);
    __syncthreads();
    float kc = krow[t];
    ksl += kc;
#pragma unroll
    for (int d = 0; d < CH; ++d) kvloc[d] += kc * vrow[h * CH + d];
    __syncthreads();
  }
  float* dstp = part + (size_t)blockIdx.x * 8448;
#pragma unroll
  for (int d = 0; d < CH; d += 4)
    *reinterpret_cast<float4*>(&dstp[t * CH + d]) =
        *reinterpret_cast<const float4*>(&kvloc[d]);
  dstp[8192 + t] = ksl;
}

// ---- sg_kv stage 2: deterministic reduce over KVB partials --------------------------
__global__ void k_sg_kv2(const float* __restrict__ part, float* __restrict__ kv,
                         float* __restrict__ ksum) {
  int idx = blockIdx.x * 256 + threadIdx.x;
  if (idx >= 8448) return;
  float s = 0.f;
  for (int b = 0; b < KVB; ++b) s += part[(size_t)b * 8448 + idx];
  if (idx < 8192) kv[idx] = s;
  else ksum[idx - 8192] = s;
}

// ---- trans + combine + LN -> f32 out ------------------------------------------------
__global__ void k_sg_final(const bf16* __restrict__ qs, const bf16* __restrict__ vv,
                           const float* __restrict__ kv, const float* __restrict__ ksum,
                           const float* __restrict__ xg, const float* __restrict__ alphap,
                           const float* __restrict__ cng, const float* __restrict__ cnb,
                           float* __restrict__ out) {
  int t = threadIdx.x;
  int d = t & 31, sub = t >> 5;
  __shared__ float qrow[8][HDIM];
  __shared__ float crow[8][CH];
  int n = blockIdx.x * 8 + sub;
  for (int tt = t; tt < 8 * HDIM; tt += 256) {
    int p = tt >> 8, k = tt & 255;
    int n2 = blockIdx.x * 8 + p;
    if (n2 < NN) qrow[p][k] = b2f(qs[(size_t)n2 * HDIM + k]);
  }
  __syncthreads();
  float alpha = 1.f / (1.f + expf(-alphap[0]));
  const float Nf = (float)NN;
  float comb = 0.f;
  if (n < NN) {
    float acc = 0.f;
#pragma unroll
    for (int h = 0; h < NH; ++h) {
      float nm = 0.f, dp = 0.f;
#pragma unroll 8
      for (int c = 0; c < CH; ++c) {
        float qv = qrow[sub][h * CH + c];
        nm += qv * kv[(h * CH + c) * CH + d];
        dp += qv * ksum[h * CH + c];
      }
      nm += Nf * b2f(vv[(size_t)n * HDIM + h * CH + d]);
      acc += nm / (dp + Nf);
    }
    float trans = acc * (1.f / NH);
    comb = alpha * xg[(size_t)n * CH + d] + (1.f - alpha) * trans;
    crow[sub][d] = comb;
  }
  __syncthreads();
  if (n < NN) {
    float mu = 0.f;
#pragma unroll
    for (int k = 0; k < CH; ++k) mu += crow[sub][k];
    mu *= (1.f / CH);
    float var = 0.f;
#pragma unroll
    for (int k = 0; k < CH; ++k) { float dv = crow[sub][k] - mu; var += dv * dv; }
    var *= (1.f / CH);
    float o = (comb - mu) * rsqrtf(var + 1e-5f) * cng[d] + cnb[d];
    out[(size_t)n * CH + d] = o;
  }
}

extern "C" void kernel_launch(void* const* d_in, const int* in_sizes, int n_in,
                              void* d_out, int out_size, void* d_ws, size_t ws_size,
                              hipStream_t stream) {
  const float* mesh  = (const float*)d_in[0];
  const int*   eidx  = (const int*)d_in[1];
  const float* eattr = (const float*)d_in[2];
  const float* epW   = (const float*)d_in[3];
  const float* epb   = (const float*)d_in[4];
  const float* Wl0   = (const float*)d_in[5];
  const float* Wr0   = (const float*)d_in[6];
  const float* WlL   = (const float*)d_in[7];
  const float* WrL   = (const float*)d_in[8];
  const float* We0   = (const float*)d_in[9];
  const float* WeL   = (const float*)d_in[10];
  const float* att0  = (const float*)d_in[11];
  const float* attL  = (const float*)d_in[12];
  const float* Wres0 = (const float*)d_in[13];
  const float* WresL = (const float*)d_in[14];
  const float* bn0   = (const float*)d_in[15];
  const float* bnL   = (const float*)d_in[16];
  const float* Wu1_0 = (const float*)d_in[17];
  const float* Wu1L  = (const float*)d_in[18];
  const float* bu1_0 = (const float*)d_in[19];
  const float* bu1L  = (const float*)d_in[20];
  const float* Wu2_0 = (const float*)d_in[21];
  const float* Wu2L  = (const float*)d_in[22];
  const float* bu2_0 = (const float*)d_in[23];
  const float* bu2L  = (const float*)d_in[24];
  const float* lng   = (const float*)d_in[25];
  const float* lnb   = (const float*)d_in[26];
  const float* Wq    = (const float*)d_in[27];
  const float* Wk    = (const float*)d_in[28];
  const float* Wv    = (const float*)d_in[29];
  const float* alphap= (const float*)d_in[30];
  const float* cng   = (const float*)d_in[31];
  const float* cnb   = (const float*)d_in[32];

  const int* src = eidx;
  const int* dst = eidx + NE;

  char* base = (char*)d_ws;
  size_t o = 0;
  auto alloc = [&](size_t bytes) -> char* {
    o = (o + 255) & ~(size_t)255;
    char* p = base + o;
    o += bytes;
    return p;
  };
  bf16* e    = (bf16*)alloc((size_t)NE * HDIM * 2);
  bf16* xl   = (bf16*)alloc((size_t)NN * HDIM * 2);   // reused: qs
  bf16* xr   = (bf16*)alloc((size_t)NN * HDIM * 2);   // reused: ks
  bf16* vvb  = (bf16*)alloc((size_t)NN * HDIM * 2);   // SGFormer v
  float* sbuf= (float*)alloc((size_t)NE * NH * 4);    // exp(scores)
  float* xa  = (float*)alloc((size_t)NN * CH * 4);
  float* xb  = (float*)alloc((size_t)NN * CH * 4);
  float* xc  = (float*)alloc((size_t)NN * CH * 4);
  float* kv  = (float*)alloc(NH * CH * CH * 4);
  float* ksum= (float*)alloc(NH * CH * 4);
  float* kvpart = (float*)alloc((size_t)KVB * 8448 * 4);   // 17.3 MB
  unsigned short* w1s = (unsigned short*)alloc((size_t)3 * 320 * 256 * 2);
  unsigned short* w2s = (unsigned short*)alloc((size_t)3 * 256 * 256 * 2);
  unsigned short* wall= (unsigned short*)alloc((size_t)9 * 65536 * 2);
  unsigned short* w32s= (unsigned short*)alloc((size_t)6 * 32 * 256 * 2);
  unsigned short* wep = (unsigned short*)alloc((size_t)SWZ_N4 * 2);
  int* cnt    = (int*)alloc((size_t)NN * 4);
  int* rowptr = (int*)alloc((size_t)(NN + 1) * 4);
  int* cursor = (int*)alloc((size_t)NN * 4);
  int2* csr   = (int2*)alloc((size_t)NE * 8);
  if (ws_size < o) return;   // fail cleanly if ws too small

  // fused pre-pass: all weight swizzles (incl. epW) + cnt zeroing in ONE launch
  SwzP P;
  P.We0 = We0; P.WeL = WeL; P.Wl0 = Wl0; P.Wr0 = Wr0; P.Wq = Wq; P.Wk = Wk; P.Wv = Wv;
  P.Wu1_0 = Wu1_0; P.Wu1L = Wu1L; P.Wu2_0 = Wu2_0; P.Wu2L = Wu2L;
  P.WlL = WlL; P.WrL = WrL; P.epW = epW;
  P.wall = wall; P.w1s = w1s; P.w2s = w2s; P.w32s = w32s; P.wep = wep; P.cnt = cnt;
  int swz_total = SWZ_NW + SWZ_N1 + SWZ_N2 + SWZ_N3 + SWZ_N4 + NN;
  k_swz_fused<<<(swz_total + 255) / 256, 256, 0, stream>>>(P);

  // CSR build (graph constant across layers)
  k_csr_count<<<(NE + 255) / 256, 256, 0, stream>>>(dst, cnt);
  k_csr_scan<<<1, 256, 0, stream>>>(cnt, rowptr, cursor);
  k_csr_fill<<<(NE + 255) / 256, 256, 0, stream>>>(src, dst, cursor, csr);

  k_edge_proj_mfma<<<NE / MT, 512, 0, stream>>>(eattr, wep, epb, e);

  const float* xin = mesh;
  float* post = xb;
  for (int l = 0; l < 4; ++l) {
    const float *att_p, *Wres_p, *bn_p, *bu1_p, *bu2_p;
    if (l == 0) {
      att_p = att0; Wres_p = Wres0; bn_p = bn0; bu1_p = bu1_0; bu2_p = bu2_0;
    } else {
      int i = l - 1;
      att_p = attL + (size_t)i * HDIM;
      Wres_p = WresL + (size_t)i * CH * CH;
      bn_p = bnL + (size_t)i * CH;
      bu1_p = bu1L + (size_t)i * HDIM;
      bu2_p = bu2L + (size_t)i * HDIM;
    }

    if (l == 0)
      k_node_proj0_mfma<<<(NN + MT - 1) / MT, 256, 0, stream>>>(
          mesh, wall + (size_t)4 * 65536, wall + (size_t)5 * 65536, xl, xr);
    else
      k_node_projS_mfma<<<(NN + MT - 1) / MT, 256, 0, stream>>>(
          xin, w32s + (size_t)((l - 1) * 2 + 0) * 8192,
          w32s + (size_t)((l - 1) * 2 + 1) * 8192, xl, xr);

    k_edge_score_mfma<<<NE / MT, 512, 0, stream>>>(e, wall + (size_t)l * 65536,
                                                   xl, xr, att_p, src, dst, sbuf);

    if (l == 0)
      k_gat_out<HDIM, true><<<NN, 256, 0, stream>>>(rowptr, csr, sbuf, xl, xin, Wres_p,
                                                    bn_p, lng, lnb, xa, post);
    else if (l < 3)
      k_gat_out<CH, true><<<NN, 256, 0, stream>>>(rowptr, csr, sbuf, xl, xin, Wres_p,
                                                  bn_p, lng + (size_t)l * CH,
                                                  lnb + (size_t)l * CH, xa, post);
    else
      k_gat_out<CH, false><<<NN, 256, 0, stream>>>(rowptr, csr, sbuf, xl, xin, Wres_p,
                                                   bn_p, nullptr, nullptr, xa, nullptr);

    if (l < 3)
      k_edge_mlp_mfma<<<NE / MT, 512, 0, stream>>>(e, xa, src, dst,
                                                   w1s + (size_t)l * 320 * 256, bu1_p,
                                                   w2s + (size_t)l * 256 * 256, bu2_p);

    xin = post;
    post = (post == xb) ? xc : xb;
  }
  // final GAT output (no LN) is in xa

  k_sg_qkv_mfma<<<(NN + MT - 1) / MT, 256, 0, stream>>>(
      mesh, wall + (size_t)6 * 65536, wall + (size_t)7 * 65536,
      wall + (size_t)8 * 65536, xl, xr, vvb);
  k_sg_kv1<<<KVB, 256, 0, stream>>>(xr, vvb, kvpart);
  k_sg_kv2<<<33, 256, 0, stream>>>(kvpart, kv, ksum);
  k_sg_final<<<(NN + 7) / 8, 256, 0, stream>>>(xl, vvb, kv, ksum, xa, alphap, cng, cnb,
                                               (float*)d_out);
}

// Round 12
// 1425.560 us; speedup vs baseline: 7.8091x; 1.0467x over previous
//
#include <hip/hip_runtime.h>
#include <hip/hip_bf16.h>
#include <math.h>

typedef __hip_bfloat16 bf16;
typedef __attribute__((ext_vector_type(8))) __bf16 bf16x8;
typedef __attribute__((ext_vector_type(4))) float f32x4;

#define NN 40962
#define NE 245760
#define HDIM 256
#define NH 8
#define CH 32

#define MT 64     // rows per block in MFMA kernels
#define KVB 512   // stage-1 blocks for sg_kv partial reduction

__device__ __forceinline__ float b2f(bf16 v) { return __bfloat162float(v); }
__device__ __forceinline__ bf16 f2b(float v) { return __float2bfloat16(v); }
__device__ __forceinline__ unsigned short f2bs(float v) {
  bf16 b = __float2bfloat16(v);
  return __builtin_bit_cast(unsigned short, b);
}
__device__ __forceinline__ float bs2f(unsigned short u) {
  return __bfloat162float(__builtin_bit_cast(bf16, u));
}

// gelu (tanh form) with native exp2: tanh(g) = (e^{2g}-1)/(e^{2g}+1)
__device__ __forceinline__ float fast_gelu(float x) {
  float x2 = x * x;
  float g = x * (0.7978845608028654f + 0.0356774081f * x2);
  float y = fminf(g * 2.885390081777927f, 60.f);   // 2*log2(e)*g, clamped
  float t = exp2f(y);
  float th = (t - 1.f) * __builtin_amdgcn_rcpf(t + 1.f);
  return 0.5f * x * (1.f + th);
}

// ---- MFMA edge input projection: e = attr @ epW + epb (K=16 zero-padded to 32) ------
__global__ __launch_bounds__(512) void k_edge_proj_mfma(
    const float* __restrict__ attr, const unsigned short* __restrict__ Weps,
    const float* __restrict__ bias, bf16* __restrict__ e) {
  __shared__ unsigned short At[MT][40];    // 64 x 32 (cols 16..31 zero) + pad
  __shared__ unsigned short O[MT][264];
  int tid = threadIdx.x, l = tid & 63, w = tid >> 6;
  int lr = l & 15, lk = l >> 4;
  int base = blockIdx.x * MT;              // NE % 64 == 0
  {
    int p = tid >> 3, q = tid & 7;         // 512 threads = 64 x 8 exactly
    if (q < 4) {
      float4 v = *reinterpret_cast<const float4*>(&attr[(size_t)(base + p) * 16 + q * 4]);
      unsigned short tmp[4] = {f2bs(v.x), f2bs(v.y), f2bs(v.z), f2bs(v.w)};
      *reinterpret_cast<uint2*>(&At[p][q * 4]) = *reinterpret_cast<const uint2*>(tmp);
    } else {
      unsigned short z[4] = {0, 0, 0, 0};
      *reinterpret_cast<uint2*>(&At[p][q * 4]) = *reinterpret_cast<const uint2*>(z);
    }
  }
  __syncthreads();

  int j0 = w * 32;
  f32x4 acc[4][2];
#pragma unroll
  for (int m = 0; m < 4; ++m)
#pragma unroll
    for (int n = 0; n < 2; ++n)
#pragma unroll
      for (int r = 0; r < 4; ++r) acc[m][n][r] = 0.f;
  {
    bf16x8 a[4], b[2];
#pragma unroll
    for (int m = 0; m < 4; ++m)
      a[m] = *reinterpret_cast<const bf16x8*>(&At[m * 16 + lr][lk * 8]);
#pragma unroll
    for (int n = 0; n < 2; ++n) {
      int nt = w * 2 + n;
      b[n] = *reinterpret_cast<const bf16x8*>(Weps + ((size_t)nt * 64 + l) * 8);
    }
#pragma unroll
    for (int m = 0; m < 4; ++m)
#pragma unroll
      for (int n = 0; n < 2; ++n)
        acc[m][n] = __builtin_amdgcn_mfma_f32_16x16x32_bf16(a[m], b[n], acc[m][n], 0, 0, 0);
  }
#pragma unroll
  for (int n = 0; n < 2; ++n) {
    int col = j0 + n * 16 + lr;
    float bv = bias[col];
#pragma unroll
    for (int m = 0; m < 4; ++m)
#pragma unroll
      for (int r = 0; r < 4; ++r)
        O[m * 16 + lk * 4 + r][col] = f2bs(acc[m][n][r] + bv);
  }
  __syncthreads();
  for (int t = tid; t < MT * 32; t += 512) {
    int p = t >> 5, c = t & 31;
    *reinterpret_cast<uint4*>(&e[(size_t)(base + p) * HDIM + c * 8]) =
        *reinterpret_cast<const uint4*>(&O[p][c * 8]);
  }
}

// ---- CSR build: count, scan(+cursor), fill (records pos[e] = CSR slot) --------------
__global__ void k_csr_count(const int* __restrict__ dst, int* __restrict__ cnt) {
  int e = blockIdx.x * 256 + threadIdx.x;
  if (e < NE) atomicAdd(&cnt[dst[e]], 1);
}
__global__ void k_csr_scan(const int* __restrict__ cnt, int* __restrict__ rowptr,
                           int* __restrict__ cursor) {
  __shared__ int part[256];
  __shared__ int tot;
  int t = threadIdx.x;
  const int CHUNK = (NN + 255) / 256;
  int lo = t * CHUNK, hi = lo + CHUNK; if (hi > NN) hi = NN; if (lo > NN) lo = NN;
  int s = 0;
  for (int i = lo; i < hi; ++i) s += cnt[i];
  part[t] = s;
  __syncthreads();
  if (t == 0) {
    int run = 0;
    for (int i = 0; i < 256; ++i) { int v = part[i]; part[i] = run; run += v; }
    tot = run;
  }
  __syncthreads();
  int run = part[t];
  for (int i = lo; i < hi; ++i) { rowptr[i] = run; cursor[i] = run; run += cnt[i]; }
  if (t == 0) rowptr[NN] = tot;
}
__global__ void k_csr_fill(const int* __restrict__ src, const int* __restrict__ dst,
                           int* __restrict__ cursor, int* __restrict__ csrsrc,
                           int* __restrict__ pos) {
  int e = blockIdx.x * 256 + threadIdx.x;
  if (e >= NE) return;
  int p = atomicAdd(&cursor[dst[e]], 1);
  csrsrc[p] = src[e];
  pos[e] = p;
}

// ---- fused weight swizzle (all matrices) + cnt zeroing ------------------------------
struct SwzP {
  const float *We0, *WeL, *Wl0, *Wr0, *Wq, *Wk, *Wv;
  const float *Wu1_0, *Wu1L, *Wu2_0, *Wu2L, *WlL, *WrL, *epW;
  unsigned short *wall, *w1s, *w2s, *w32s, *wep;
  int* cnt;
};
__device__ __forceinline__ void swz1(const float* __restrict__ W,
                                     unsigned short* __restrict__ out, int t, int Kdiv32) {
  int i = t & 7, l = (t >> 3) & 63;
  int k0 = (t >> 9) % Kdiv32;
  int n0 = t / (512 * Kdiv32);
  int k = k0 * 32 + (l >> 4) * 8 + i;
  int n = n0 * 16 + (l & 15);
  out[t] = f2bs(W[k * 256 + n]);
}
#define SWZ_NW (9 * 65536)
#define SWZ_N1 (3 * 81920)
#define SWZ_N2 (3 * 65536)
#define SWZ_N3 (6 * 8192)
#define SWZ_N4 8192
__global__ void k_swz_fused(SwzP P) {
  int gid = blockIdx.x * 256 + threadIdx.x;
  if (gid < SWZ_NW) {
    int mat = gid >> 16, t = gid & 65535;
    const float* W;
    switch (mat) {
      case 0: W = P.We0; break;
      case 1: W = P.WeL; break;
      case 2: W = P.WeL + 65536; break;
      case 3: W = P.WeL + 131072; break;
      case 4: W = P.Wl0; break;
      case 5: W = P.Wr0; break;
      case 6: W = P.Wq; break;
      case 7: W = P.Wk; break;
      default: W = P.Wv; break;
    }
    swz1(W, P.wall + (size_t)mat * 65536, t, 8);
  } else if (gid < SWZ_NW + SWZ_N1) {
    int idx = gid - SWZ_NW;
    int mat = idx / 81920, t = idx % 81920;
    const float* W = (mat == 0) ? P.Wu1_0 : P.Wu1L + (size_t)(mat - 1) * 81920;
    swz1(W, P.w1s + (size_t)mat * 81920, t, 10);
  } else if (gid < SWZ_NW + SWZ_N1 + SWZ_N2) {
    int idx = gid - SWZ_NW - SWZ_N1;
    int mat = idx >> 16, t = idx & 65535;
    const float* W = (mat == 0) ? P.Wu2_0 : P.Wu2L + (size_t)(mat - 1) * 65536;
    swz1(W, P.w2s + (size_t)mat * 65536, t, 8);
  } else if (gid < SWZ_NW + SWZ_N1 + SWZ_N2 + SWZ_N3) {
    int idx = gid - SWZ_NW - SWZ_N1 - SWZ_N2;
    int mat = idx >> 13, t = idx & 8191;
    int i = mat >> 1;
    const float* W = (mat & 1) ? P.WrL + (size_t)i * 8192 : P.WlL + (size_t)i * 8192;
    swz1(W, P.w32s + (size_t)mat * 8192, t, 1);
  } else if (gid < SWZ_NW + SWZ_N1 + SWZ_N2 + SWZ_N3 + SWZ_N4) {
    // epW [16][256] zero-padded to K=32 fragment layout
    int t = gid - (SWZ_NW + SWZ_N1 + SWZ_N2 + SWZ_N3);
    int i = t & 7, l = (t >> 3) & 63;
    int n0 = t >> 9;
    int k = (l >> 4) * 8 + i;
    int n = n0 * 16 + (l & 15);
    P.wep[t] = (k < 16) ? f2bs(P.epW[k * 256 + n]) : (unsigned short)0;
  } else {
    int i = gid - (SWZ_NW + SWZ_N1 + SWZ_N2 + SWZ_N3 + SWZ_N4);
    if (i < NN) P.cnt[i] = 0;
  }
}

// ---- MFMA edge score -> writes sxc[pos[e]*8+h] = exp(s)  (CSR-ordered) --------------
__global__ __launch_bounds__(512) void k_edge_score_mfma(
    const bf16* __restrict__ e, const unsigned short* __restrict__ Wes,
    const bf16* __restrict__ xl, const bf16* __restrict__ xr,
    const float* __restrict__ att, const int* __restrict__ src,
    const int* __restrict__ dst, const int* __restrict__ pos,
    float* __restrict__ sxc) {
  __shared__ unsigned short Ae[MT][264];   // e-tile, then reused as scoreboard
  __shared__ float attS[HDIM];
  __shared__ int sidx[MT], didx[MT];
  int tid = threadIdx.x, l = tid & 63, w = tid >> 6;
  int lr = l & 15, lk = l >> 4;
  int base = blockIdx.x * MT;
  if (tid < HDIM) attS[tid] = att[tid];
  if (tid < MT) sidx[tid] = src[base + tid];
  else if (tid < 2 * MT) didx[tid - MT] = dst[base + tid - MT];
  for (int t = tid; t < MT * 32; t += 512) {
    int p = t >> 5, c = t & 31;
    *reinterpret_cast<uint4*>(&Ae[p][c * 8]) =
        *reinterpret_cast<const uint4*>(&e[(size_t)(base + p) * HDIM + c * 8]);
  }
  __syncthreads();

  f32x4 acc[4][2];
#pragma unroll
  for (int m = 0; m < 4; ++m)
#pragma unroll
    for (int n = 0; n < 2; ++n)
#pragma unroll
      for (int r = 0; r < 4; ++r) acc[m][n][r] = 0.f;
  for (int k0 = 0; k0 < 8; ++k0) {
    bf16x8 a[4], b[2];
#pragma unroll
    for (int m = 0; m < 4; ++m)
      a[m] = *reinterpret_cast<const bf16x8*>(&Ae[m * 16 + lr][k0 * 32 + lk * 8]);
#pragma unroll
    for (int n = 0; n < 2; ++n) {
      int nt = w * 2 + n;
      b[n] = *reinterpret_cast<const bf16x8*>(Wes + ((size_t)(nt * 8 + k0) * 64 + l) * 8);
    }
#pragma unroll
    for (int m = 0; m < 4; ++m)
#pragma unroll
      for (int n = 0; n < 2; ++n)
        acc[m][n] = __builtin_amdgcn_mfma_f32_16x16x32_bf16(a[m], b[n], acc[m][n], 0, 0, 0);
  }
  __syncthreads();   // all Ae reads complete before scoreboard overwrite

  // epilogue: xl/xr read directly from global (L2-hot), scoreboard into Ae alias
#pragma unroll
  for (int n = 0; n < 2; ++n) {
    int col = w * 32 + n * 16 + lr;
    float av = attS[col];
#pragma unroll
    for (int m = 0; m < 4; ++m)
#pragma unroll
      for (int r = 0; r < 4; ++r) {
        int row = m * 16 + lk * 4 + r;
        float xs = b2f(xl[(size_t)sidx[row] * HDIM + col]) +
                   b2f(xr[(size_t)didx[row] * HDIM + col]);
        float mm = acc[m][n][r] + xs;
        mm = (mm > 0.f) ? mm : 0.2f * mm;
        Ae[row][col] = f2bs(mm * av);
      }
  }
  __syncthreads();
  for (int pair = tid; pair < MT * NH; pair += 512) {
    int ed = pair >> 3, h = pair & 7;
    float s = 0.f;
#pragma unroll
    for (int c = 0; c < CH; ++c) s += bs2f(Ae[ed][h * CH + c]);
    sxc[(size_t)pos[base + ed] * NH + h] = expf(s);
  }
}

// ---- fused CSR aggregate + node output + optional LN --------------------------------
// sxc is CSR-ordered: node n's ex values are contiguous at [rowptr[n]*8, rowptr[n+1]*8)
#define GCHUNK 64
template <int ID, bool LN>
__global__ __launch_bounds__(256) void k_gat_out(
    const int* __restrict__ rowptr, const int* __restrict__ csrsrc,
    const float* __restrict__ sxc, const bf16* __restrict__ xl,
    const float* __restrict__ x, const float* __restrict__ Wres,
    const float* __restrict__ bn, const float* __restrict__ lng,
    const float* __restrict__ lnb, float* __restrict__ xpre,
    float* __restrict__ xpost) {
  int n = blockIdx.x;
  int j = threadIdx.x;
  int h = j >> 5, c = j & 31;
  int p0 = rowptr[n], p1 = rowptr[n + 1];
  __shared__ int srcS[GCHUNK];
  __shared__ float exS[GCHUNK * NH];
  float a = 0.f, dsum = 0.f;
  for (int pb = p0; pb < p1; pb += GCHUNK) {
    int chunk = p1 - pb; if (chunk > GCHUNK) chunk = GCHUNK;
    if (j < chunk) srcS[j] = csrsrc[pb + j];
    for (int t = j; t < chunk * NH; t += 256) exS[t] = sxc[(size_t)pb * NH + t];
    __syncthreads();
    int i = 0;
    for (; i + 4 <= chunk; i += 4) {
      float e0 = exS[(i + 0) * NH + h], e1 = exS[(i + 1) * NH + h];
      float e2 = exS[(i + 2) * NH + h], e3 = exS[(i + 3) * NH + h];
      float x0 = b2f(xl[(size_t)srcS[i + 0] * HDIM + j]);
      float x1 = b2f(xl[(size_t)srcS[i + 1] * HDIM + j]);
      float x2 = b2f(xl[(size_t)srcS[i + 2] * HDIM + j]);
      float x3 = b2f(xl[(size_t)srcS[i + 3] * HDIM + j]);
      a += e0 * x0 + e1 * x1 + e2 * x2 + e3 * x3;
      dsum += e0 + e1 + e2 + e3;
    }
    for (; i < chunk; ++i) {
      float ev = exS[i * NH + h];
      a += ev * b2f(xl[(size_t)srcS[i] * HDIM + j]);
      dsum += ev;
    }
    __syncthreads();
  }
  __shared__ float oh[HDIM];
  __shared__ float rs[NH][CH];
  __shared__ float oc[CH + 1];
  oh[j] = a / (dsum + 1e-16f);
  const int KS = ID / NH;
  float r = 0.f;
  for (int k = h * KS; k < (h + 1) * KS; ++k)
    r += x[(size_t)n * ID + k] * Wres[k * CH + c];
  rs[h][c] = r;
  __syncthreads();
  if (j < CH) {
    float o = 0.f;
#pragma unroll
    for (int hh = 0; hh < NH; ++hh) o += oh[hh * CH + j];
    o *= (1.f / NH);
    float rr = 0.f;
#pragma unroll
    for (int hh = 0; hh < NH; ++hh) rr += rs[hh][j];
    o += rr + bn[j];
    xpre[(size_t)n * CH + j] = o;
    oc[j] = o;
  }
  __syncthreads();
  if (LN && j < CH) {
    float mu = 0.f;
#pragma unroll
    for (int k = 0; k < CH; ++k) mu += oc[k];
    mu *= (1.f / CH);
    float var = 0.f;
#pragma unroll
    for (int k = 0; k < CH; ++k) { float d = oc[k] - mu; var += d * d; }
    var *= (1.f / CH);
    xpost[(size_t)n * CH + j] = (oc[j] - mu) * rsqrtf(var + 1e-5f) * lng[j] + lnb[j];
  }
}

// ---- MFMA residual edge MLP (8 waves, single aliased 42KB LDS buffer) ---------------
__global__ __launch_bounds__(512) void k_edge_mlp_mfma(
    bf16* __restrict__ e, const float* __restrict__ xo,
    const int* __restrict__ src, const int* __restrict__ dst,
    const unsigned short* __restrict__ W1s, const float* __restrict__ bu1,
    const unsigned short* __restrict__ W2s, const float* __restrict__ bu2) {
  __shared__ unsigned short buf[MT][328];   // A1 (xo|e), then gelu(h1), then delta
  __shared__ int sidx[MT], didx[MT];
  int tid = threadIdx.x;
  int l = tid & 63;
  int w = tid >> 6;
  int base = blockIdx.x * MT;
  int lr = l & 15;
  int lk = l >> 4;

  if (tid < MT) sidx[tid] = src[base + tid];
  else if (tid < 2 * MT) didx[tid - MT] = dst[base + tid - MT];
  __syncthreads();

  for (int t = tid; t < MT * 32; t += 512) {
    int p = t >> 5, cc = t & 31;
    uint4 v = *reinterpret_cast<const uint4*>(&e[(size_t)(base + p) * HDIM + cc * 8]);
    *reinterpret_cast<uint4*>(&buf[p][64 + cc * 8]) = v;
  }
  for (int t = tid; t < MT * 64; t += 512) {
    int p = t >> 6, c = t & 63;
    float v = (c < CH) ? xo[(size_t)sidx[p] * CH + c]
                       : xo[(size_t)didx[p] * CH + (c - CH)];
    buf[p][c] = f2bs(v);
  }
  __syncthreads();

  int j0 = w * 32;

  f32x4 acc[4][2];
#pragma unroll
  for (int m = 0; m < 4; ++m)
#pragma unroll
    for (int n = 0; n < 2; ++n)
#pragma unroll
      for (int r = 0; r < 4; ++r) acc[m][n][r] = 0.f;

  for (int k0 = 0; k0 < 10; ++k0) {
    bf16x8 a[4], b[2];
#pragma unroll
    for (int m = 0; m < 4; ++m)
      a[m] = *reinterpret_cast<const bf16x8*>(&buf[m * 16 + lr][k0 * 32 + lk * 8]);
#pragma unroll
    for (int n = 0; n < 2; ++n) {
      int nt = w * 2 + n;
      b[n] = *reinterpret_cast<const bf16x8*>(W1s + ((size_t)(nt * 10 + k0) * 64 + l) * 8);
    }
#pragma unroll
    for (int m = 0; m < 4; ++m)
#pragma unroll
      for (int n = 0; n < 2; ++n)
        acc[m][n] = __builtin_amdgcn_mfma_f32_16x16x32_bf16(a[m], b[n], acc[m][n], 0, 0, 0);
  }
  __syncthreads();   // all A1 reads complete before overwrite

  // gelu(h1 + bu1) -> buf alias (cols 0..255)
#pragma unroll
  for (int n = 0; n < 2; ++n) {
    float bv = bu1[j0 + n * 16 + lr];
#pragma unroll
    for (int m = 0; m < 4; ++m)
#pragma unroll
      for (int r = 0; r < 4; ++r) {
        float g = fast_gelu(acc[m][n][r] + bv);
        buf[m * 16 + lk * 4 + r][j0 + n * 16 + lr] = f2bs(g);
      }
  }
  __syncthreads();

#pragma unroll
  for (int m = 0; m < 4; ++m)
#pragma unroll
    for (int n = 0; n < 2; ++n)
#pragma unroll
      for (int r = 0; r < 4; ++r) acc[m][n][r] = 0.f;

  for (int k0 = 0; k0 < 8; ++k0) {
    bf16x8 a[4], b[2];
#pragma unroll
    for (int m = 0; m < 4; ++m)
      a[m] = *reinterpret_cast<const bf16x8*>(&buf[m * 16 + lr][k0 * 32 + lk * 8]);
#pragma unroll
    for (int n = 0; n < 2; ++n) {
      int nt = w * 2 + n;
      b[n] = *reinterpret_cast<const bf16x8*>(W2s + ((size_t)(nt * 8 + k0) * 64 + l) * 8);
    }
#pragma unroll
    for (int m = 0; m < 4; ++m)
#pragma unroll
      for (int n = 0; n < 2; ++n)
        acc[m][n] = __builtin_amdgcn_mfma_f32_16x16x32_bf16(a[m], b[n], acc[m][n], 0, 0, 0);
  }
  __syncthreads();   // all gelu reads done before delta overwrite

  // delta = acc + bu2 -> buf alias
#pragma unroll
  for (int n = 0; n < 2; ++n) {
    int col = j0 + n * 16 + lr;
    float bv = bu2[col];
#pragma unroll
    for (int m = 0; m < 4; ++m)
#pragma unroll
      for (int r = 0; r < 4; ++r)
        buf[m * 16 + lk * 4 + r][col] = f2bs(acc[m][n][r] + bv);
  }
  __syncthreads();

  // store: e_new = e_old (global re-read, L2-hot) + delta
  for (int t = tid; t < MT * 32; t += 512) {
    int p = t >> 5, cc = t & 31;
    uint4 dv = *reinterpret_cast<const uint4*>(&buf[p][cc * 8]);
    uint4 ev = *reinterpret_cast<const uint4*>(&e[(size_t)(base + p) * HDIM + cc * 8]);
    const unsigned short* dd = (const unsigned short*)&dv;
    const unsigned short* ee = (const unsigned short*)&ev;
    unsigned short ov[8];
#pragma unroll
    for (int i = 0; i < 8; ++i) ov[i] = f2bs(bs2f(ee[i]) + bs2f(dd[i]));
    *reinterpret_cast<uint4*>(&e[(size_t)(base + p) * HDIM + cc * 8]) =
        *reinterpret_cast<const uint4*>(ov);
  }
}

// ---- MFMA layer-0 node projection ---------------------------------------------------
__global__ __launch_bounds__(256) void k_node_proj0_mfma(
    const float* __restrict__ x, const unsigned short* __restrict__ Wls,
    const unsigned short* __restrict__ Wrs, bf16* __restrict__ xl,
    bf16* __restrict__ xr) {
  __shared__ unsigned short A[MT][264];
  __shared__ unsigned short O[MT][264];
  int tid = threadIdx.x, l = tid & 63, w = tid >> 6;
  int lr = l & 15, lk = l >> 4;
  int base = blockIdx.x * MT;
  for (int t = tid; t < MT * 64; t += 256) {
    int p = t >> 6, c = t & 63;
    int row = base + p; if (row >= NN) row = NN - 1;
    float4 v = *reinterpret_cast<const float4*>(&x[(size_t)row * HDIM + c * 4]);
    unsigned short tmp[4] = {f2bs(v.x), f2bs(v.y), f2bs(v.z), f2bs(v.w)};
    *reinterpret_cast<uint2*>(&A[p][c * 4]) = *reinterpret_cast<const uint2*>(tmp);
  }
  __syncthreads();
  int j0 = w * 64;
#pragma unroll
  for (int mtx = 0; mtx < 2; ++mtx) {
    const unsigned short* Ws = (mtx == 0) ? Wls : Wrs;
    bf16* outp = (mtx == 0) ? xl : xr;
    f32x4 acc[4][4];
#pragma unroll
    for (int m = 0; m < 4; ++m)
#pragma unroll
      for (int n = 0; n < 4; ++n)
#pragma unroll
        for (int r = 0; r < 4; ++r) acc[m][n][r] = 0.f;
    for (int k0 = 0; k0 < 8; ++k0) {
      bf16x8 a[4], b[4];
#pragma unroll
      for (int m = 0; m < 4; ++m)
        a[m] = *reinterpret_cast<const bf16x8*>(&A[m * 16 + lr][k0 * 32 + lk * 8]);
#pragma unroll
      for (int n = 0; n < 4; ++n) {
        int nt = (j0 >> 4) + n;
        b[n] = *reinterpret_cast<const bf16x8*>(Ws + ((size_t)(nt * 8 + k0) * 64 + l) * 8);
      }
#pragma unroll
      for (int m = 0; m < 4; ++m)
#pragma unroll
        for (int n = 0; n < 4; ++n)
          acc[m][n] = __builtin_amdgcn_mfma_f32_16x16x32_bf16(a[m], b[n], acc[m][n], 0, 0, 0);
    }
#pragma unroll
    for (int n = 0; n < 4; ++n)
#pragma unroll
      for (int m = 0; m < 4; ++m)
#pragma unroll
        for (int r = 0; r < 4; ++r)
          O[m * 16 + lk * 4 + r][j0 + n * 16 + lr] = f2bs(acc[m][n][r]);
    __syncthreads();
    for (int t = tid; t < MT * 32; t += 256) {
      int p = t >> 5, c = t & 31;
      if (base + p < NN)
        *reinterpret_cast<uint4*>(&outp[(size_t)(base + p) * HDIM + c * 8]) =
            *reinterpret_cast<const uint4*>(&O[p][c * 8]);
    }
    __syncthreads();
  }
}

// ---- MFMA small node projection (layers 1..3, K=32) ---------------------------------
__global__ __launch_bounds__(256) void k_node_projS_mfma(
    const float* __restrict__ x, const unsigned short* __restrict__ Wls,
    const unsigned short* __restrict__ Wrs, bf16* __restrict__ xl,
    bf16* __restrict__ xr) {
  __shared__ unsigned short A[MT][40];
  __shared__ unsigned short O[MT][264];
  int tid = threadIdx.x, l = tid & 63, w = tid >> 6;
  int lr = l & 15, lk = l >> 4;
  int base = blockIdx.x * MT;
  for (int t = tid; t < MT * 8; t += 256) {
    int p = t >> 3, q = t & 7;
    int row = base + p; if (row >= NN) row = NN - 1;
    float4 v = *reinterpret_cast<const float4*>(&x[(size_t)row * CH + q * 4]);
    unsigned short tmp[4] = {f2bs(v.x), f2bs(v.y), f2bs(v.z), f2bs(v.w)};
    *reinterpret_cast<uint2*>(&A[p][q * 4]) = *reinterpret_cast<const uint2*>(tmp);
  }
  __syncthreads();
  int j0 = w * 64;
#pragma unroll
  for (int mtx = 0; mtx < 2; ++mtx) {
    const unsigned short* Ws = (mtx == 0) ? Wls : Wrs;
    bf16* outp = (mtx == 0) ? xl : xr;
    f32x4 acc[4][4];
#pragma unroll
    for (int m = 0; m < 4; ++m)
#pragma unroll
      for (int n = 0; n < 4; ++n)
#pragma unroll
        for (int r = 0; r < 4; ++r) acc[m][n][r] = 0.f;
    bf16x8 a[4], b[4];
#pragma unroll
    for (int m = 0; m < 4; ++m)
      a[m] = *reinterpret_cast<const bf16x8*>(&A[m * 16 + lr][lk * 8]);
#pragma unroll
    for (int n = 0; n < 4; ++n) {
      int nt = (j0 >> 4) + n;
      b[n] = *reinterpret_cast<const bf16x8*>(Ws + ((size_t)nt * 64 + l) * 8);
    }
#pragma unroll
    for (int m = 0; m < 4; ++m)
#pragma unroll
      for (int n = 0; n < 4; ++n)
        acc[m][n] = __builtin_amdgcn_mfma_f32_16x16x32_bf16(a[m], b[n], acc[m][n], 0, 0, 0);
#pragma unroll
    for (int n = 0; n < 4; ++n)
#pragma unroll
      for (int m = 0; m < 4; ++m)
#pragma unroll
        for (int r = 0; r < 4; ++r)
          O[m * 16 + lk * 4 + r][j0 + n * 16 + lr] = f2bs(acc[m][n][r]);
    __syncthreads();
    for (int t = tid; t < MT * 32; t += 256) {
      int p = t >> 5, c = t & 31;
      if (base + p < NN)
        *reinterpret_cast<uint4*>(&outp[(size_t)(base + p) * HDIM + c * 8]) =
            *reinterpret_cast<const uint4*>(&O[p][c * 8]);
    }
    __syncthreads();
  }
}

// ---- MFMA SGFormer qkv --------------------------------------------------------------
__global__ __launch_bounds__(256) void k_sg_qkv_mfma(
    const float* __restrict__ x, const unsigned short* __restrict__ Wqs,
    const unsigned short* __restrict__ Wks, const unsigned short* __restrict__ Wvs,
    bf16* __restrict__ qs, bf16* __restrict__ ks, bf16* __restrict__ vv) {
  __shared__ unsigned short A[MT][264];
  __shared__ unsigned short O[MT][264];
  int tid = threadIdx.x, l = tid & 63, w = tid >> 6;
  int lr = l & 15, lk = l >> 4;
  int base = blockIdx.x * MT;
  for (int t = tid; t < MT * 64; t += 256) {
    int p = t >> 6, c = t & 63;
    int row = base + p; if (row >= NN) row = NN - 1;
    float4 v = *reinterpret_cast<const float4*>(&x[(size_t)row * HDIM + c * 4]);
    unsigned short tmp[4] = {f2bs(v.x), f2bs(v.y), f2bs(v.z), f2bs(v.w)};
    *reinterpret_cast<uint2*>(&A[p][c * 4]) = *reinterpret_cast<const uint2*>(tmp);
  }
  __syncthreads();
  int j0 = w * 64;
#pragma unroll
  for (int mtx = 0; mtx < 3; ++mtx) {
    const unsigned short* Ws = (mtx == 0) ? Wqs : (mtx == 1) ? Wks : Wvs;
    bf16* outp = (mtx == 0) ? qs : (mtx == 1) ? ks : vv;
    f32x4 acc[4][4];
#pragma unroll
    for (int m = 0; m < 4; ++m)
#pragma unroll
      for (int n = 0; n < 4; ++n)
#pragma unroll
        for (int r = 0; r < 4; ++r) acc[m][n][r] = 0.f;
    for (int k0 = 0; k0 < 8; ++k0) {
      bf16x8 a[4], b[4];
#pragma unroll
      for (int m = 0; m < 4; ++m)
        a[m] = *reinterpret_cast<const bf16x8*>(&A[m * 16 + lr][k0 * 32 + lk * 8]);
#pragma unroll
      for (int n = 0; n < 4; ++n) {
        int nt = (j0 >> 4) + n;
        b[n] = *reinterpret_cast<const bf16x8*>(Ws + ((size_t)(nt * 8 + k0) * 64 + l) * 8);
      }
#pragma unroll
      for (int m = 0; m < 4; ++m)
#pragma unroll
        for (int n = 0; n < 4; ++n)
          acc[m][n] = __builtin_amdgcn_mfma_f32_16x16x32_bf16(a[m], b[n], acc[m][n], 0, 0, 0);
    }
    if (mtx < 2) {
      float pa[4][4], pb[4][4];
#pragma unroll
      for (int m = 0; m < 4; ++m)
#pragma unroll
        for (int r = 0; r < 4; ++r) {
          pa[m][r] = acc[m][0][r] * acc[m][0][r] + acc[m][1][r] * acc[m][1][r];
          pb[m][r] = acc[m][2][r] * acc[m][2][r] + acc[m][3][r] * acc[m][3][r];
        }
#pragma unroll
      for (int off = 1; off < 16; off <<= 1) {
#pragma unroll
        for (int m = 0; m < 4; ++m)
#pragma unroll
          for (int r = 0; r < 4; ++r) {
            pa[m][r] += __shfl_xor(pa[m][r], off);
            pb[m][r] += __shfl_xor(pb[m][r], off);
          }
      }
#pragma unroll
      for (int m = 0; m < 4; ++m)
#pragma unroll
        for (int r = 0; r < 4; ++r) {
          float ra = 1.f / (sqrtf(pa[m][r]) + 1e-6f);
          float rb = 1.f / (sqrtf(pb[m][r]) + 1e-6f);
          acc[m][0][r] *= ra; acc[m][1][r] *= ra;
          acc[m][2][r] *= rb; acc[m][3][r] *= rb;
        }
    }
#pragma unroll
    for (int n = 0; n < 4; ++n)
#pragma unroll
      for (int m = 0; m < 4; ++m)
#pragma unroll
        for (int r = 0; r < 4; ++r)
          O[m * 16 + lk * 4 + r][j0 + n * 16 + lr] = f2bs(acc[m][n][r]);
    __syncthreads();
    for (int t = tid; t < MT * 32; t += 256) {
      int p = t >> 5, c = t & 31;
      if (base + p < NN)
        *reinterpret_cast<uint4*>(&outp[(size_t)(base + p) * HDIM + c * 8]) =
            *reinterpret_cast<const uint4*>(&O[p][c * 8]);
    }
    __syncthreads();
  }
}

// ---- sg_kv stage 1: per-block partials (NO atomics) ---------------------------------
__global__ void k_sg_kv1(const bf16* __restrict__ ks, const bf16* __restrict__ vv,
                         float* __restrict__ part) {
  int t = threadIdx.x;
  int h = t >> 5;
  float kvloc[CH];
  float ksl = 0.f;
#pragma unroll
  for (int d = 0; d < CH; ++d) kvloc[d] = 0.f;
  __shared__ float krow[HDIM], vrow[HDIM];
  for (int n = blockIdx.x; n < NN; n += KVB) {
    krow[t] = b2f(ks[(size_t)n * HDIM + t]);
    vrow[t] = b2f(vv[(size_t)n * HDIM + t]);
    __syncthreads();
    float kc = krow[t];
    ksl += kc;
#pragma unroll
    for (int d = 0; d < CH; ++d) kvloc[d] += kc * vrow[h * CH + d];
    __syncthreads();
  }
  float* dstp = part + (size_t)blockIdx.x * 8448;
#pragma unroll
  for (int d = 0; d < CH; d += 4)
    *reinterpret_cast<float4*>(&dstp[t * CH + d]) =
        *reinterpret_cast<const float4*>(&kvloc[d]);
  dstp[8192 + t] = ksl;
}

// ---- sg_kv stage 2: deterministic reduce over KVB partials --------------------------
__global__ void k_sg_kv2(const float* __restrict__ part, float* __restrict__ kv,
                         float* __restrict__ ksum) {
  int idx = blockIdx.x * 256 + threadIdx.x;
  if (idx >= 8448) return;
  float s = 0.f;
  for (int b = 0; b < KVB; ++b) s += part[(size_t)b * 8448 + idx];
  if (idx < 8192) kv[idx] = s;
  else ksum[idx - 8192] = s;
}

// ---- trans + combine + LN -> f32 out ------------------------------------------------
__global__ void k_sg_final(const bf16* __restrict__ qs, const bf16* __restrict__ vv,
                           const float* __restrict__ kv, const float* __restrict__ ksum,
                           const float* __restrict__ xg, const float* __restrict__ alphap,
                           const float* __restrict__ cng, const float* __restrict__ cnb,
                           float* __restrict__ out) {
  int t = threadIdx.x;
  int d = t & 31, sub = t >> 5;
  __shared__ float qrow[8][HDIM];
  __shared__ float crow[8][CH];
  int n = blockIdx.x * 8 + sub;
  for (int tt = t; tt < 8 * HDIM; tt += 256) {
    int p = tt >> 8, k = tt & 255;
    int n2 = blockIdx.x * 8 + p;
    if (n2 < NN) qrow[p][k] = b2f(qs[(size_t)n2 * HDIM + k]);
  }
  __syncthreads();
  float alpha = 1.f / (1.f + expf(-alphap[0]));
  const float Nf = (float)NN;
  float comb = 0.f;
  if (n < NN) {
    float acc = 0.f;
#pragma unroll
    for (int h = 0; h < NH; ++h) {
      float nm = 0.f, dp = 0.f;
#pragma unroll 8
      for (int c = 0; c < CH; ++c) {
        float qv = qrow[sub][h * CH + c];
        nm += qv * kv[(h * CH + c) * CH + d];
        dp += qv * ksum[h * CH + c];
      }
      nm += Nf * b2f(vv[(size_t)n * HDIM + h * CH + d]);
      acc += nm / (dp + Nf);
    }
    float trans = acc * (1.f / NH);
    comb = alpha * xg[(size_t)n * CH + d] + (1.f - alpha) * trans;
    crow[sub][d] = comb;
  }
  __syncthreads();
  if (n < NN) {
    float mu = 0.f;
#pragma unroll
    for (int k = 0; k < CH; ++k) mu += crow[sub][k];
    mu *= (1.f / CH);
    float var = 0.f;
#pragma unroll
    for (int k = 0; k < CH; ++k) { float dv = crow[sub][k] - mu; var += dv * dv; }
    var *= (1.f / CH);
    float o = (comb - mu) * rsqrtf(var + 1e-5f) * cng[d] + cnb[d];
    out[(size_t)n * CH + d] = o;
  }
}

extern "C" void kernel_launch(void* const* d_in, const int* in_sizes, int n_in,
                              void* d_out, int out_size, void* d_ws, size_t ws_size,
                              hipStream_t stream) {
  const float* mesh  = (const float*)d_in[0];
  const int*   eidx  = (const int*)d_in[1];
  const float* eattr = (const float*)d_in[2];
  const float* epW   = (const float*)d_in[3];
  const float* epb   = (const float*)d_in[4];
  const float* Wl0   = (const float*)d_in[5];
  const float* Wr0   = (const float*)d_in[6];
  const float* WlL   = (const float*)d_in[7];
  const float* WrL   = (const float*)d_in[8];
  const float* We0   = (const float*)d_in[9];
  const float* WeL   = (const float*)d_in[10];
  const float* att0  = (const float*)d_in[11];
  const float* attL  = (const float*)d_in[12];
  const float* Wres0 = (const float*)d_in[13];
  const float* WresL = (const float*)d_in[14];
  const float* bn0   = (const float*)d_in[15];
  const float* bnL   = (const float*)d_in[16];
  const float* Wu1_0 = (const float*)d_in[17];
  const float* Wu1L  = (const float*)d_in[18];
  const float* bu1_0 = (const float*)d_in[19];
  const float* bu1L  = (const float*)d_in[20];
  const float* Wu2_0 = (const float*)d_in[21];
  const float* Wu2L  = (const float*)d_in[22];
  const float* bu2_0 = (const float*)d_in[23];
  const float* bu2L  = (const float*)d_in[24];
  const float* lng   = (const float*)d_in[25];
  const float* lnb   = (const float*)d_in[26];
  const float* Wq    = (const float*)d_in[27];
  const float* Wk    = (const float*)d_in[28];
  const float* Wv    = (const float*)d_in[29];
  const float* alphap= (const float*)d_in[30];
  const float* cng   = (const float*)d_in[31];
  const float* cnb   = (const float*)d_in[32];

  const int* src = eidx;
  const int* dst = eidx + NE;

  char* base = (char*)d_ws;
  size_t o = 0;
  auto alloc = [&](size_t bytes) -> char* {
    o = (o + 255) & ~(size_t)255;
    char* p = base + o;
    o += bytes;
    return p;
  };
  bf16* e    = (bf16*)alloc((size_t)NE * HDIM * 2);
  bf16* xl   = (bf16*)alloc((size_t)NN * HDIM * 2);   // reused: qs
  bf16* xr   = (bf16*)alloc((size_t)NN * HDIM * 2);   // reused: ks
  bf16* vvb  = (bf16*)alloc((size_t)NN * HDIM * 2);   // SGFormer v
  float* sxc = (float*)alloc((size_t)NE * NH * 4);    // exp(scores), CSR-ordered
  float* xa  = (float*)alloc((size_t)NN * CH * 4);
  float* xb  = (float*)alloc((size_t)NN * CH * 4);
  float* xc  = (float*)alloc((size_t)NN * CH * 4);
  float* kv  = (float*)alloc(NH * CH * CH * 4);
  float* ksum= (float*)alloc(NH * CH * 4);
  float* kvpart = (float*)alloc((size_t)KVB * 8448 * 4);   // 17.3 MB
  unsigned short* w1s = (unsigned short*)alloc((size_t)3 * 320 * 256 * 2);
  unsigned short* w2s = (unsigned short*)alloc((size_t)3 * 256 * 256 * 2);
  unsigned short* wall= (unsigned short*)alloc((size_t)9 * 65536 * 2);
  unsigned short* w32s= (unsigned short*)alloc((size_t)6 * 32 * 256 * 2);
  unsigned short* wep = (unsigned short*)alloc((size_t)SWZ_N4 * 2);
  int* cnt    = (int*)alloc((size_t)NN * 4);
  int* rowptr = (int*)alloc((size_t)(NN + 1) * 4);
  int* cursor = (int*)alloc((size_t)NN * 4);
  int* csrsrc = (int*)alloc((size_t)NE * 4);
  int* pos    = (int*)alloc((size_t)NE * 4);
  if (ws_size < o) return;   // fail cleanly if ws too small

  // fused pre-pass: all weight swizzles (incl. epW) + cnt zeroing in ONE launch
  SwzP P;
  P.We0 = We0; P.WeL = WeL; P.Wl0 = Wl0; P.Wr0 = Wr0; P.Wq = Wq; P.Wk = Wk; P.Wv = Wv;
  P.Wu1_0 = Wu1_0; P.Wu1L = Wu1L; P.Wu2_0 = Wu2_0; P.Wu2L = Wu2L;
  P.WlL = WlL; P.WrL = WrL; P.epW = epW;
  P.wall = wall; P.w1s = w1s; P.w2s = w2s; P.w32s = w32s; P.wep = wep; P.cnt = cnt;
  int swz_total = SWZ_NW + SWZ_N1 + SWZ_N2 + SWZ_N3 + SWZ_N4 + NN;
  k_swz_fused<<<(swz_total + 255) / 256, 256, 0, stream>>>(P);

  // CSR build (graph constant across layers); pos[e] = CSR slot of edge e
  k_csr_count<<<(NE + 255) / 256, 256, 0, stream>>>(dst, cnt);
  k_csr_scan<<<1, 256, 0, stream>>>(cnt, rowptr, cursor);
  k_csr_fill<<<(NE + 255) / 256, 256, 0, stream>>>(src, dst, cursor, csrsrc, pos);

  k_edge_proj_mfma<<<NE / MT, 512, 0, stream>>>(eattr, wep, epb, e);

  const float* xin = mesh;
  float* post = xb;
  for (int l = 0; l < 4; ++l) {
    const float *att_p, *Wres_p, *bn_p, *bu1_p, *bu2_p;
    if (l == 0) {
      att_p = att0; Wres_p = Wres0; bn_p = bn0; bu1_p = bu1_0; bu2_p = bu2_0;
    } else {
      int i = l - 1;
      att_p = attL + (size_t)i * HDIM;
      Wres_p = WresL + (size_t)i * CH * CH;
      bn_p = bnL + (size_t)i * CH;
      bu1_p = bu1L + (size_t)i * HDIM;
      bu2_p = bu2L + (size_t)i * HDIM;
    }

    if (l == 0)
      k_node_proj0_mfma<<<(NN + MT - 1) / MT, 256, 0, stream>>>(
          mesh, wall + (size_t)4 * 65536, wall + (size_t)5 * 65536, xl, xr);
    else
      k_node_projS_mfma<<<(NN + MT - 1) / MT, 256, 0, stream>>>(
          xin, w32s + (size_t)((l - 1) * 2 + 0) * 8192,
          w32s + (size_t)((l - 1) * 2 + 1) * 8192, xl, xr);

    k_edge_score_mfma<<<NE / MT, 512, 0, stream>>>(e, wall + (size_t)l * 65536,
                                                   xl, xr, att_p, src, dst, pos, sxc);

    if (l == 0)
      k_gat_out<HDIM, true><<<NN, 256, 0, stream>>>(rowptr, csrsrc, sxc, xl, xin, Wres_p,
                                                    bn_p, lng, lnb, xa, post);
    else if (l < 3)
      k_gat_out<CH, true><<<NN, 256, 0, stream>>>(rowptr, csrsrc, sxc, xl, xin, Wres_p,
                                                  bn_p, lng + (size_t)l * CH,
                                                  lnb + (size_t)l * CH, xa, post);
    else
      k_gat_out<CH, false><<<NN, 256, 0, stream>>>(rowptr, csrsrc, sxc, xl, xin, Wres_p,
                                                   bn_p, nullptr, nullptr, xa, nullptr);

    if (l < 3)
      k_edge_mlp_mfma<<<NE / MT, 512, 0, stream>>>(e, xa, src, dst,
                                                   w1s + (size_t)l * 320 * 256, bu1_p,
                                                   w2s + (size_t)l * 256 * 256, bu2_p);

    xin = post;
    post = (post == xb) ? xc : xb;
  }
  // final GAT output (no LN) is in xa

  k_sg_qkv_mfma<<<(NN + MT - 1) / MT, 256, 0, stream>>>(
      mesh, wall + (size_t)6 * 65536, wall + (size_t)7 * 65536,
      wall + (size_t)8 * 65536, xl, xr, vvb);
  k_sg_kv1<<<KVB, 256, 0, stream>>>(xr, vvb, kvpart);
  k_sg_kv2<<<33, 256, 0, stream>>>(kvpart, kv, ksum);
  k_sg_final<<<(NN + 7) / 8, 256, 0, stream>>>(xl, vvb, kv, ksum, xa, alphap, cng, cnb,
                                               (float*)d_out);
}